// Round 4
// baseline (1419.832 us; speedup 1.0000x reference)
//
#include <hip/hip_runtime.h>
#include <type_traits>

typedef unsigned short ushort_t;
typedef unsigned int   uint_t;
typedef __attribute__((ext_vector_type(8))) short bf16x8;
typedef __attribute__((ext_vector_type(4))) float f32x4;

constexpr int Bn = 4, Tn = 1024, Cn = 2048, NH = 16, HS = 128;
constexpr int NLQ = 1536, NLKV = 512, DHR = 64;
constexpr int BT = Bn * Tn;
constexpr float ATT_SCALE = 0.07216878364870323f; // 1/sqrt(192)
constexpr float LOG2E = 1.4426950408889634f;

__device__ __forceinline__ ushort_t f2bf(float f) {
    uint_t u = __float_as_uint(f);
    u += 0x7fffu + ((u >> 16) & 1u);   // RNE
    return (ushort_t)(u >> 16);
}

__device__ __forceinline__ void gload_lds16(const void* g, void* l) {
    __builtin_amdgcn_global_load_lds(
        (__attribute__((address_space(1))) void*)g,
        (__attribute__((address_space(3))) void*)l, 16, 0, 0);
}

// ---------------------------------------------------------------------------
// f32 -> bf16 conversion (vectorized, 8/thread). n must be multiple of 2048.
// ---------------------------------------------------------------------------
__global__ void cvt_bf16(const float* __restrict__ in, ushort_t* __restrict__ out) {
    long i = ((long)blockIdx.x * 256 + threadIdx.x) * 8;
    float4 a = *(const float4*)&in[i];
    float4 b = *(const float4*)&in[i + 4];
    ushort_t p[8] = {f2bf(a.x), f2bf(a.y), f2bf(a.z), f2bf(a.w),
                     f2bf(b.x), f2bf(b.y), f2bf(b.z), f2bf(b.w)};
    *(uint4*)&out[i] = *(const uint4*)p;
}

// ---------------------------------------------------------------------------
// Transpose+convert [2048][512] f32 -> [512][2048] bf16 (z=0: W_uk, z=1: W_uv)
// ---------------------------------------------------------------------------
__global__ __launch_bounds__(256) void transcvt_bf16(
    const float* __restrict__ A, ushort_t* __restrict__ At,
    const float* __restrict__ Bp, ushort_t* __restrict__ Bt)
{
    __shared__ float tile[64][65];
    const float* in = blockIdx.z ? Bp : A;
    ushort_t* out   = blockIdx.z ? Bt : At;
    const int k0 = blockIdx.x * 64, c0 = blockIdx.y * 64;
    const int t = threadIdx.x;
    #pragma unroll
    for (int i = 0; i < 4; ++i) {
        int idx = t + i * 256;
        int r = idx >> 4, c4 = idx & 15;
        float4 v = *(const float4*)&in[(long)(c0 + r) * 512 + k0 + c4 * 4];
        tile[r][c4 * 4 + 0] = v.x; tile[r][c4 * 4 + 1] = v.y;
        tile[r][c4 * 4 + 2] = v.z; tile[r][c4 * 4 + 3] = v.w;
    }
    __syncthreads();
    #pragma unroll
    for (int i = 0; i < 4; ++i) {
        int idx = t + i * 256;
        int kr = idx >> 4, c4 = idx & 15;
        ushort_t p[4];
        #pragma unroll
        for (int j = 0; j < 4; ++j) p[j] = f2bf(tile[c4 * 4 + j][kr]);
        *(uint2*)&out[(long)(k0 + kr) * 2048 + c0 + c4 * 4] = *(const uint2*)p;
    }
}

// ---------------------------------------------------------------------------
// bf16 MFMA GEMM (m97 structure), NT, bf16 out. Unchanged from round 3.
// ---------------------------------------------------------------------------
__global__ __launch_bounds__(256, 2) void gemm_bf16(
    const ushort_t* __restrict__ A, const ushort_t* __restrict__ B,
    ushort_t* __restrict__ C,
    int K, int lda, int ldb, int ldc, long sA, long sB, long sC)
{
    constexpr int BK = 32;
    __shared__ ushort_t As[128 * BK];
    __shared__ ushort_t Bs[128 * BK];

    const int tid  = threadIdx.x;
    const int lane = tid & 63;
    const int w    = tid >> 6;
    const int l15 = lane & 15, l4 = lane >> 4;
    const int wr = w >> 1, wc = w & 1;
    const int m0 = blockIdx.y * 128, n0 = blockIdx.x * 128;
    const ushort_t* Ab = A + (long)blockIdx.z * sA;
    const ushort_t* Bb = B + (long)blockIdx.z * sB;
    ushort_t*       Cb = C + (long)blockIdx.z * sC;

    const int srow = lane >> 2;
    const int scol = (lane & 3) * 8;

    f32x4 acc[4][4];
    #pragma unroll
    for (int m = 0; m < 4; ++m)
        #pragma unroll
        for (int n = 0; n < 4; ++n) acc[m][n] = (f32x4){0.f, 0.f, 0.f, 0.f};

    for (int k0 = 0; k0 < K; k0 += BK) {
        #pragma unroll
        for (int i = 0; i < 2; ++i) {
            int r = w * 32 + i * 16;
            gload_lds16(Ab + (long)(m0 + r + srow) * lda + k0 + scol, &As[r * BK]);
            gload_lds16(Bb + (long)(n0 + r + srow) * ldb + k0 + scol, &Bs[r * BK]);
        }
        __syncthreads();

        bf16x8 af[4], bfv[4];
        #pragma unroll
        for (int m = 0; m < 4; ++m)
            af[m] = *(const bf16x8*)&As[(wr * 64 + m * 16 + l15) * BK + l4 * 8];
        #pragma unroll
        for (int n = 0; n < 4; ++n)
            bfv[n] = *(const bf16x8*)&Bs[(wc * 64 + n * 16 + l15) * BK + l4 * 8];
        #pragma unroll
        for (int m = 0; m < 4; ++m)
            #pragma unroll
            for (int n = 0; n < 4; ++n)
                acc[m][n] = __builtin_amdgcn_mfma_f32_16x16x32_bf16(af[m], bfv[n], acc[m][n], 0, 0, 0);
        __syncthreads();
    }

    #pragma unroll
    for (int m = 0; m < 4; ++m)
        #pragma unroll
        for (int j = 0; j < 4; ++j) {
            long row = m0 + wr * 64 + m * 16 + l4 * 4 + j;
            #pragma unroll
            for (int n = 0; n < 4; ++n)
                Cb[row * ldc + n0 + wc * 64 + n * 16 + l15] = f2bf(acc[m][n][j]);
        }
}

// ---------------------------------------------------------------------------
// Tiled f32 GEMM (kept only for c_kr: M=4096, N=64, K=2048)
// ---------------------------------------------------------------------------
template<int BM, int BN, int BK, int TM, int TN, bool BTRANS, typename OutT>
__global__ __launch_bounds__(256) void gemm_f32(
    const float* __restrict__ A, const float* __restrict__ Bp, OutT* __restrict__ Cp,
    int K, int lda, int ldb, int ldc, long sA, long sB, long sC)
{
    static_assert(BK == 16, "loader assumes BK=16");
    static_assert((BM / TM) * (BN / TN) == 256, "256 threads");
    const float* Ab = A  + (long)blockIdx.z * sA;
    const float* Bx = Bp + (long)blockIdx.z * sB;
    OutT*        Cb = Cp + (long)blockIdx.z * sC;

    __shared__ float As[BK][BM + 4];
    __shared__ float Bs[BK][BN + 4];

    const int tid = threadIdx.x;
    const int tx = tid % (BN / TN);
    const int ty = tid / (BN / TN);
    const int m0 = blockIdx.y * BM, n0 = blockIdx.x * BN;

    float acc[TM][TN] = {};

    for (int k0 = 0; k0 < K; k0 += BK) {
        #pragma unroll
        for (int i = 0; i < BM * BK / 1024; ++i) {
            int chunk = tid + i * 256;
            int row = chunk >> 2;
            int kq  = chunk & 3;
            float4 v = *(const float4*)&Ab[(long)(m0 + row) * lda + k0 + kq * 4];
            As[kq * 4 + 0][row] = v.x; As[kq * 4 + 1][row] = v.y;
            As[kq * 4 + 2][row] = v.z; As[kq * 4 + 3][row] = v.w;
        }
        if constexpr (BTRANS) {
            #pragma unroll
            for (int i = 0; i < BN * BK / 1024; ++i) {
                int chunk = tid + i * 256;
                int row = chunk >> 2;
                int kq  = chunk & 3;
                float4 v = *(const float4*)&Bx[(long)(n0 + row) * ldb + k0 + kq * 4];
                Bs[kq * 4 + 0][row] = v.x; Bs[kq * 4 + 1][row] = v.y;
                Bs[kq * 4 + 2][row] = v.z; Bs[kq * 4 + 3][row] = v.w;
            }
        } else {
            #pragma unroll
            for (int i = 0; i < BN * BK / 1024; ++i) {
                int chunk = tid + i * 256;
                int krow = chunk / (BN / 4);
                int nq   = chunk % (BN / 4);
                *(float4*)&Bs[krow][nq * 4] =
                    *(const float4*)&Bx[(long)(k0 + krow) * ldb + n0 + nq * 4];
            }
        }
        __syncthreads();

        #pragma unroll
        for (int kk = 0; kk < BK; ++kk) {
            float a[TM], bv[TN];
            #pragma unroll
            for (int i = 0; i < TM; ++i) a[i] = As[kk][ty * TM + i];
            #pragma unroll
            for (int j = 0; j < TN; ++j) {
                int half = j / (TN / 2), jj = j % (TN / 2);
                bv[j] = Bs[kk][half * (BN / 2) + tx * (TN / 2) + jj];
            }
            #pragma unroll
            for (int i = 0; i < TM; ++i)
                #pragma unroll
                for (int j = 0; j < TN; ++j)
                    acc[i][j] += a[i] * bv[j];
        }
        __syncthreads();
    }

    #pragma unroll
    for (int i = 0; i < TM; ++i) {
        long rbase = (long)(m0 + ty * TM + i) * ldc + n0;
        #pragma unroll
        for (int half = 0; half < 2; ++half) {
            long cbase = rbase + half * (BN / 2) + tx * (TN / 2);
            #pragma unroll
            for (int jj = 0; jj < TN / 2; ++jj)
                Cb[cbase + jj] = acc[i][half * (TN / 2) + jj];
        }
    }
}

// ---------------------------------------------------------------------------
// RoPE kernels
// ---------------------------------------------------------------------------
__global__ void rope_kr_kernel(const float* __restrict__ krb, ushort_t* __restrict__ kfull,
                               const float* __restrict__ cosT, const float* __restrict__ sinT) {
    int p = blockIdx.x * 256 + threadIdx.x;          // BT*32 pairs
    if (p >= BT * 32) return;
    int bt = p >> 5, i = p & 31;
    int t = bt & (Tn - 1);
    float c = cosT[t * 32 + i], s = sinT[t * 32 + i];
    float re = krb[bt * 64 + 2 * i], im = krb[bt * 64 + 2 * i + 1];
    float o0 = re * c - im * s, o1 = re * s + im * c;
    uint_t u = (uint_t)f2bf(o0) | ((uint_t)f2bf(o1) << 16);
    *(uint_t*)&kfull[(long)bt * 576 + 512 + 2 * i] = u;
}

__global__ void rope_qr_kernel(const ushort_t* __restrict__ qrb, ushort_t* __restrict__ qfull,
                               const float* __restrict__ cosT, const float* __restrict__ sinT) {
    int p = blockIdx.x * 256 + threadIdx.x;          // BT*NH*32 pairs
    if (p >= BT * 512) return;
    int bt = p >> 9, rem = p & 511;
    int hh = rem >> 5, i = rem & 31;
    int t = bt & (Tn - 1);
    float c = cosT[t * 32 + i], s = sinT[t * 32 + i];
    uint_t u = *(const uint_t*)&qrb[(long)bt * 1024 + hh * 64 + 2 * i];
    float re = __uint_as_float(u << 16);
    float im = __uint_as_float(u & 0xffff0000u);
    float o0 = re * c - im * s, o1 = re * s + im * c;
    uint_t o = (uint_t)f2bf(o0) | ((uint_t)f2bf(o1) << 16);
    *(uint_t*)&qfull[((long)hh * BT + bt) * 576 + 512 + 2 * i] = o;
}

// ---------------------------------------------------------------------------
// Transpose c_kv (cols 0..511 of kfull) into ckvT[b][c][t] (bf16)
// ---------------------------------------------------------------------------
__global__ void transpose_ckv(const ushort_t* __restrict__ kfull, ushort_t* __restrict__ ckvT) {
    int idx = blockIdx.x * 256 + threadIdx.x;        // 4*128*512
    int c = idx & 511, rest = idx >> 9;
    int t8 = rest & 127, b = rest >> 7;
    ushort_t v[8];
    #pragma unroll
    for (int j = 0; j < 8; ++j)
        v[j] = kfull[((long)b * Tn + t8 * 8 + j) * 576 + c];
    *(uint4*)&ckvT[((long)b * 512 + c) * Tn + t8 * 8] = *(const uint4*)v;
}

// ---------------------------------------------------------------------------
// Flash MLA v3: ONE WAVE per block (16 q-rows, 1 head, 1 batch). No barriers,
// no K/V LDS staging (K,V are L2-resident; fragments loaded straight from
// global). Swapped S^T = mfma(K_frag, Q_frag): lane owns ONE q-row (q=l15),
// kv = (l>>4)*4+reg (+16) -> softmax = 7 in-reg fmax + 2 shfl; m,l,corr are
// per-lane scalars. P round-trips a per-wave LDS buffer P_s[q][kv]. PV:
// y^T[c][q] = mfma(Vt_frag, P_frag) with Vt from ckvT. Epilogue: y^T -> LDS
// -> B-frags, out^T = mfma(Mt_frag, y_frag), coalesced dwordx4 stores.
// ---------------------------------------------------------------------------
__global__ __launch_bounds__(64, 2) void flash_mla3(
    const ushort_t* __restrict__ qfull,   // [NH][BT][576]
    const ushort_t* __restrict__ kfull,   // [BT][576]
    const ushort_t* __restrict__ ckvT,    // [B][512][1024]
    const ushort_t* __restrict__ Mtb,     // [2048][512]
    float*          __restrict__ out)     // [BT][2048]
{
    constexpr int PS = 40;    // P_s row stride (bf16): 80B rows -> <=2-way banks
    constexpr int YS = 520;   // y_s row stride: 1040B = 4 mod 32 banks

    __shared__ ushort_t y_s[16 * YS];     // 16640 B (epilogue only)
    __shared__ ushort_t P_s[16 * PS];     // 1280 B  (main loop)

    const int lane = threadIdx.x;
    const int l15 = lane & 15, l4 = lane >> 4;
    const int q0 = blockIdx.x * 16;
    const int h  = blockIdx.y;
    const int b  = blockIdx.z;
    const long bt0 = (long)b * Tn + q0;
    const int q = q0 + l15;               // this lane's q-row

    // Q B-frags (col=l15 -> q-row, k=(l4)*8+j -> channel)
    bf16x8 qf[18];
    {
        const ushort_t* qrow = qfull + ((long)h * BT + bt0 + l15) * 576 + l4 * 8;
        #pragma unroll
        for (int ks = 0; ks < 18; ++ks)
            qf[ks] = *(const bf16x8*)(qrow + ks * 32);
    }

    f32x4 y[32];                          // y^T: c = n*16 + l4*4+j, q = l15
    #pragma unroll
    for (int n = 0; n < 32; ++n) y[n] = (f32x4){0.f, 0.f, 0.f, 0.f};
    float mrun = -INFINITY, lrun = 0.f;

    const float SCL = ATT_SCALE * LOG2E;
    const int niter = (q0 + 47) / 32;     // ceil((q0+16)/32)

    const ushort_t* kb_base = kfull + (long)b * Tn * 576 + l4 * 8;
    const ushort_t* v_base  = ckvT  + (long)b * 512 * Tn + l4 * 8;

    for (int it = 0; it < niter; ++it) {
        const int s0 = it * 32;

        // ---- S^T phase: A = K-frags from global (L2), B = Q in regs
        const ushort_t* k0p = kb_base + (long)(s0 + l15) * 576;
        const ushort_t* k1p = k0p + 16 * 576;
        f32x4 sa0 = (f32x4){0.f,0.f,0.f,0.f}, sa1 = (f32x4){0.f,0.f,0.f,0.f};
        #pragma unroll
        for (int ks = 0; ks < 18; ++ks) {
            bf16x8 kb0 = *(const bf16x8*)(k0p + ks * 32);
            bf16x8 kb1 = *(const bf16x8*)(k1p + ks * 32);
            sa0 = __builtin_amdgcn_mfma_f32_16x16x32_bf16(kb0, qf[ks], sa0, 0, 0, 0);
            sa1 = __builtin_amdgcn_mfma_f32_16x16x32_bf16(kb1, qf[ks], sa1, 0, 0, 0);
        }

        // ---- scale + causal mask (lane's scores: kv = s0 + l4*4+j, +16)
        float sv[8];
        const bool maskp = (s0 + 32 > q0);
        #pragma unroll
        for (int j = 0; j < 4; ++j) {
            float a0 = sa0[j] * SCL;
            float a1 = sa1[j] * SCL;
            if (maskp) {
                int kv = s0 + l4 * 4 + j;
                if (kv > q)      a0 = -INFINITY;
                if (kv + 16 > q) a1 = -INFINITY;
            }
            sv[j] = a0; sv[4 + j] = a1;
        }

        // ---- online softmax: 7 in-reg max + 2 shfl; sum likewise
        float tm = fmaxf(fmaxf(fmaxf(sv[0], sv[1]), fmaxf(sv[2], sv[3])),
                         fmaxf(fmaxf(sv[4], sv[5]), fmaxf(sv[6], sv[7])));
        tm = fmaxf(tm, __shfl_xor(tm, 16));
        tm = fmaxf(tm, __shfl_xor(tm, 32));
        const float mnew = fmaxf(mrun, tm);
        const float corr = exp2f(mrun - mnew);
        float p[8];
        float rs = 0.f;
        #pragma unroll
        for (int j = 0; j < 8; ++j) { p[j] = exp2f(sv[j] - mnew); rs += p[j]; }
        rs += __shfl_xor(rs, 16);
        rs += __shfl_xor(rs, 32);
        lrun = lrun * corr + rs;
        mrun = mnew;

        // ---- P -> per-wave LDS: P_s[q=l15][kv]
        {
            ushort_t pk0[4] = {f2bf(p[0]), f2bf(p[1]), f2bf(p[2]), f2bf(p[3])};
            ushort_t pk1[4] = {f2bf(p[4]), f2bf(p[5]), f2bf(p[6]), f2bf(p[7])};
            *(uint2*)&P_s[l15 * PS + l4 * 4]      = *(const uint2*)pk0;
            *(uint2*)&P_s[l15 * PS + 16 + l4 * 4] = *(const uint2*)pk1;
        }

        // ---- rescale y (corr is a per-lane scalar!)
        #pragma unroll
        for (int n = 0; n < 32; ++n) {
            y[n][0] *= corr; y[n][1] *= corr; y[n][2] *= corr; y[n][3] *= corr;
        }

        // ---- PV: A = Vt-frags from ckvT (L2), B = P from LDS
        bf16x8 pb = *(const bf16x8*)&P_s[l15 * PS + l4 * 8];
        const ushort_t* vp = v_base + s0;
        #pragma unroll
        for (int n = 0; n < 32; ++n) {
            bf16x8 vb = *(const bf16x8*)(vp + (long)(n * 16 + l15) * Tn);
            y[n] = __builtin_amdgcn_mfma_f32_16x16x32_bf16(vb, pb, y[n], 0, 0, 0);
        }
    }

    // ---- epilogue: y^T -> LDS (bf16, normalized), project through Mt
    const float inv = 1.f / lrun;
    #pragma unroll
    for (int n = 0; n < 32; ++n) {
        ushort_t pk[4] = {f2bf(y[n][0] * inv), f2bf(y[n][1] * inv),
                          f2bf(y[n][2] * inv), f2bf(y[n][3] * inv)};
        *(uint2*)&y_s[l15 * YS + n * 16 + l4 * 4] = *(const uint2*)pk;
    }

    bf16x8 ya[16];
    #pragma unroll
    for (int ks = 0; ks < 16; ++ks)
        ya[ks] = *(const bf16x8*)&y_s[l15 * YS + ks * 32 + l4 * 8];

    const ushort_t* mtb = Mtb + (long)h * 128 * 512;
    #pragma unroll
    for (int nt = 0; nt < 8; ++nt) {
        f32x4 acc = (f32x4){0.f, 0.f, 0.f, 0.f};
        const ushort_t* mrow = mtb + (long)(nt * 16 + l15) * 512 + l4 * 8;
        #pragma unroll
        for (int ks = 0; ks < 16; ++ks) {
            bf16x8 mb = *(const bf16x8*)(mrow + ks * 32);
            acc = __builtin_amdgcn_mfma_f32_16x16x32_bf16(mb, ya[ks], acc, 0, 0, 0);
        }
        // D: row = d = nt*16 + l4*4+j, col = q = l15 -> 16B coalesced store
        *(f32x4*)&out[(bt0 + l15) * Cn + h * 128 + nt * 16 + l4 * 4] = acc;
    }
}

// ---------------------------------------------------------------------------
extern "C" void kernel_launch(void* const* d_in, const int* in_sizes, int n_in,
                              void* d_out, int out_size, void* d_ws, size_t ws_size,
                              hipStream_t stream)
{
    (void)in_sizes; (void)n_in; (void)out_size; (void)ws_size;
    const float* x     = (const float*)d_in[0];
    const float* cosT  = (const float*)d_in[1];
    const float* sinT  = (const float*)d_in[2];
    const float* W_dq  = (const float*)d_in[3];   // [1536][2048]
    const float* W_uq  = (const float*)d_in[4];   // flat [2048*1536]
    const float* W_dkv = (const float*)d_in[5];   // [512][2048]
    const float* W_uk  = (const float*)d_in[6];   // [2048][512]
    const float* W_uv  = (const float*)d_in[7];   // [2048][512]
    const float* W_qr  = (const float*)d_in[8];   // [1024][1536]
    const float* W_kr  = (const float*)d_in[9];   // [64][2048]
    const float* W_o   = (const float*)d_in[10];  // [2048][2048]
    float* out = (float*)d_out;

    // workspace layout (~181 MB, all bf16 except krb)
    ushort_t* xb     = (ushort_t*)d_ws;                 // 8388608
    ushort_t* Wdq_b  = xb     + 8388608;                // 3145728
    ushort_t* Wuq_b  = Wdq_b  + 3145728;                // 3145728
    ushort_t* Wqr_b  = Wuq_b  + 3145728;                // 1572864
    ushort_t* Wo_b   = Wqr_b  + 1572864;                // 4194304
    ushort_t* Wdkv_b = Wo_b   + 4194304;                // 1048576
    ushort_t* WukT_b = Wdkv_b + 1048576;                // 1048576  [512][2048]
    ushort_t* WuvT_b = WukT_b + 1048576;                // 1048576  [512][2048]
    ushort_t* cq_b   = WuvT_b + 1048576;                // 6291456  [4096][1536]
    ushort_t* qr_b   = cq_b   + 6291456;                // 4194304  [4096][1024]
    ushort_t* keffT  = qr_b   + 4194304;                // 12582912 [16][512][1536]
    ushort_t* Mtb    = keffT  + 12582912;               // 1048576  [2048][512]
    ushort_t* qfull  = Mtb    + 1048576;                // 37748736 [16][4096][576]
    ushort_t* kfull  = qfull  + 37748736;               // 2359296  [4096][576]
    ushort_t* ckvT   = kfull  + 2359296;                // 2097152  [4][512][1024]
    float*    krb    = (float*)(ckvT + 2097152);        // [4096][64] f32

    dim3 blk(256, 1, 1);

    // ---- bf16 conversions ----
    cvt_bf16<<<dim3(4096), blk, 0, stream>>>(x, xb);
    cvt_bf16<<<dim3(1536), blk, 0, stream>>>(W_dq, Wdq_b);
    cvt_bf16<<<dim3(1536), blk, 0, stream>>>(W_uq, Wuq_b);
    cvt_bf16<<<dim3(768),  blk, 0, stream>>>(W_qr, Wqr_b);
    cvt_bf16<<<dim3(2048), blk, 0, stream>>>(W_o, Wo_b);
    cvt_bf16<<<dim3(512),  blk, 0, stream>>>(W_dkv, Wdkv_b);
    transcvt_bf16<<<dim3(8, 32, 2), blk, 0, stream>>>(W_uk, WukT_b, W_uv, WuvT_b);

    // ---- MFMA GEMMs (all NT) ----
    gemm_bf16<<<dim3(12, 32, 1), blk, 0, stream>>>(
        xb, Wdq_b, cq_b, Cn, Cn, Cn, NLQ, 0, 0, 0);
    gemm_bf16<<<dim3(4, 32, 1), blk, 0, stream>>>(
        xb, Wdkv_b, kfull, Cn, Cn, Cn, 576, 0, 0, 0);
    gemm_f32<64,64,16,4,4,true,float><<<dim3(1, BT/64, 1), blk, 0, stream>>>(
        x, W_kr, krb, Cn, Cn, Cn, DHR, 0, 0, 0);
    rope_kr_kernel<<<dim3(BT*32/256), blk, 0, stream>>>(krb, kfull, cosT, sinT);
    gemm_bf16<<<dim3(8, 32, 1), blk, 0, stream>>>(
        cq_b, Wqr_b, qr_b, NLQ, NLQ, NLQ, NH*DHR, 0, 0, 0);
    rope_qr_kernel<<<dim3(BT*512/256), blk, 0, stream>>>(qr_b, qfull, cosT, sinT);
    gemm_bf16<<<dim3(12, 4, NH), blk, 0, stream>>>(
        WukT_b, Wuq_b, keffT, HS, Cn, Cn, NLQ, 128, 128, (long)NLKV*NLQ);
    gemm_bf16<<<dim3(4, 16, 1), blk, 0, stream>>>(
        Wo_b, WuvT_b, Mtb, Cn, Cn, Cn, NLKV, 0, 0, 0);
    gemm_bf16<<<dim3(4, 32, NH), blk, 0, stream>>>(
        cq_b, keffT, qfull, NLQ, NLQ, NLQ, 576,
        0, (long)NLKV*NLQ, (long)BT*576);
    transpose_ckv<<<dim3(Bn*512*128/256), blk, 0, stream>>>(kfull, ckvT);
    // flash attention + fused output projection (1 wave / block)
    flash_mla3<<<dim3(Tn/16, NH, Bn), dim3(64,1,1), 0, stream>>>(qfull, kfull, ckvT, Mtb, out);
}

// Round 5
// 1312.936 us; speedup vs baseline: 1.0814x; 1.0814x over previous
//
#include <hip/hip_runtime.h>
#include <type_traits>

typedef unsigned short ushort_t;
typedef unsigned int   uint_t;
typedef __attribute__((ext_vector_type(8))) short bf16x8;
typedef __attribute__((ext_vector_type(4))) float f32x4;

constexpr int Bn = 4, Tn = 1024, Cn = 2048, NH = 16, HS = 128;
constexpr int NLQ = 1536, NLKV = 512, DHR = 64;
constexpr int BT = Bn * Tn;
constexpr float ATT_SCALE = 0.07216878364870323f; // 1/sqrt(192)
constexpr float LOG2E = 1.4426950408889634f;

__device__ __forceinline__ ushort_t f2bf(float f) {
    uint_t u = __float_as_uint(f);
    u += 0x7fffu + ((u >> 16) & 1u);   // RNE
    return (ushort_t)(u >> 16);
}

__device__ __forceinline__ void gload_lds16(const void* g, void* l) {
    __builtin_amdgcn_global_load_lds(
        (__attribute__((address_space(1))) void*)g,
        (__attribute__((address_space(3))) void*)l, 16, 0, 0);
}

// ---------------------------------------------------------------------------
// f32 -> bf16 conversion (vectorized, 8/thread). n must be multiple of 2048.
// ---------------------------------------------------------------------------
__global__ void cvt_bf16(const float* __restrict__ in, ushort_t* __restrict__ out) {
    long i = ((long)blockIdx.x * 256 + threadIdx.x) * 8;
    float4 a = *(const float4*)&in[i];
    float4 b = *(const float4*)&in[i + 4];
    ushort_t p[8] = {f2bf(a.x), f2bf(a.y), f2bf(a.z), f2bf(a.w),
                     f2bf(b.x), f2bf(b.y), f2bf(b.z), f2bf(b.w)};
    *(uint4*)&out[i] = *(const uint4*)p;
}

// ---------------------------------------------------------------------------
// Transpose+convert [2048][512] f32 -> [512][2048] bf16 (z=0: W_uk, z=1: W_uv)
// ---------------------------------------------------------------------------
__global__ __launch_bounds__(256) void transcvt_bf16(
    const float* __restrict__ A, ushort_t* __restrict__ At,
    const float* __restrict__ Bp, ushort_t* __restrict__ Bt)
{
    __shared__ float tile[64][65];
    const float* in = blockIdx.z ? Bp : A;
    ushort_t* out   = blockIdx.z ? Bt : At;
    const int k0 = blockIdx.x * 64, c0 = blockIdx.y * 64;
    const int t = threadIdx.x;
    #pragma unroll
    for (int i = 0; i < 4; ++i) {
        int idx = t + i * 256;
        int r = idx >> 4, c4 = idx & 15;
        float4 v = *(const float4*)&in[(long)(c0 + r) * 512 + k0 + c4 * 4];
        tile[r][c4 * 4 + 0] = v.x; tile[r][c4 * 4 + 1] = v.y;
        tile[r][c4 * 4 + 2] = v.z; tile[r][c4 * 4 + 3] = v.w;
    }
    __syncthreads();
    #pragma unroll
    for (int i = 0; i < 4; ++i) {
        int idx = t + i * 256;
        int kr = idx >> 4, c4 = idx & 15;
        ushort_t p[4];
        #pragma unroll
        for (int j = 0; j < 4; ++j) p[j] = f2bf(tile[c4 * 4 + j][kr]);
        *(uint2*)&out[(long)(k0 + kr) * 2048 + c0 + c4 * 4] = *(const uint2*)p;
    }
}

// ---------------------------------------------------------------------------
// bf16 MFMA GEMM (m97 structure), NT, bf16 out.
// ---------------------------------------------------------------------------
__global__ __launch_bounds__(256, 2) void gemm_bf16(
    const ushort_t* __restrict__ A, const ushort_t* __restrict__ B,
    ushort_t* __restrict__ C,
    int K, int lda, int ldb, int ldc, long sA, long sB, long sC)
{
    constexpr int BK = 32;
    __shared__ ushort_t As[128 * BK];
    __shared__ ushort_t Bs[128 * BK];

    const int tid  = threadIdx.x;
    const int lane = tid & 63;
    const int w    = tid >> 6;
    const int l15 = lane & 15, l4 = lane >> 4;
    const int wr = w >> 1, wc = w & 1;
    const int m0 = blockIdx.y * 128, n0 = blockIdx.x * 128;
    const ushort_t* Ab = A + (long)blockIdx.z * sA;
    const ushort_t* Bb = B + (long)blockIdx.z * sB;
    ushort_t*       Cb = C + (long)blockIdx.z * sC;

    const int srow = lane >> 2;
    const int scol = (lane & 3) * 8;

    f32x4 acc[4][4];
    #pragma unroll
    for (int m = 0; m < 4; ++m)
        #pragma unroll
        for (int n = 0; n < 4; ++n) acc[m][n] = (f32x4){0.f, 0.f, 0.f, 0.f};

    for (int k0 = 0; k0 < K; k0 += BK) {
        #pragma unroll
        for (int i = 0; i < 2; ++i) {
            int r = w * 32 + i * 16;
            gload_lds16(Ab + (long)(m0 + r + srow) * lda + k0 + scol, &As[r * BK]);
            gload_lds16(Bb + (long)(n0 + r + srow) * ldb + k0 + scol, &Bs[r * BK]);
        }
        __syncthreads();

        bf16x8 af[4], bfv[4];
        #pragma unroll
        for (int m = 0; m < 4; ++m)
            af[m] = *(const bf16x8*)&As[(wr * 64 + m * 16 + l15) * BK + l4 * 8];
        #pragma unroll
        for (int n = 0; n < 4; ++n)
            bfv[n] = *(const bf16x8*)&Bs[(wc * 64 + n * 16 + l15) * BK + l4 * 8];
        #pragma unroll
        for (int m = 0; m < 4; ++m)
            #pragma unroll
            for (int n = 0; n < 4; ++n)
                acc[m][n] = __builtin_amdgcn_mfma_f32_16x16x32_bf16(af[m], bfv[n], acc[m][n], 0, 0, 0);
        __syncthreads();
    }

    #pragma unroll
    for (int m = 0; m < 4; ++m)
        #pragma unroll
        for (int j = 0; j < 4; ++j) {
            long row = m0 + wr * 64 + m * 16 + l4 * 4 + j;
            #pragma unroll
            for (int n = 0; n < 4; ++n)
                Cb[row * ldc + n0 + wc * 64 + n * 16 + l15] = f2bf(acc[m][n][j]);
        }
}

// ---------------------------------------------------------------------------
// Tiled f32 GEMM (kept only for c_kr: M=4096, N=64, K=2048)
// ---------------------------------------------------------------------------
template<int BM, int BN, int BK, int TM, int TN, bool BTRANS, typename OutT>
__global__ __launch_bounds__(256) void gemm_f32(
    const float* __restrict__ A, const float* __restrict__ Bp, OutT* __restrict__ Cp,
    int K, int lda, int ldb, int ldc, long sA, long sB, long sC)
{
    static_assert(BK == 16, "loader assumes BK=16");
    static_assert((BM / TM) * (BN / TN) == 256, "256 threads");
    const float* Ab = A  + (long)blockIdx.z * sA;
    const float* Bx = Bp + (long)blockIdx.z * sB;
    OutT*        Cb = Cp + (long)blockIdx.z * sC;

    __shared__ float As[BK][BM + 4];
    __shared__ float Bs[BK][BN + 4];

    const int tid = threadIdx.x;
    const int tx = tid % (BN / TN);
    const int ty = tid / (BN / TN);
    const int m0 = blockIdx.y * BM, n0 = blockIdx.x * BN;

    float acc[TM][TN] = {};

    for (int k0 = 0; k0 < K; k0 += BK) {
        #pragma unroll
        for (int i = 0; i < BM * BK / 1024; ++i) {
            int chunk = tid + i * 256;
            int row = chunk >> 2;
            int kq  = chunk & 3;
            float4 v = *(const float4*)&Ab[(long)(m0 + row) * lda + k0 + kq * 4];
            As[kq * 4 + 0][row] = v.x; As[kq * 4 + 1][row] = v.y;
            As[kq * 4 + 2][row] = v.z; As[kq * 4 + 3][row] = v.w;
        }
        if constexpr (BTRANS) {
            #pragma unroll
            for (int i = 0; i < BN * BK / 1024; ++i) {
                int chunk = tid + i * 256;
                int row = chunk >> 2;
                int kq  = chunk & 3;
                float4 v = *(const float4*)&Bx[(long)(n0 + row) * ldb + k0 + kq * 4];
                Bs[kq * 4 + 0][row] = v.x; Bs[kq * 4 + 1][row] = v.y;
                Bs[kq * 4 + 2][row] = v.z; Bs[kq * 4 + 3][row] = v.w;
            }
        } else {
            #pragma unroll
            for (int i = 0; i < BN * BK / 1024; ++i) {
                int chunk = tid + i * 256;
                int krow = chunk / (BN / 4);
                int nq   = chunk % (BN / 4);
                *(float4*)&Bs[krow][nq * 4] =
                    *(const float4*)&Bx[(long)(k0 + krow) * ldb + n0 + nq * 4];
            }
        }
        __syncthreads();

        #pragma unroll
        for (int kk = 0; kk < BK; ++kk) {
            float a[TM], bv[TN];
            #pragma unroll
            for (int i = 0; i < TM; ++i) a[i] = As[kk][ty * TM + i];
            #pragma unroll
            for (int j = 0; j < TN; ++j) {
                int half = j / (TN / 2), jj = j % (TN / 2);
                bv[j] = Bs[kk][half * (BN / 2) + tx * (TN / 2) + jj];
            }
            #pragma unroll
            for (int i = 0; i < TM; ++i)
                #pragma unroll
                for (int j = 0; j < TN; ++j)
                    acc[i][j] += a[i] * bv[j];
        }
        __syncthreads();
    }

    #pragma unroll
    for (int i = 0; i < TM; ++i) {
        long rbase = (long)(m0 + ty * TM + i) * ldc + n0;
        #pragma unroll
        for (int half = 0; half < 2; ++half) {
            long cbase = rbase + half * (BN / 2) + tx * (TN / 2);
            #pragma unroll
            for (int jj = 0; jj < TN / 2; ++jj)
                Cb[cbase + jj] = acc[i][half * (TN / 2) + jj];
        }
    }
}

// ---------------------------------------------------------------------------
// RoPE kernels
// ---------------------------------------------------------------------------
__global__ void rope_kr_kernel(const float* __restrict__ krb, ushort_t* __restrict__ kfull,
                               const float* __restrict__ cosT, const float* __restrict__ sinT) {
    int p = blockIdx.x * 256 + threadIdx.x;          // BT*32 pairs
    if (p >= BT * 32) return;
    int bt = p >> 5, i = p & 31;
    int t = bt & (Tn - 1);
    float c = cosT[t * 32 + i], s = sinT[t * 32 + i];
    float re = krb[bt * 64 + 2 * i], im = krb[bt * 64 + 2 * i + 1];
    float o0 = re * c - im * s, o1 = re * s + im * c;
    uint_t u = (uint_t)f2bf(o0) | ((uint_t)f2bf(o1) << 16);
    *(uint_t*)&kfull[(long)bt * 576 + 512 + 2 * i] = u;
}

__global__ void rope_qr_kernel(const ushort_t* __restrict__ qrb, ushort_t* __restrict__ qfull,
                               const float* __restrict__ cosT, const float* __restrict__ sinT) {
    int p = blockIdx.x * 256 + threadIdx.x;          // BT*NH*32 pairs
    if (p >= BT * 512) return;
    int bt = p >> 9, rem = p & 511;
    int hh = rem >> 5, i = rem & 31;
    int t = bt & (Tn - 1);
    float c = cosT[t * 32 + i], s = sinT[t * 32 + i];
    uint_t u = *(const uint_t*)&qrb[(long)bt * 1024 + hh * 64 + 2 * i];
    float re = __uint_as_float(u << 16);
    float im = __uint_as_float(u & 0xffff0000u);
    float o0 = re * c - im * s, o1 = re * s + im * c;
    uint_t o = (uint_t)f2bf(o0) | ((uint_t)f2bf(o1) << 16);
    *(uint_t*)&qfull[((long)hh * BT + bt) * 576 + 512 + 2 * i] = o;
}

// ---------------------------------------------------------------------------
// Transpose c_kv (cols 0..511 of kfull) into ckvT[b][c][t] (bf16)
// ---------------------------------------------------------------------------
__global__ void transpose_ckv(const ushort_t* __restrict__ kfull, ushort_t* __restrict__ ckvT) {
    int idx = blockIdx.x * 256 + threadIdx.x;        // 4*128*512
    int c = idx & 511, rest = idx >> 9;
    int t8 = rest & 127, b = rest >> 7;
    ushort_t v[8];
    #pragma unroll
    for (int j = 0; j < 8; ++j)
        v[j] = kfull[((long)b * Tn + t8 * 8 + j) * 576 + c];
    *(uint4*)&ckvT[((long)b * 512 + c) * Tn + t8 * 8] = *(const uint4*)v;
}

// ---------------------------------------------------------------------------
// Flash MLA v4: 4 waves / 64 q-rows / head / batch.
// K tile (32 kv x 576 ch) double-buffered in LDS, chunked [18][32kv][32ch] so
// global_load_lds (wave-uniform base + lane*16) stages it linearly; tile t+1's
// loads issue at the TOP of iter t and drain at the single end-of-iter
// barrier (compiler emits vmcnt(0) there) -> staging hidden under compute.
// S^T = mfma(K_frag, Q_frag): lane owns one q-row (q=l15) -> softmax is
// 7 in-reg fmax + 2 shfl; m/l/corr per-lane scalars. P via per-wave LDS.
// PV: y^T = mfma(Vt_frag from ckvT (L2), P_frag). Epilogue: y^T -> LDS
// (reusing K buffers) -> out^T = mfma(Mt_frag, y_frag), coalesced stores.
// ---------------------------------------------------------------------------
__global__ __launch_bounds__(256, 2) void flash_mla4(
    const ushort_t* __restrict__ qfull,   // [NH][BT][576]
    const ushort_t* __restrict__ kfull,   // [BT][576]
    const ushort_t* __restrict__ ckvT,    // [B][512][1024]
    const ushort_t* __restrict__ Mtb,     // [2048][512]
    float*          __restrict__ out)     // [BT][2048]
{
    constexpr int PS = 40;    // P_s row stride (ushort)
    constexpr int YS = 520;   // y_s row stride (ushort), epilogue only

    __shared__ ushort_t Kbuf[2][18 * 1024];   // [buf][chunk(18)][kv(32)][ch(32)] = 73728 B
    __shared__ ushort_t P_s[4][16 * PS];      // 5120 B, per-wave

    const int tid  = threadIdx.x;
    const int lane = tid & 63;
    const int w    = tid >> 6;
    const int l15  = lane & 15, l4 = lane >> 4;
    const int t0 = (gridDim.x - 1 - blockIdx.x) * 64;   // heavy tiles first
    const int h  = blockIdx.y;
    const int b  = blockIdx.z;
    const long bt0 = (long)b * Tn + t0;
    const int q = t0 + w * 16 + l15;          // this lane's q-row (abs)

    const ushort_t* kf_b = kfull + (long)b * Tn * 576;
    const int srow = lane >> 2;               // 0..15 (staging row)
    const int soct = (lane & 3) * 8;          // staging col octet

    // Q B-frags in registers (col=q-row, k=(l4)*8+j)
    bf16x8 qf[18];
    {
        const ushort_t* qrow = qfull + ((long)h * BT + bt0 + w * 16 + l15) * 576 + l4 * 8;
        #pragma unroll
        for (int ks = 0; ks < 18; ++ks)
            qf[ks] = *(const bf16x8*)(qrow + ks * 32);
    }

    f32x4 y[32];                              // y^T: c = n*16 + l4*4+j, q-col = l15
    #pragma unroll
    for (int n = 0; n < 32; ++n) y[n] = (f32x4){0.f, 0.f, 0.f, 0.f};
    float mrun = -INFINITY, lrun = 0.f;

    const float SCL = ATT_SCALE * LOG2E;
    const int niter = t0 / 32 + 2;

    // prologue: stage tile 0 into Kbuf[0] (wave w: 9 of the 36 1KB-chunks)
    #pragma unroll
    for (int i = 0; i < 9; ++i) {
        int idx = w * 9 + i;                  // 0..35: chunk c = idx>>1, half = idx&1
        int c = idx >> 1, hf = idx & 1;
        gload_lds16(kf_b + (long)(hf * 16 + srow) * 576 + c * 32 + soct,
                    &Kbuf[0][c * 1024 + hf * 512 + lane * 8]);
    }
    __syncthreads();                          // vmcnt(0) emitted -> tile 0 ready

    int cur = 0;
    const ushort_t* v_base = ckvT + (long)b * 512 * Tn + l4 * 8;

    for (int it = 0; it < niter; ++it) {
        const int s0 = it * 32;

        // ---- issue next tile's staging (drains at this iter's end barrier)
        if (it + 1 < niter) {
            const ushort_t* src = kf_b + (long)(s0 + 32) * 576;
            #pragma unroll
            for (int i = 0; i < 9; ++i) {
                int idx = w * 9 + i;
                int c = idx >> 1, hf = idx & 1;
                gload_lds16(src + (long)(hf * 16 + srow) * 576 + c * 32 + soct,
                            &Kbuf[cur ^ 1][c * 1024 + hf * 512 + lane * 8]);
            }
        }

        // ---- S^T phase: A = K frags from LDS, B = Q regs
        const ushort_t* Kc = &Kbuf[cur][0];
        f32x4 sa0 = (f32x4){0.f,0.f,0.f,0.f}, sa1 = (f32x4){0.f,0.f,0.f,0.f};
        #pragma unroll
        for (int ks = 0; ks < 18; ++ks) {
            bf16x8 a0 = *(const bf16x8*)&Kc[ks * 1024 + l15 * 32 + l4 * 8];
            bf16x8 a1 = *(const bf16x8*)&Kc[ks * 1024 + 512 + l15 * 32 + l4 * 8];
            sa0 = __builtin_amdgcn_mfma_f32_16x16x32_bf16(a0, qf[ks], sa0, 0, 0, 0);
            sa1 = __builtin_amdgcn_mfma_f32_16x16x32_bf16(a1, qf[ks], sa1, 0, 0, 0);
        }

        // ---- scale + causal mask; lane's kv = s0 + l4*4+j (+16)
        float sv[8];
        const bool maskp = (s0 + 32 > t0 + w * 16);
        #pragma unroll
        for (int j = 0; j < 4; ++j) {
            float a0 = sa0[j] * SCL;
            float a1 = sa1[j] * SCL;
            if (maskp) {
                int kv = s0 + l4 * 4 + j;
                if (kv > q)      a0 = -INFINITY;
                if (kv + 16 > q) a1 = -INFINITY;
            }
            sv[j] = a0; sv[4 + j] = a1;
        }

        // ---- online softmax (per q-row = per lane-mod-16; reduce over l4 groups)
        float tm = fmaxf(fmaxf(fmaxf(sv[0], sv[1]), fmaxf(sv[2], sv[3])),
                         fmaxf(fmaxf(sv[4], sv[5]), fmaxf(sv[6], sv[7])));
        tm = fmaxf(tm, __shfl_xor(tm, 16));
        tm = fmaxf(tm, __shfl_xor(tm, 32));
        const float mnew = fmaxf(mrun, tm);
        const float corr = exp2f(mrun - mnew);
        float p[8];
        float rs = 0.f;
        #pragma unroll
        for (int j = 0; j < 8; ++j) { p[j] = exp2f(sv[j] - mnew); rs += p[j]; }
        rs += __shfl_xor(rs, 16);
        rs += __shfl_xor(rs, 32);
        lrun = lrun * corr + rs;
        mrun = mnew;

        // ---- P^T -> per-wave LDS: P_s[q=l15][kv]
        {
            ushort_t pk0[4] = {f2bf(p[0]), f2bf(p[1]), f2bf(p[2]), f2bf(p[3])};
            ushort_t pk1[4] = {f2bf(p[4]), f2bf(p[5]), f2bf(p[6]), f2bf(p[7])};
            *(uint2*)&P_s[w][l15 * PS + l4 * 4]      = *(const uint2*)pk0;
            *(uint2*)&P_s[w][l15 * PS + 16 + l4 * 4] = *(const uint2*)pk1;
        }

        // ---- rescale y (per-lane scalar)
        #pragma unroll
        for (int n = 0; n < 32; ++n) {
            y[n][0] *= corr; y[n][1] *= corr; y[n][2] *= corr; y[n][3] *= corr;
        }

        // ---- PV: A = Vt frags from ckvT (L2), B = P from LDS
        bf16x8 pb = *(const bf16x8*)&P_s[w][l15 * PS + l4 * 8];
        const ushort_t* vp = v_base + s0;
        #pragma unroll
        for (int n = 0; n < 32; ++n) {
            bf16x8 vb = *(const bf16x8*)(vp + (long)(n * 16 + l15) * Tn);
            y[n] = __builtin_amdgcn_mfma_f32_16x16x32_bf16(vb, pb, y[n], 0, 0, 0);
        }

        __syncthreads();    // drains glds (next tile ready) + fences buffers
        cur ^= 1;
    }

    // ---- epilogue: y^T -> LDS (reuse Kbuf; all waves past final barrier)
    const float inv = 1.f / lrun;
    ushort_t* yw = &Kbuf[0][0] + w * 16 * YS;     // per-wave 16 x YS (66.5KB total)
    #pragma unroll
    for (int n = 0; n < 32; ++n) {
        ushort_t pk[4] = {f2bf(y[n][0] * inv), f2bf(y[n][1] * inv),
                          f2bf(y[n][2] * inv), f2bf(y[n][3] * inv)};
        *(uint2*)&yw[l15 * YS + n * 16 + l4 * 4] = *(const uint2*)pk;
    }

    bf16x8 ya[16];
    #pragma unroll
    for (int ks = 0; ks < 16; ++ks)
        ya[ks] = *(const bf16x8*)&yw[l15 * YS + ks * 32 + l4 * 8];

    const ushort_t* mtb = Mtb + (long)h * 128 * 512;
    #pragma unroll
    for (int nt = 0; nt < 8; ++nt) {
        f32x4 acc = (f32x4){0.f, 0.f, 0.f, 0.f};
        const ushort_t* mrow = mtb + (long)(nt * 16 + l15) * 512 + l4 * 8;
        #pragma unroll
        for (int ks = 0; ks < 16; ++ks) {
            bf16x8 mb = *(const bf16x8*)(mrow + ks * 32);
            acc = __builtin_amdgcn_mfma_f32_16x16x32_bf16(mb, ya[ks], acc, 0, 0, 0);
        }
        *(f32x4*)&out[(bt0 + w * 16 + l15) * Cn + h * 128 + nt * 16 + l4 * 4] = acc;
    }
}

// ---------------------------------------------------------------------------
extern "C" void kernel_launch(void* const* d_in, const int* in_sizes, int n_in,
                              void* d_out, int out_size, void* d_ws, size_t ws_size,
                              hipStream_t stream)
{
    (void)in_sizes; (void)n_in; (void)out_size; (void)ws_size;
    const float* x     = (const float*)d_in[0];
    const float* cosT  = (const float*)d_in[1];
    const float* sinT  = (const float*)d_in[2];
    const float* W_dq  = (const float*)d_in[3];   // [1536][2048]
    const float* W_uq  = (const float*)d_in[4];   // flat [2048*1536]
    const float* W_dkv = (const float*)d_in[5];   // [512][2048]
    const float* W_uk  = (const float*)d_in[6];   // [2048][512]
    const float* W_uv  = (const float*)d_in[7];   // [2048][512]
    const float* W_qr  = (const float*)d_in[8];   // [1024][1536]
    const float* W_kr  = (const float*)d_in[9];   // [64][2048]
    const float* W_o   = (const float*)d_in[10];  // [2048][2048]
    float* out = (float*)d_out;

    // workspace layout (~181 MB, all bf16 except krb)
    ushort_t* xb     = (ushort_t*)d_ws;                 // 8388608
    ushort_t* Wdq_b  = xb     + 8388608;                // 3145728
    ushort_t* Wuq_b  = Wdq_b  + 3145728;                // 3145728
    ushort_t* Wqr_b  = Wuq_b  + 3145728;                // 1572864
    ushort_t* Wo_b   = Wqr_b  + 1572864;                // 4194304
    ushort_t* Wdkv_b = Wo_b   + 4194304;                // 1048576
    ushort_t* WukT_b = Wdkv_b + 1048576;                // 1048576  [512][2048]
    ushort_t* WuvT_b = WukT_b + 1048576;                // 1048576  [512][2048]
    ushort_t* cq_b   = WuvT_b + 1048576;                // 6291456  [4096][1536]
    ushort_t* qr_b   = cq_b   + 6291456;                // 4194304  [4096][1024]
    ushort_t* keffT  = qr_b   + 4194304;                // 12582912 [16][512][1536]
    ushort_t* Mtb    = keffT  + 12582912;               // 1048576  [2048][512]
    ushort_t* qfull  = Mtb    + 1048576;                // 37748736 [16][4096][576]
    ushort_t* kfull  = qfull  + 37748736;               // 2359296  [4096][576]
    ushort_t* ckvT   = kfull  + 2359296;                // 2097152  [4][512][1024]
    float*    krb    = (float*)(ckvT + 2097152);        // [4096][64] f32

    dim3 blk(256, 1, 1);

    // ---- bf16 conversions ----
    cvt_bf16<<<dim3(4096), blk, 0, stream>>>(x, xb);
    cvt_bf16<<<dim3(1536), blk, 0, stream>>>(W_dq, Wdq_b);
    cvt_bf16<<<dim3(1536), blk, 0, stream>>>(W_uq, Wuq_b);
    cvt_bf16<<<dim3(768),  blk, 0, stream>>>(W_qr, Wqr_b);
    cvt_bf16<<<dim3(2048), blk, 0, stream>>>(W_o, Wo_b);
    cvt_bf16<<<dim3(512),  blk, 0, stream>>>(W_dkv, Wdkv_b);
    transcvt_bf16<<<dim3(8, 32, 2), blk, 0, stream>>>(W_uk, WukT_b, W_uv, WuvT_b);

    // ---- MFMA GEMMs (all NT) ----
    gemm_bf16<<<dim3(12, 32, 1), blk, 0, stream>>>(
        xb, Wdq_b, cq_b, Cn, Cn, Cn, NLQ, 0, 0, 0);
    gemm_bf16<<<dim3(4, 32, 1), blk, 0, stream>>>(
        xb, Wdkv_b, kfull, Cn, Cn, Cn, 576, 0, 0, 0);
    gemm_f32<64,64,16,4,4,true,float><<<dim3(1, BT/64, 1), blk, 0, stream>>>(
        x, W_kr, krb, Cn, Cn, Cn, DHR, 0, 0, 0);
    rope_kr_kernel<<<dim3(BT*32/256), blk, 0, stream>>>(krb, kfull, cosT, sinT);
    gemm_bf16<<<dim3(8, 32, 1), blk, 0, stream>>>(
        cq_b, Wqr_b, qr_b, NLQ, NLQ, NLQ, NH*DHR, 0, 0, 0);
    rope_qr_kernel<<<dim3(BT*512/256), blk, 0, stream>>>(qr_b, qfull, cosT, sinT);
    gemm_bf16<<<dim3(12, 4, NH), blk, 0, stream>>>(
        WukT_b, Wuq_b, keffT, HS, Cn, Cn, NLQ, 128, 128, (long)NLKV*NLQ);
    gemm_bf16<<<dim3(4, 16, 1), blk, 0, stream>>>(
        Wo_b, WuvT_b, Mtb, Cn, Cn, Cn, NLKV, 0, 0, 0);
    gemm_bf16<<<dim3(4, 32, NH), blk, 0, stream>>>(
        cq_b, keffT, qfull, NLQ, NLQ, NLQ, 576,
        0, (long)NLKV*NLQ, (long)BT*576);
    transpose_ckv<<<dim3(Bn*512*128/256), blk, 0, stream>>>(kfull, ckvT);
    // flash attention + fused output projection (4 waves, dbuf LDS K)
    flash_mla4<<<dim3(Tn/64, NH, Bn), blk, 0, stream>>>(qfull, kfull, ckvT, Mtb, out);
}

// Round 7
// 748.636 us; speedup vs baseline: 1.8966x; 1.7538x over previous
//
#include <hip/hip_runtime.h>
#include <type_traits>

typedef unsigned short ushort_t;
typedef unsigned int   uint_t;
typedef __attribute__((ext_vector_type(8))) short bf16x8;
typedef __attribute__((ext_vector_type(4))) float f32x4;

constexpr int Bn = 4, Tn = 1024, Cn = 2048, NH = 16, HS = 128;
constexpr int NLQ = 1536, NLKV = 512, DHR = 64;
constexpr int BT = Bn * Tn;
constexpr float ATT_SCALE = 0.07216878364870323f; // 1/sqrt(192)
constexpr float LOG2E = 1.4426950408889634f;

__device__ __forceinline__ ushort_t f2bf(float f) {
    uint_t u = __float_as_uint(f);
    u += 0x7fffu + ((u >> 16) & 1u);   // RNE
    return (ushort_t)(u >> 16);
}

__device__ __forceinline__ void gload_lds16(const void* g, void* l) {
    __builtin_amdgcn_global_load_lds(
        (__attribute__((address_space(1))) void*)g,
        (__attribute__((address_space(3))) void*)l, 16, 0, 0);
}

// ---------------------------------------------------------------------------
// Shared 128x128 MFMA GEMM tile core (m97 structure): C128 = A128xK @ B128xK^T
// (NT). Offsets pre-folded into Ab/Bb/Cb. OutT = ushort (bf16) or f32.
// ---------------------------------------------------------------------------
template<typename OutT>
__device__ __forceinline__ void gemm_tile128(
    const ushort_t* __restrict__ Ab, int lda,
    const ushort_t* __restrict__ Bb, int ldb,
    OutT* __restrict__ Cb, int ldc, int K,
    ushort_t* As, ushort_t* Bs)
{
    constexpr int BK = 32;
    const int tid  = threadIdx.x;
    const int lane = tid & 63;
    const int w    = tid >> 6;
    const int l15 = lane & 15, l4 = lane >> 4;
    const int wr = w >> 1, wc = w & 1;
    const int srow = lane >> 2;          // 0..15
    const int scol = (lane & 3) * 8;     // octet within 32-col row

    f32x4 acc[4][4];
    #pragma unroll
    for (int m = 0; m < 4; ++m)
        #pragma unroll
        for (int n = 0; n < 4; ++n) acc[m][n] = (f32x4){0.f, 0.f, 0.f, 0.f};

    for (int k0 = 0; k0 < K; k0 += BK) {
        #pragma unroll
        for (int i = 0; i < 2; ++i) {
            int r = w * 32 + i * 16;
            gload_lds16(Ab + (long)(r + srow) * lda + k0 + scol, &As[r * BK]);
            gload_lds16(Bb + (long)(r + srow) * ldb + k0 + scol, &Bs[r * BK]);
        }
        __syncthreads();

        bf16x8 af[4], bfv[4];
        #pragma unroll
        for (int m = 0; m < 4; ++m)
            af[m] = *(const bf16x8*)&As[(wr * 64 + m * 16 + l15) * BK + l4 * 8];
        #pragma unroll
        for (int n = 0; n < 4; ++n)
            bfv[n] = *(const bf16x8*)&Bs[(wc * 64 + n * 16 + l15) * BK + l4 * 8];
        #pragma unroll
        for (int m = 0; m < 4; ++m)
            #pragma unroll
            for (int n = 0; n < 4; ++n)
                acc[m][n] = __builtin_amdgcn_mfma_f32_16x16x32_bf16(af[m], bfv[n], acc[m][n], 0, 0, 0);
        __syncthreads();
    }

    #pragma unroll
    for (int m = 0; m < 4; ++m)
        #pragma unroll
        for (int j = 0; j < 4; ++j) {
            long row = wr * 64 + m * 16 + l4 * 4 + j;
            #pragma unroll
            for (int n = 0; n < 4; ++n) {
                long col = wc * 64 + n * 16 + l15;
                if constexpr (std::is_same<OutT, float>::value)
                    Cb[row * ldc + col] = acc[m][n][j];
                else
                    Cb[row * ldc + col] = f2bf(acc[m][n][j]);
            }
        }
}

// Generic NT GEMM wrapper (batched via sA/sB/sC)
template<typename OutT>
__global__ __launch_bounds__(256, 2) void gemm_bf16(
    const ushort_t* __restrict__ A, const ushort_t* __restrict__ B,
    OutT* __restrict__ C,
    int K, int lda, int ldb, int ldc, long sA, long sB, long sC)
{
    __shared__ ushort_t As[128 * 32];
    __shared__ ushort_t Bs[128 * 32];
    const ushort_t* Ab = A + (long)blockIdx.z * sA + (long)blockIdx.y * 128 * lda;
    const ushort_t* Bb = B + (long)blockIdx.z * sB + (long)blockIdx.x * 128 * ldb;
    OutT*           Cb = C + (long)blockIdx.z * sC + (long)blockIdx.y * 128 * ldc
                           + (long)blockIdx.x * 128;
    gemm_tile128<OutT>(Ab, lda, Bb, ldb, Cb, ldc, K, As, Bs);
}

// ---------------------------------------------------------------------------
// Phase A: S lower-triangle tiles, triangle-PACKED: Spk[z'][x][128][128],
// x = ti*(ti+1)/2 + si. One z-group (16 z' = 4 heads x 4 batch) per launch.
// ---------------------------------------------------------------------------
__global__ __launch_bounds__(256, 2) void attn_s_gemm(
    const ushort_t* __restrict__ qfull, const ushort_t* __restrict__ kfull,
    ushort_t* __restrict__ Spk, int hbase)
{
    __shared__ ushort_t As[128 * 32];
    __shared__ ushort_t Bs[128 * 32];
    const int x = blockIdx.x;                 // 0..35 (packed tile idx)
    int ti = 0;
    while ((ti + 1) * (ti + 2) / 2 <= x) ++ti;  // uniform scalar (<=8 iters)
    const int si = x - ti * (ti + 1) / 2;
    const int z = blockIdx.z;                 // 0..15 local
    const int h = hbase + (z >> 2), b = z & 3;
    const ushort_t* Ab = qfull + ((long)h * 4096 + b * 1024 + ti * 128) * 576;
    const ushort_t* Bb = kfull + ((long)b * 1024 + si * 128) * 576;
    ushort_t* Cb = Spk + (long)z * 589824 + (long)x * 16384;
    gemm_tile128<ushort_t>(Ab, 576, Bb, 576, Cb, 128, 576, As, Bs);
}

// ---------------------------------------------------------------------------
// Phase B: in-place causal row softmax on packed S. One wave per q-row.
// grid = 16*1024/4 blocks.
// ---------------------------------------------------------------------------
__global__ __launch_bounds__(256) void attn_softmax(ushort_t* __restrict__ Spk)
{
    const int wid  = threadIdx.x >> 6;
    const int lane = threadIdx.x & 63;
    const int r = blockIdx.x * 4 + wid;              // 0..16383
    const int z = r >> 10, t = r & 1023;
    const int ti = t >> 7;
    const int nc = ti + 1;                           // valid 128-col chunks
    ushort_t* base = Spk + (long)z * 589824 + (long)(ti * (ti + 1) / 2) * 16384
                        + (t & 127) * 128;
    const float SCL = ATT_SCALE * LOG2E;

    float p0[8], p1[8];
    float mx = -INFINITY;
    #pragma unroll
    for (int c = 0; c < 8; ++c) {
        p0[c] = -INFINITY; p1[c] = -INFINITY;
        if (c < nc) {
            uint_t u = *(const uint_t*)&base[c * 16384 + lane * 2];
            int kv = c * 128 + lane * 2;
            float a  = __uint_as_float(u << 16);
            float bb = __uint_as_float(u & 0xffff0000u);
            if (kv     <= t) p0[c] = a  * SCL;
            if (kv + 1 <= t) p1[c] = bb * SCL;
            mx = fmaxf(mx, fmaxf(p0[c], p1[c]));
        }
    }
    #pragma unroll
    for (int off = 32; off >= 1; off >>= 1) mx = fmaxf(mx, __shfl_xor(mx, off));
    float s = 0.f;
    #pragma unroll
    for (int c = 0; c < 8; ++c) {
        p0[c] = exp2f(p0[c] - mx);                   // -inf -> 0
        p1[c] = exp2f(p1[c] - mx);
        if (c < nc) s += p0[c] + p1[c];
    }
    #pragma unroll
    for (int off = 32; off >= 1; off >>= 1) s += __shfl_xor(s, off);
    const float inv = 1.f / s;
    #pragma unroll
    for (int c = 0; c < 8; ++c) if (c < nc) {
        uint_t o = (uint_t)f2bf(p0[c] * inv) | ((uint_t)f2bf(p1[c] * inv) << 16);
        *(uint_t*)&base[c * 16384 + lane * 2] = o;
    }
}

// ---------------------------------------------------------------------------
// Phase C: y[zg][q][c] = P @ V from packed S. grid (4 c-tiles, 8 ti, 16 z').
// A addressing walks packed tiles: elem (q,k) at tile k>>7, offset q*128+(k&127).
// ---------------------------------------------------------------------------
__global__ __launch_bounds__(256, 2) void attn_pv_gemm(
    const ushort_t* __restrict__ Spk, const ushort_t* __restrict__ ckvT,
    ushort_t* __restrict__ y, int zbase)
{
    __shared__ ushort_t As[128 * 32];
    __shared__ ushort_t Bs[128 * 32];
    const int tid  = threadIdx.x;
    const int lane = tid & 63;
    const int w    = tid >> 6;
    const int l15 = lane & 15, l4 = lane >> 4;
    const int wr = w >> 1, wc = w & 1;
    const int srow = lane >> 2;
    const int scol = (lane & 3) * 8;
    const int cx = blockIdx.x, ti = blockIdx.y, z = blockIdx.z;
    const int b = (zbase + z) & 3;
    const int K = (ti + 1) * 128;
    const ushort_t* Abase = Spk + (long)z * 589824 + (long)(ti * (ti + 1) / 2) * 16384;
    const ushort_t* Bb = ckvT + (long)b * 512 * 1024 + (long)cx * 128 * 1024;
    ushort_t* Cb = y + ((long)(zbase + z) * 1024 + ti * 128) * 512 + cx * 128;

    f32x4 acc[4][4];
    #pragma unroll
    for (int m = 0; m < 4; ++m)
        #pragma unroll
        for (int n = 0; n < 4; ++n) acc[m][n] = (f32x4){0.f, 0.f, 0.f, 0.f};

    for (int k0 = 0; k0 < K; k0 += 32) {
        const ushort_t* At = Abase + (k0 >> 7) * 16384 + (k0 & 127);
        #pragma unroll
        for (int i = 0; i < 2; ++i) {
            int r = w * 32 + i * 16;
            gload_lds16(At + (long)(r + srow) * 128 + scol, &As[r * 32]);
            gload_lds16(Bb + (long)(r + srow) * 1024 + k0 + scol, &Bs[r * 32]);
        }
        __syncthreads();

        bf16x8 af[4], bfv[4];
        #pragma unroll
        for (int m = 0; m < 4; ++m)
            af[m] = *(const bf16x8*)&As[(wr * 64 + m * 16 + l15) * 32 + l4 * 8];
        #pragma unroll
        for (int n = 0; n < 4; ++n)
            bfv[n] = *(const bf16x8*)&Bs[(wc * 64 + n * 16 + l15) * 32 + l4 * 8];
        #pragma unroll
        for (int m = 0; m < 4; ++m)
            #pragma unroll
            for (int n = 0; n < 4; ++n)
                acc[m][n] = __builtin_amdgcn_mfma_f32_16x16x32_bf16(af[m], bfv[n], acc[m][n], 0, 0, 0);
        __syncthreads();
    }

    #pragma unroll
    for (int m = 0; m < 4; ++m)
        #pragma unroll
        for (int j = 0; j < 4; ++j) {
            long row = wr * 64 + m * 16 + l4 * 4 + j;
            #pragma unroll
            for (int n = 0; n < 4; ++n)
                Cb[row * 512 + wc * 64 + n * 16 + l15] = f2bf(acc[m][n][j]);
        }
}

// ---------------------------------------------------------------------------
// f32 -> bf16 conversion (vectorized, 8/thread). n must be multiple of 2048.
// ---------------------------------------------------------------------------
__global__ void cvt_bf16(const float* __restrict__ in, ushort_t* __restrict__ out) {
    long i = ((long)blockIdx.x * 256 + threadIdx.x) * 8;
    float4 a = *(const float4*)&in[i];
    float4 b = *(const float4*)&in[i + 4];
    ushort_t p[8] = {f2bf(a.x), f2bf(a.y), f2bf(a.z), f2bf(a.w),
                     f2bf(b.x), f2bf(b.y), f2bf(b.z), f2bf(b.w)};
    *(uint4*)&out[i] = *(const uint4*)p;
}

// ---------------------------------------------------------------------------
// Transpose+convert [2048][512] f32 -> [512][2048] bf16 (z=0: W_uk, z=1: W_uv)
// ---------------------------------------------------------------------------
__global__ __launch_bounds__(256) void transcvt_bf16(
    const float* __restrict__ A, ushort_t* __restrict__ At,
    const float* __restrict__ Bp, ushort_t* __restrict__ Bt)
{
    __shared__ float tile[64][65];
    const float* in = blockIdx.z ? Bp : A;
    ushort_t* out   = blockIdx.z ? Bt : At;
    const int k0 = blockIdx.x * 64, c0 = blockIdx.y * 64;
    const int t = threadIdx.x;
    #pragma unroll
    for (int i = 0; i < 4; ++i) {
        int idx = t + i * 256;
        int r = idx >> 4, c4 = idx & 15;
        float4 v = *(const float4*)&in[(long)(c0 + r) * 512 + k0 + c4 * 4];
        tile[r][c4 * 4 + 0] = v.x; tile[r][c4 * 4 + 1] = v.y;
        tile[r][c4 * 4 + 2] = v.z; tile[r][c4 * 4 + 3] = v.w;
    }
    __syncthreads();
    #pragma unroll
    for (int i = 0; i < 4; ++i) {
        int idx = t + i * 256;
        int kr = idx >> 4, c4 = idx & 15;
        ushort_t p[4];
        #pragma unroll
        for (int j = 0; j < 4; ++j) p[j] = f2bf(tile[c4 * 4 + j][kr]);
        *(uint2*)&out[(long)(k0 + kr) * 2048 + c0 + c4 * 4] = *(const uint2*)p;
    }
}

// ---------------------------------------------------------------------------
// Tiled f32 GEMM (kept only for c_kr: M=4096, N=64, K=2048)
// ---------------------------------------------------------------------------
template<int BM, int BN, int BK, int TM, int TN, bool BTRANS, typename OutT>
__global__ __launch_bounds__(256) void gemm_f32(
    const float* __restrict__ A, const float* __restrict__ Bp, OutT* __restrict__ Cp,
    int K, int lda, int ldb, int ldc, long sA, long sB, long sC)
{
    static_assert(BK == 16, "loader assumes BK=16");
    static_assert((BM / TM) * (BN / TN) == 256, "256 threads");
    const float* Ab = A  + (long)blockIdx.z * sA;
    const float* Bx = Bp + (long)blockIdx.z * sB;
    OutT*        Cb = Cp + (long)blockIdx.z * sC;

    __shared__ float As[BK][BM + 4];
    __shared__ float Bs[BK][BN + 4];

    const int tid = threadIdx.x;
    const int tx = tid % (BN / TN);
    const int ty = tid / (BN / TN);
    const int m0 = blockIdx.y * BM, n0 = blockIdx.x * BN;

    float acc[TM][TN] = {};

    for (int k0 = 0; k0 < K; k0 += BK) {
        #pragma unroll
        for (int i = 0; i < BM * BK / 1024; ++i) {
            int chunk = tid + i * 256;
            int row = chunk >> 2;
            int kq  = chunk & 3;
            float4 v = *(const float4*)&Ab[(long)(m0 + row) * lda + k0 + kq * 4];
            As[kq * 4 + 0][row] = v.x; As[kq * 4 + 1][row] = v.y;
            As[kq * 4 + 2][row] = v.z; As[kq * 4 + 3][row] = v.w;
        }
        if constexpr (BTRANS) {
            #pragma unroll
            for (int i = 0; i < BN * BK / 1024; ++i) {
                int chunk = tid + i * 256;
                int row = chunk >> 2;
                int kq  = chunk & 3;
                float4 v = *(const float4*)&Bx[(long)(n0 + row) * ldb + k0 + kq * 4];
                Bs[kq * 4 + 0][row] = v.x; Bs[kq * 4 + 1][row] = v.y;
                Bs[kq * 4 + 2][row] = v.z; Bs[kq * 4 + 3][row] = v.w;
            }
        } else {
            #pragma unroll
            for (int i = 0; i < BN * BK / 1024; ++i) {
                int chunk = tid + i * 256;
                int krow = chunk / (BN / 4);
                int nq   = chunk % (BN / 4);
                *(float4*)&Bs[krow][nq * 4] =
                    *(const float4*)&Bx[(long)(k0 + krow) * ldb + n0 + nq * 4];
            }
        }
        __syncthreads();

        #pragma unroll
        for (int kk = 0; kk < BK; ++kk) {
            float a[TM], bv[TN];
            #pragma unroll
            for (int i = 0; i < TM; ++i) a[i] = As[kk][ty * TM + i];
            #pragma unroll
            for (int j = 0; j < TN; ++j) {
                int half = j / (TN / 2), jj = j % (TN / 2);
                bv[j] = Bs[kk][half * (BN / 2) + tx * (TN / 2) + jj];
            }
            #pragma unroll
            for (int i = 0; i < TM; ++i)
                #pragma unroll
                for (int j = 0; j < TN; ++j)
                    acc[i][j] += a[i] * bv[j];
        }
        __syncthreads();
    }

    #pragma unroll
    for (int i = 0; i < TM; ++i) {
        long rbase = (long)(m0 + ty * TM + i) * ldc + n0;
        #pragma unroll
        for (int half = 0; half < 2; ++half) {
            long cbase = rbase + half * (BN / 2) + tx * (TN / 2);
            #pragma unroll
            for (int jj = 0; jj < TN / 2; ++jj)
                Cb[cbase + jj] = acc[i][half * (TN / 2) + jj];
        }
    }
}

// ---------------------------------------------------------------------------
// RoPE kernels
// ---------------------------------------------------------------------------
__global__ void rope_kr_kernel(const float* __restrict__ krb, ushort_t* __restrict__ kfull,
                               const float* __restrict__ cosT, const float* __restrict__ sinT) {
    int p = blockIdx.x * 256 + threadIdx.x;          // BT*32 pairs
    if (p >= BT * 32) return;
    int bt = p >> 5, i = p & 31;
    int t = bt & (Tn - 1);
    float c = cosT[t * 32 + i], s = sinT[t * 32 + i];
    float re = krb[bt * 64 + 2 * i], im = krb[bt * 64 + 2 * i + 1];
    float o0 = re * c - im * s, o1 = re * s + im * c;
    uint_t u = (uint_t)f2bf(o0) | ((uint_t)f2bf(o1) << 16);
    *(uint_t*)&kfull[(long)bt * 576 + 512 + 2 * i] = u;
}

__global__ void rope_qr_kernel(const ushort_t* __restrict__ qrb, ushort_t* __restrict__ qfull,
                               const float* __restrict__ cosT, const float* __restrict__ sinT) {
    int p = blockIdx.x * 256 + threadIdx.x;          // BT*NH*32 pairs
    if (p >= BT * 512) return;
    int bt = p >> 9, rem = p & 511;
    int hh = rem >> 5, i = rem & 31;
    int t = bt & (Tn - 1);
    float c = cosT[t * 32 + i], s = sinT[t * 32 + i];
    uint_t u = *(const uint_t*)&qrb[(long)bt * 1024 + hh * 64 + 2 * i];
    float re = __uint_as_float(u << 16);
    float im = __uint_as_float(u & 0xffff0000u);
    float o0 = re * c - im * s, o1 = re * s + im * c;
    uint_t o = (uint_t)f2bf(o0) | ((uint_t)f2bf(o1) << 16);
    *(uint_t*)&qfull[(((long)hh * Bn * Tn) + bt) * 576 + 512 + 2 * i] = o;
}

// ---------------------------------------------------------------------------
// Transpose c_kv (cols 0..511 of kfull) into ckvT[b][c][t] (bf16)
// ---------------------------------------------------------------------------
__global__ void transpose_ckv(const ushort_t* __restrict__ kfull, ushort_t* __restrict__ ckvT) {
    int idx = blockIdx.x * 256 + threadIdx.x;        // 4*128*512
    int c = idx & 511, rest = idx >> 9;
    int t8 = rest & 127, b = rest >> 7;
    ushort_t v[8];
    #pragma unroll
    for (int j = 0; j < 8; ++j)
        v[j] = kfull[((long)b * Tn + t8 * 8 + j) * 576 + c];
    *(uint4*)&ckvT[((long)b * 512 + c) * Tn + t8 * 8] = *(const uint4*)v;
}

// ---------------------------------------------------------------------------
extern "C" void kernel_launch(void* const* d_in, const int* in_sizes, int n_in,
                              void* d_out, int out_size, void* d_ws, size_t ws_size,
                              hipStream_t stream)
{
    (void)in_sizes; (void)n_in; (void)out_size; (void)ws_size;
    const float* x     = (const float*)d_in[0];
    const float* cosT  = (const float*)d_in[1];
    const float* sinT  = (const float*)d_in[2];
    const float* W_dq  = (const float*)d_in[3];   // [1536][2048]
    const float* W_uq  = (const float*)d_in[4];   // flat [2048*1536]
    const float* W_dkv = (const float*)d_in[5];   // [512][2048]
    const float* W_uk  = (const float*)d_in[6];   // [2048][512]
    const float* W_uv  = (const float*)d_in[7];   // [2048][512]
    const float* W_qr  = (const float*)d_in[8];   // [1024][1536]
    const float* W_kr  = (const float*)d_in[9];   // [64][2048]
    const float* W_o   = (const float*)d_in[10];  // [2048][2048]
    float* out = (float*)d_out;

    // ---- workspace: 90,439,680 ushorts = 180.9 MB (byte-identical to round 5) ----
    // SCRATCH region [0, 46661632): conversions/intermediates, then aliased by
    // attention (ybuf + Spk) after the qabs GEMM retires all of them.
    ushort_t* ws = (ushort_t*)d_ws;
    ushort_t* xb     = ws;                              // 8388608
    ushort_t* Wdq_b  = ws + 8388608;                    // 3145728
    ushort_t* Wuq_b  = ws + 11534336;                   // 3145728
    ushort_t* Wqr_b  = ws + 14680064;                   // 1572864
    ushort_t* Wo_b   = ws + 16252928;                   // 4194304
    ushort_t* Wdkv_b = ws + 20447232;                   // 1048576
    ushort_t* WukT_b = ws + 21495808;                   // 1048576  [512][2048]
    ushort_t* WuvT_b = ws + 22544384;                   // 1048576  [512][2048]
    ushort_t* cq_b   = ws + 23592960;                   // 6291456  [4096][1536]
    ushort_t* qr_b   = ws + 29884416;                   // 4194304  [4096][1024]
    ushort_t* keffT  = ws + 34078720;                   // 12582912 [16][512][1536]
    // attention aliases (valid post-qabs):
    ushort_t* ybuf   = ws;                              // 33554432 [64 z][1024][512]
    ushort_t* Spk    = ws + 33554432;                   // 9437184  [16 z'][36][128][128]
    // PERSISTENT region:
    ushort_t* Mtb    = ws + 46661632;                   // 1048576  [2048][512]
    ushort_t* qfull  = ws + 47710208;                   // 37748736 [16][4096][576]
    ushort_t* kfull  = ws + 85458944;                   // 2359296  [4096][576]
    ushort_t* ckvT   = ws + 87818240;                   // 2097152  [4][512][1024]
    float*    krb    = (float*)(ws + 89915392);         // 262144 f32 [4096][64]

    dim3 blk(256, 1, 1);

    // ---- bf16 conversions ----
    cvt_bf16<<<dim3(4096), blk, 0, stream>>>(x, xb);
    cvt_bf16<<<dim3(1536), blk, 0, stream>>>(W_dq, Wdq_b);
    cvt_bf16<<<dim3(1536), blk, 0, stream>>>(W_uq, Wuq_b);
    cvt_bf16<<<dim3(768),  blk, 0, stream>>>(W_qr, Wqr_b);
    cvt_bf16<<<dim3(2048), blk, 0, stream>>>(W_o, Wo_b);
    cvt_bf16<<<dim3(512),  blk, 0, stream>>>(W_dkv, Wdkv_b);
    transcvt_bf16<<<dim3(8, 32, 2), blk, 0, stream>>>(W_uk, WukT_b, W_uv, WuvT_b);

    // ---- projection GEMMs (all NT, bf16) ----
    gemm_bf16<ushort_t><<<dim3(12, 32, 1), blk, 0, stream>>>(
        xb, Wdq_b, cq_b, Cn, Cn, Cn, NLQ, 0, 0, 0);
    gemm_bf16<ushort_t><<<dim3(4, 32, 1), blk, 0, stream>>>(
        xb, Wdkv_b, kfull, Cn, Cn, Cn, 576, 0, 0, 0);
    gemm_f32<64,64,16,4,4,true,float><<<dim3(1, BT/64, 1), blk, 0, stream>>>(
        x, W_kr, krb, Cn, Cn, Cn, DHR, 0, 0, 0);
    rope_kr_kernel<<<dim3(BT*32/256), blk, 0, stream>>>(krb, kfull, cosT, sinT);
    gemm_bf16<ushort_t><<<dim3(8, 32, 1), blk, 0, stream>>>(
        cq_b, Wqr_b, qr_b, NLQ, NLQ, NLQ, NH*DHR, 0, 0, 0);
    rope_qr_kernel<<<dim3(BT*512/256), blk, 0, stream>>>(qr_b, qfull, cosT, sinT);
    gemm_bf16<ushort_t><<<dim3(12, 4, NH), blk, 0, stream>>>(
        WukT_b, Wuq_b, keffT, HS, Cn, Cn, NLQ, 128, 128, (long)NLKV*NLQ);
    gemm_bf16<ushort_t><<<dim3(4, 16, 1), blk, 0, stream>>>(
        Wo_b, WuvT_b, Mtb, Cn, Cn, Cn, NLKV, 0, 0, 0);
    gemm_bf16<ushort_t><<<dim3(4, 32, NH), blk, 0, stream>>>(
        cq_b, keffT, qfull, NLQ, NLQ, NLQ, 576,
        0, (long)NLKV*NLQ, (long)BT*576);
    transpose_ckv<<<dim3(Bn*512*128/256), blk, 0, stream>>>(kfull, ckvT);

    // ---- attention as GEMM phases, 4 z-groups of 16 (4 heads each) ----
    for (int g = 0; g < 4; ++g) {
        attn_s_gemm<<<dim3(36, 1, 16), blk, 0, stream>>>(qfull, kfull, Spk, g * 4);
        attn_softmax<<<dim3(16 * Tn / 4), blk, 0, stream>>>(Spk);
        attn_pv_gemm<<<dim3(4, 8, 16), blk, 0, stream>>>(Spk, ckvT, ybuf, g * 16);
    }
    // D: out = y @ Mt^T  (per-head batch, f32 out, full grid)
    gemm_bf16<float><<<dim3(1, 32, NH), blk, 0, stream>>>(
        ybuf, Mtb, out, NLKV, NLKV, NLKV, Cn,
        (long)BT*NLKV, (long)HS*NLKV, HS);
}

// Round 9
// 680.406 us; speedup vs baseline: 2.0867x; 1.1003x over previous
//
#include <hip/hip_runtime.h>
#include <type_traits>

typedef unsigned short ushort_t;
typedef unsigned int   uint_t;
typedef __attribute__((ext_vector_type(8))) short bf16x8;
typedef __attribute__((ext_vector_type(4))) float f32x4;

constexpr int Bn = 4, Tn = 1024, Cn = 2048, NH = 16, HS = 128;
constexpr int NLQ = 1536, NLKV = 512, DHR = 64;
constexpr int BT = Bn * Tn;
constexpr float ATT_SCALE = 0.07216878364870323f; // 1/sqrt(192)
constexpr float LOG2E = 1.4426950408889634f;

__device__ __forceinline__ ushort_t f2bf(float f) {
    uint_t u = __float_as_uint(f);
    u += 0x7fffu + ((u >> 16) & 1u);   // RNE
    return (ushort_t)(u >> 16);
}

__device__ __forceinline__ void gload_lds16(const void* g, void* l) {
    __builtin_amdgcn_global_load_lds(
        (__attribute__((address_space(1))) void*)g,
        (__attribute__((address_space(3))) void*)l, 16, 0, 0);
}

// ---------------------------------------------------------------------------
// Shared 128x128 MFMA GEMM tile core (m97 structure): C128 = A128xK @ B128xK^T
// (NT). Offsets pre-folded into Ab/Bb/Cb. OutT = ushort (bf16) or f32.
// ---------------------------------------------------------------------------
template<typename OutT>
__device__ __forceinline__ void gemm_tile128(
    const ushort_t* __restrict__ Ab, int lda,
    const ushort_t* __restrict__ Bb, int ldb,
    OutT* __restrict__ Cb, int ldc, int K,
    ushort_t* As, ushort_t* Bs)
{
    constexpr int BK = 32;
    const int tid  = threadIdx.x;
    const int lane = tid & 63;
    const int w    = tid >> 6;
    const int l15 = lane & 15, l4 = lane >> 4;
    const int wr = w >> 1, wc = w & 1;
    const int srow = lane >> 2;          // 0..15
    const int scol = (lane & 3) * 8;     // octet within 32-col row

    f32x4 acc[4][4];
    #pragma unroll
    for (int m = 0; m < 4; ++m)
        #pragma unroll
        for (int n = 0; n < 4; ++n) acc[m][n] = (f32x4){0.f, 0.f, 0.f, 0.f};

    for (int k0 = 0; k0 < K; k0 += BK) {
        #pragma unroll
        for (int i = 0; i < 2; ++i) {
            int r = w * 32 + i * 16;
            gload_lds16(Ab + (long)(r + srow) * lda + k0 + scol, &As[r * BK]);
            gload_lds16(Bb + (long)(r + srow) * ldb + k0 + scol, &Bs[r * BK]);
        }
        __syncthreads();

        bf16x8 af[4], bfv[4];
        #pragma unroll
        for (int m = 0; m < 4; ++m)
            af[m] = *(const bf16x8*)&As[(wr * 64 + m * 16 + l15) * BK + l4 * 8];
        #pragma unroll
        for (int n = 0; n < 4; ++n)
            bfv[n] = *(const bf16x8*)&Bs[(wc * 64 + n * 16 + l15) * BK + l4 * 8];
        #pragma unroll
        for (int m = 0; m < 4; ++m)
            #pragma unroll
            for (int n = 0; n < 4; ++n)
                acc[m][n] = __builtin_amdgcn_mfma_f32_16x16x32_bf16(af[m], bfv[n], acc[m][n], 0, 0, 0);
        __syncthreads();
    }

    #pragma unroll
    for (int m = 0; m < 4; ++m)
        #pragma unroll
        for (int j = 0; j < 4; ++j) {
            long row = wr * 64 + m * 16 + l4 * 4 + j;
            #pragma unroll
            for (int n = 0; n < 4; ++n) {
                long col = wc * 64 + n * 16 + l15;
                if constexpr (std::is_same<OutT, float>::value)
                    Cb[row * ldc + col] = acc[m][n][j];
                else
                    Cb[row * ldc + col] = f2bf(acc[m][n][j]);
            }
        }
}

// Generic NT GEMM wrapper (batched via sA/sB/sC)
template<typename OutT>
__global__ __launch_bounds__(256, 2) void gemm_bf16(
    const ushort_t* __restrict__ A, const ushort_t* __restrict__ B,
    OutT* __restrict__ C,
    int K, int lda, int ldb, int ldc, long sA, long sB, long sC)
{
    __shared__ ushort_t As[128 * 32];
    __shared__ ushort_t Bs[128 * 32];
    const ushort_t* Ab = A + (long)blockIdx.z * sA + (long)blockIdx.y * 128 * lda;
    const ushort_t* Bb = B + (long)blockIdx.z * sB + (long)blockIdx.x * 128 * ldb;
    OutT*           Cb = C + (long)blockIdx.z * sC + (long)blockIdx.y * 128 * ldc
                           + (long)blockIdx.x * 128;
    gemm_tile128<OutT>(Ab, lda, Bb, ldb, Cb, ldc, K, As, Bs);
}

// ---------------------------------------------------------------------------
// Phase A: S lower-triangle tiles, triangle-PACKED: Spk[z'][x][128][128],
// x = ti*(ti+1)/2 + si. One z-group (16 z' = 4 heads x 4 batch) per launch.
// ---------------------------------------------------------------------------
__global__ __launch_bounds__(256, 2) void attn_s_gemm(
    const ushort_t* __restrict__ qfull, const ushort_t* __restrict__ kfull,
    ushort_t* __restrict__ Spk, int hbase)
{
    __shared__ ushort_t As[128 * 32];
    __shared__ ushort_t Bs[128 * 32];
    const int x = blockIdx.x;                 // 0..35 (packed tile idx)
    int ti = 0;
    while ((ti + 1) * (ti + 2) / 2 <= x) ++ti;  // uniform scalar (<=8 iters)
    const int si = x - ti * (ti + 1) / 2;
    const int z = blockIdx.z;                 // 0..15 local
    const int h = hbase + (z >> 2), b = z & 3;
    const ushort_t* Ab = qfull + ((long)h * 4096 + b * 1024 + ti * 128) * 576;
    const ushort_t* Bb = kfull + ((long)b * 1024 + si * 128) * 576;
    ushort_t* Cb = Spk + (long)z * 589824 + (long)x * 16384;
    gemm_tile128<ushort_t>(Ab, 576, Bb, 576, Cb, 128, 576, As, Bs);
}

// ---------------------------------------------------------------------------
// Phase B: in-place causal row softmax on packed S. One wave per q-row.
// grid = 16*1024/4 blocks.
// ---------------------------------------------------------------------------
__global__ __launch_bounds__(256) void attn_softmax(ushort_t* __restrict__ Spk)
{
    const int wid  = threadIdx.x >> 6;
    const int lane = threadIdx.x & 63;
    const int r = blockIdx.x * 4 + wid;              // 0..16383
    const int z = r >> 10, t = r & 1023;
    const int ti = t >> 7;
    const int nc = ti + 1;                           // valid 128-col chunks
    ushort_t* base = Spk + (long)z * 589824 + (long)(ti * (ti + 1) / 2) * 16384
                        + (t & 127) * 128;
    const float SCL = ATT_SCALE * LOG2E;

    float p0[8], p1[8];
    float mx = -INFINITY;
    #pragma unroll
    for (int c = 0; c < 8; ++c) {
        p0[c] = -INFINITY; p1[c] = -INFINITY;
        if (c < nc) {
            uint_t u = *(const uint_t*)&base[c * 16384 + lane * 2];
            int kv = c * 128 + lane * 2;
            float a  = __uint_as_float(u << 16);
            float bb = __uint_as_float(u & 0xffff0000u);
            if (kv     <= t) p0[c] = a  * SCL;
            if (kv + 1 <= t) p1[c] = bb * SCL;
            mx = fmaxf(mx, fmaxf(p0[c], p1[c]));
        }
    }
    #pragma unroll
    for (int off = 32; off >= 1; off >>= 1) mx = fmaxf(mx, __shfl_xor(mx, off));
    float s = 0.f;
    #pragma unroll
    for (int c = 0; c < 8; ++c) {
        p0[c] = exp2f(p0[c] - mx);                   // -inf -> 0
        p1[c] = exp2f(p1[c] - mx);
        if (c < nc) s += p0[c] + p1[c];
    }
    #pragma unroll
    for (int off = 32; off >= 1; off >>= 1) s += __shfl_xor(s, off);
    const float inv = 1.f / s;
    #pragma unroll
    for (int c = 0; c < 8; ++c) if (c < nc) {
        uint_t o = (uint_t)f2bf(p0[c] * inv) | ((uint_t)f2bf(p1[c] * inv) << 16);
        *(uint_t*)&base[c * 16384 + lane * 2] = o;
    }
}

// ---------------------------------------------------------------------------
// Phase C: y[zg][q][c] = P @ V from packed S. grid (4 c-tiles, 8 ti, 16 z').
// A addressing walks packed tiles: elem (q,k) at tile k>>7, offset q*128+(k&127).
// ---------------------------------------------------------------------------
__global__ __launch_bounds__(256, 2) void attn_pv_gemm(
    const ushort_t* __restrict__ Spk, const ushort_t* __restrict__ ckvT,
    ushort_t* __restrict__ y, int zbase)
{
    __shared__ ushort_t As[128 * 32];
    __shared__ ushort_t Bs[128 * 32];
    const int tid  = threadIdx.x;
    const int lane = tid & 63;
    const int w    = tid >> 6;
    const int l15 = lane & 15, l4 = lane >> 4;
    const int wr = w >> 1, wc = w & 1;
    const int srow = lane >> 2;
    const int scol = (lane & 3) * 8;
    const int cx = blockIdx.x, ti = blockIdx.y, z = blockIdx.z;
    const int b = (zbase + z) & 3;
    const int K = (ti + 1) * 128;
    const ushort_t* Abase = Spk + (long)z * 589824 + (long)(ti * (ti + 1) / 2) * 16384;
    const ushort_t* Bb = ckvT + (long)b * 512 * 1024 + (long)cx * 128 * 1024;
    ushort_t* Cb = y + ((long)(zbase + z) * 1024 + ti * 128) * 512 + cx * 128;

    f32x4 acc[4][4];
    #pragma unroll
    for (int m = 0; m < 4; ++m)
        #pragma unroll
        for (int n = 0; n < 4; ++n) acc[m][n] = (f32x4){0.f, 0.f, 0.f, 0.f};

    for (int k0 = 0; k0 < K; k0 += 32) {
        const ushort_t* At = Abase + (k0 >> 7) * 16384 + (k0 & 127);
        #pragma unroll
        for (int i = 0; i < 2; ++i) {
            int r = w * 32 + i * 16;
            gload_lds16(At + (long)(r + srow) * 128 + scol, &As[r * 32]);
            gload_lds16(Bb + (long)(r + srow) * 1024 + k0 + scol, &Bs[r * 32]);
        }
        __syncthreads();

        bf16x8 af[4], bfv[4];
        #pragma unroll
        for (int m = 0; m < 4; ++m)
            af[m] = *(const bf16x8*)&As[(wr * 64 + m * 16 + l15) * 32 + l4 * 8];
        #pragma unroll
        for (int n = 0; n < 4; ++n)
            bfv[n] = *(const bf16x8*)&Bs[(wc * 64 + n * 16 + l15) * 32 + l4 * 8];
        #pragma unroll
        for (int m = 0; m < 4; ++m)
            #pragma unroll
            for (int n = 0; n < 4; ++n)
                acc[m][n] = __builtin_amdgcn_mfma_f32_16x16x32_bf16(af[m], bfv[n], acc[m][n], 0, 0, 0);
        __syncthreads();
    }

    #pragma unroll
    for (int m = 0; m < 4; ++m)
        #pragma unroll
        for (int j = 0; j < 4; ++j) {
            long row = wr * 64 + m * 16 + l4 * 4 + j;
            #pragma unroll
            for (int n = 0; n < 4; ++n)
                Cb[row * 512 + wc * 64 + n * 16 + l15] = f2bf(acc[m][n][j]);
        }
}

// ---------------------------------------------------------------------------
// f32 -> bf16 conversion (vectorized, 8/thread). n must be multiple of 2048.
// ---------------------------------------------------------------------------
__global__ void cvt_bf16(const float* __restrict__ in, ushort_t* __restrict__ out) {
    long i = ((long)blockIdx.x * 256 + threadIdx.x) * 8;
    float4 a = *(const float4*)&in[i];
    float4 b = *(const float4*)&in[i + 4];
    ushort_t p[8] = {f2bf(a.x), f2bf(a.y), f2bf(a.z), f2bf(a.w),
                     f2bf(b.x), f2bf(b.y), f2bf(b.z), f2bf(b.w)};
    *(uint4*)&out[i] = *(const uint4*)p;
}

// ---------------------------------------------------------------------------
// Generic transpose+convert: in [R][ldin] f32 (row-major) -> out [ldin][R] bf16.
// grid = (ldin/64, R/64). out[(c0+c)*R + r0+r] = in[(r0+r)*ldin + c0+c].
// ---------------------------------------------------------------------------
__global__ __launch_bounds__(256) void transcvt_g(
    const float* __restrict__ in, ushort_t* __restrict__ out, int ldin, int R)
{
    __shared__ float tile[64][65];
    const int c0 = blockIdx.x * 64, r0 = blockIdx.y * 64;
    const int t = threadIdx.x;
    #pragma unroll
    for (int i = 0; i < 4; ++i) {
        int idx = t + i * 256;
        int r = idx >> 4, c4 = idx & 15;
        float4 v = *(const float4*)&in[(long)(r0 + r) * ldin + c0 + c4 * 4];
        tile[r][c4 * 4 + 0] = v.x; tile[r][c4 * 4 + 1] = v.y;
        tile[r][c4 * 4 + 2] = v.z; tile[r][c4 * 4 + 3] = v.w;
    }
    __syncthreads();
    #pragma unroll
    for (int i = 0; i < 4; ++i) {
        int idx = t + i * 256;
        int c = idx >> 4, r4 = idx & 15;
        ushort_t p[4];
        #pragma unroll
        for (int j = 0; j < 4; ++j) p[j] = f2bf(tile[r4 * 4 + j][c]);
        *(uint2*)&out[(long)(c0 + c) * R + r0 + r4 * 4] = *(const uint2*)p;
    }
}

// ---------------------------------------------------------------------------
// Tiled f32 GEMM (kept only for c_kr: M=4096, N=64, K=2048)
// ---------------------------------------------------------------------------
template<int BM, int BN, int BK, int TM, int TN, bool BTRANS, typename OutT>
__global__ __launch_bounds__(256) void gemm_f32(
    const float* __restrict__ A, const float* __restrict__ Bp, OutT* __restrict__ Cp,
    int K, int lda, int ldb, int ldc, long sA, long sB, long sC)
{
    static_assert(BK == 16, "loader assumes BK=16");
    static_assert((BM / TM) * (BN / TN) == 256, "256 threads");
    const float* Ab = A  + (long)blockIdx.z * sA;
    const float* Bx = Bp + (long)blockIdx.z * sB;
    OutT*        Cb = Cp + (long)blockIdx.z * sC;

    __shared__ float As[BK][BM + 4];
    __shared__ float Bs[BK][BN + 4];

    const int tid = threadIdx.x;
    const int tx = tid % (BN / TN);
    const int ty = tid / (BN / TN);
    const int m0 = blockIdx.y * BM, n0 = blockIdx.x * BN;

    float acc[TM][TN] = {};

    for (int k0 = 0; k0 < K; k0 += BK) {
        #pragma unroll
        for (int i = 0; i < BM * BK / 1024; ++i) {
            int chunk = tid + i * 256;
            int row = chunk >> 2;
            int kq  = chunk & 3;
            float4 v = *(const float4*)&Ab[(long)(m0 + row) * lda + k0 + kq * 4];
            As[kq * 4 + 0][row] = v.x; As[kq * 4 + 1][row] = v.y;
            As[kq * 4 + 2][row] = v.z; As[kq * 4 + 3][row] = v.w;
        }
        if constexpr (BTRANS) {
            #pragma unroll
            for (int i = 0; i < BN * BK / 1024; ++i) {
                int chunk = tid + i * 256;
                int row = chunk >> 2;
                int kq  = chunk & 3;
                float4 v = *(const float4*)&Bx[(long)(n0 + row) * ldb + k0 + kq * 4];
                Bs[kq * 4 + 0][row] = v.x; Bs[kq * 4 + 1][row] = v.y;
                Bs[kq * 4 + 2][row] = v.z; Bs[kq * 4 + 3][row] = v.w;
            }
        } else {
            #pragma unroll
            for (int i = 0; i < BN * BK / 1024; ++i) {
                int chunk = tid + i * 256;
                int krow = chunk / (BN / 4);
                int nq   = chunk % (BN / 4);
                *(float4*)&Bs[krow][nq * 4] =
                    *(const float4*)&Bx[(long)(k0 + krow) * ldb + n0 + nq * 4];
            }
        }
        __syncthreads();

        #pragma unroll
        for (int kk = 0; kk < BK; ++kk) {
            float a[TM], bv[TN];
            #pragma unroll
            for (int i = 0; i < TM; ++i) a[i] = As[kk][ty * TM + i];
            #pragma unroll
            for (int j = 0; j < TN; ++j) {
                int half = j / (TN / 2), jj = j % (TN / 2);
                bv[j] = Bs[kk][half * (BN / 2) + tx * (TN / 2) + jj];
            }
            #pragma unroll
            for (int i = 0; i < TM; ++i)
                #pragma unroll
                for (int j = 0; j < TN; ++j)
                    acc[i][j] += a[i] * bv[j];
        }
        __syncthreads();
    }

    #pragma unroll
    for (int i = 0; i < TM; ++i) {
        long rbase = (long)(m0 + ty * TM + i) * ldc + n0;
        #pragma unroll
        for (int half = 0; half < 2; ++half) {
            long cbase = rbase + half * (BN / 2) + tx * (TN / 2);
            #pragma unroll
            for (int jj = 0; jj < TN / 2; ++jj)
                Cb[cbase + jj] = acc[i][half * (TN / 2) + jj];
        }
    }
}

// ---------------------------------------------------------------------------
// RoPE kernels
// ---------------------------------------------------------------------------
__global__ void rope_kr_kernel(const float* __restrict__ krb, ushort_t* __restrict__ kfull,
                               const float* __restrict__ cosT, const float* __restrict__ sinT) {
    int p = blockIdx.x * 256 + threadIdx.x;          // BT*32 pairs
    if (p >= BT * 32) return;
    int bt = p >> 5, i = p & 31;
    int t = bt & (Tn - 1);
    float c = cosT[t * 32 + i], s = sinT[t * 32 + i];
    float re = krb[bt * 64 + 2 * i], im = krb[bt * 64 + 2 * i + 1];
    float o0 = re * c - im * s, o1 = re * s + im * c;
    uint_t u = (uint_t)f2bf(o0) | ((uint_t)f2bf(o1) << 16);
    *(uint_t*)&kfull[(long)bt * 576 + 512 + 2 * i] = u;
}

__global__ void rope_qr_kernel(const ushort_t* __restrict__ qrb, ushort_t* __restrict__ qfull,
                               const float* __restrict__ cosT, const float* __restrict__ sinT) {
    int p = blockIdx.x * 256 + threadIdx.x;          // BT*NH*32 pairs
    if (p >= BT * 512) return;
    int bt = p >> 9, rem = p & 511;
    int hh = rem >> 5, i = rem & 31;
    int t = bt & (Tn - 1);
    float c = cosT[t * 32 + i], s = sinT[t * 32 + i];
    uint_t u = *(const uint_t*)&qrb[(long)bt * 1024 + hh * 64 + 2 * i];
    float re = __uint_as_float(u << 16);
    float im = __uint_as_float(u & 0xffff0000u);
    float o0 = re * c - im * s, o1 = re * s + im * c;
    uint_t o = (uint_t)f2bf(o0) | ((uint_t)f2bf(o1) << 16);
    *(uint_t*)&qfull[(((long)hh * Bn * Tn) + bt) * 576 + 512 + 2 * i] = o;
}

// ---------------------------------------------------------------------------
// Transpose c_kv (cols 0..511 of kfull) into ckvT[b][c][t] (bf16)
// ---------------------------------------------------------------------------
__global__ void transpose_ckv(const ushort_t* __restrict__ kfull, ushort_t* __restrict__ ckvT) {
    int idx = blockIdx.x * 256 + threadIdx.x;        // 4*128*512
    int c = idx & 511, rest = idx >> 9;
    int t8 = rest & 127, b = rest >> 7;
    ushort_t v[8];
    #pragma unroll
    for (int j = 0; j < 8; ++j)
        v[j] = kfull[((long)b * Tn + t8 * 8 + j) * 576 + c];
    *(uint4*)&ckvT[((long)b * 512 + c) * Tn + t8 * 8] = *(const uint4*)v;
}

// ---------------------------------------------------------------------------
extern "C" void kernel_launch(void* const* d_in, const int* in_sizes, int n_in,
                              void* d_out, int out_size, void* d_ws, size_t ws_size,
                              hipStream_t stream)
{
    (void)in_sizes; (void)n_in; (void)out_size; (void)ws_size;
    const float* x     = (const float*)d_in[0];
    const float* cosT  = (const float*)d_in[1];
    const float* sinT  = (const float*)d_in[2];
    const float* W_dq  = (const float*)d_in[3];   // [1536][2048]
    const float* W_uq  = (const float*)d_in[4];   // flat: [1536 q][2048 hd]
    const float* W_dkv = (const float*)d_in[5];   // [512][2048]
    const float* W_uk  = (const float*)d_in[6];   // [2048][512]
    const float* W_uv  = (const float*)d_in[7];   // [2048][512]
    const float* W_qr  = (const float*)d_in[8];   // [1024][1536]
    const float* W_kr  = (const float*)d_in[9];   // [64][2048]
    const float* W_o   = (const float*)d_in[10];  // [2048][2048]
    float* out = (float*)d_out;

    // ---- workspace: 90,439,680 ushorts = 180.9 MB (unchanged footprint) ----
    // SCRATCH region [0, 46661632): conversions/intermediates, then aliased by
    // attention (ybuf + Spk) after the qabs GEMM retires all of them.
    ushort_t* ws = (ushort_t*)d_ws;
    ushort_t* xb     = ws;                              // 8388608
    ushort_t* Wdq_b  = ws + 8388608;                    // 3145728
    ushort_t* WuqT_b = ws + 11534336;                   // 3145728  [2048 hd][1536 q]
    ushort_t* Wqr_b  = ws + 14680064;                   // 1572864
    ushort_t* Wo_b   = ws + 16252928;                   // 4194304
    ushort_t* Wdkv_b = ws + 20447232;                   // 1048576
    ushort_t* WukT_b = ws + 21495808;                   // 1048576  [512][2048]
    ushort_t* WuvT_b = ws + 22544384;                   // 1048576  [512][2048]
    ushort_t* cq_b   = ws + 23592960;                   // 6291456  [4096][1536]
    ushort_t* qr_b   = ws + 29884416;                   // 4194304  [4096][1024]
    ushort_t* qnom   = ws + 34078720;                   // 8388608  [4096][2048]
    // attention aliases (valid post-qabs):
    ushort_t* ybuf   = ws;                              // 33554432 [64 z][1024][512]
    ushort_t* Spk    = ws + 33554432;                   // 9437184  [16 z'][36][128][128]
    // PERSISTENT region:
    ushort_t* Mtb    = ws + 46661632;                   // 1048576  [2048][512]
    ushort_t* qfull  = ws + 47710208;                   // 37748736 [16][4096][576]
    ushort_t* kfull  = ws + 85458944;                   // 2359296  [4096][576]
    ushort_t* ckvT   = ws + 87818240;                   // 2097152  [4][512][1024]
    float*    krb    = (float*)(ws + 89915392);         // 262144 f32 [4096][64]

    dim3 blk(256, 1, 1);

    // ---- bf16 conversions ----
    cvt_bf16<<<dim3(4096), blk, 0, stream>>>(x, xb);
    cvt_bf16<<<dim3(1536), blk, 0, stream>>>(W_dq, Wdq_b);
    cvt_bf16<<<dim3(768),  blk, 0, stream>>>(W_qr, Wqr_b);
    cvt_bf16<<<dim3(2048), blk, 0, stream>>>(W_o, Wo_b);
    cvt_bf16<<<dim3(512),  blk, 0, stream>>>(W_dkv, Wdkv_b);
    // W_uq [1536][2048] -> WuqT_b [2048][1536]
    transcvt_g<<<dim3(32, 24), blk, 0, stream>>>(W_uq, WuqT_b, 2048, 1536);
    // W_uk, W_uv [2048][512] -> [512][2048]
    transcvt_g<<<dim3(8, 32), blk, 0, stream>>>(W_uk, WukT_b, 512, 2048);
    transcvt_g<<<dim3(8, 32), blk, 0, stream>>>(W_uv, WuvT_b, 512, 2048);

    // ---- projection GEMMs (all NT, bf16) ----
    // c_q = xb @ Wdq^T
    gemm_bf16<ushort_t><<<dim3(12, 32, 1), blk, 0, stream>>>(
        xb, Wdq_b, cq_b, Cn, Cn, Cn, NLQ, 0, 0, 0);
    // c_kv -> kfull[:, :512]
    gemm_bf16<ushort_t><<<dim3(4, 32, 1), blk, 0, stream>>>(
        xb, Wdkv_b, kfull, Cn, Cn, Cn, 576, 0, 0, 0);
    // c_kr (f32, tiny)
    gemm_f32<64,64,16,4,4,true,float><<<dim3(1, BT/64, 1), blk, 0, stream>>>(
        x, W_kr, krb, Cn, Cn, Cn, DHR, 0, 0, 0);
    rope_kr_kernel<<<dim3(BT*32/256), blk, 0, stream>>>(krb, kfull, cosT, sinT);
    // c_qr = cq @ Wqr^T
    gemm_bf16<ushort_t><<<dim3(8, 32, 1), blk, 0, stream>>>(
        cq_b, Wqr_b, qr_b, NLQ, NLQ, NLQ, NH*DHR, 0, 0, 0);
    rope_qr_kernel<<<dim3(BT*512/256), blk, 0, stream>>>(qr_b, qfull, cosT, sinT);
    // q_nom = cq @ WuqT^T  (M=4096, N=2048, K=1536)
    gemm_bf16<ushort_t><<<dim3(16, 32, 1), blk, 0, stream>>>(
        cq_b, WuqT_b, qnom, NLQ, NLQ, NLQ, Cn, 0, 0, 0);
    // qabs[h] = q_nom_h @ Wuk_h  (K=128, per-head 128-col slices of A and B)
    gemm_bf16<ushort_t><<<dim3(4, 32, NH), blk, 0, stream>>>(
        qnom, WukT_b, qfull, HS, Cn, Cn, 576,
        128, 128, (long)BT*576);
    // Mt = Wo @ WuvT^T
    gemm_bf16<ushort_t><<<dim3(4, 16, 1), blk, 0, stream>>>(
        Wo_b, WuvT_b, Mtb, Cn, Cn, Cn, NLKV, 0, 0, 0);
    transpose_ckv<<<dim3(Bn*512*128/256), blk, 0, stream>>>(kfull, ckvT);

    // ---- attention as GEMM phases, 4 z-groups of 16 (4 heads each) ----
    for (int g = 0; g < 4; ++g) {
        attn_s_gemm<<<dim3(36, 1, 16), blk, 0, stream>>>(qfull, kfull, Spk, g * 4);
        attn_softmax<<<dim3(16 * Tn / 4), blk, 0, stream>>>(Spk);
        attn_pv_gemm<<<dim3(4, 8, 16), blk, 0, stream>>>(Spk, ckvT, ybuf, g * 16);
    }
    // D: out = y @ Mt^T  (per-head batch, f32 out, full grid)
    gemm_bf16<float><<<dim3(1, 32, NH), blk, 0, stream>>>(
        ybuf, Mtb, out, NLKV, NLKV, NLKV, Cn,
        (long)BT*NLKV, (long)HS*NLKV, HS);
}

// Round 10
// 567.290 us; speedup vs baseline: 2.5028x; 1.1994x over previous
//
#include <hip/hip_runtime.h>
#include <type_traits>

typedef unsigned short ushort_t;
typedef unsigned int   uint_t;
typedef __attribute__((ext_vector_type(8))) short bf16x8;
typedef __attribute__((ext_vector_type(4))) float f32x4;

constexpr int Bn = 4, Tn = 1024, Cn = 2048, NH = 16, HS = 128;
constexpr int NLQ = 1536, NLKV = 512, DHR = 64;
constexpr int BT = Bn * Tn;
constexpr int KLD = 640;                  // kfull leading dim (512 ckv + 64 kr + 64 pad)
constexpr float ATT_SCALE = 0.07216878364870323f; // 1/sqrt(192)
constexpr float LOG2E = 1.4426950408889634f;

__device__ __forceinline__ ushort_t f2bf(float f) {
    uint_t u = __float_as_uint(f);
    u += 0x7fffu + ((u >> 16) & 1u);   // RNE
    return (ushort_t)(u >> 16);
}

__device__ __forceinline__ void gload_lds16(const void* g, void* l) {
    __builtin_amdgcn_global_load_lds(
        (__attribute__((address_space(1))) void*)g,
        (__attribute__((address_space(3))) void*)l, 16, 0, 0);
}

// ---------------------------------------------------------------------------
// Shared 128x128 MFMA GEMM tile core (m97 structure): C128 = A128xK @ B128xK^T
// (NT). Offsets pre-folded into Ab/Bb/Cb. OutT = ushort (bf16) or f32.
// ---------------------------------------------------------------------------
template<typename OutT>
__device__ __forceinline__ void gemm_tile128(
    const ushort_t* __restrict__ Ab, int lda,
    const ushort_t* __restrict__ Bb, int ldb,
    OutT* __restrict__ Cb, int ldc, int K,
    ushort_t* As, ushort_t* Bs)
{
    constexpr int BK = 32;
    const int tid  = threadIdx.x;
    const int lane = tid & 63;
    const int w    = tid >> 6;
    const int l15 = lane & 15, l4 = lane >> 4;
    const int wr = w >> 1, wc = w & 1;
    const int srow = lane >> 2;          // 0..15
    const int scol = (lane & 3) * 8;     // octet within 32-col row

    f32x4 acc[4][4];
    #pragma unroll
    for (int m = 0; m < 4; ++m)
        #pragma unroll
        for (int n = 0; n < 4; ++n) acc[m][n] = (f32x4){0.f, 0.f, 0.f, 0.f};

    for (int k0 = 0; k0 < K; k0 += BK) {
        #pragma unroll
        for (int i = 0; i < 2; ++i) {
            int r = w * 32 + i * 16;
            gload_lds16(Ab + (long)(r + srow) * lda + k0 + scol, &As[r * BK]);
            gload_lds16(Bb + (long)(r + srow) * ldb + k0 + scol, &Bs[r * BK]);
        }
        __syncthreads();

        bf16x8 af[4], bfv[4];
        #pragma unroll
        for (int m = 0; m < 4; ++m)
            af[m] = *(const bf16x8*)&As[(wr * 64 + m * 16 + l15) * BK + l4 * 8];
        #pragma unroll
        for (int n = 0; n < 4; ++n)
            bfv[n] = *(const bf16x8*)&Bs[(wc * 64 + n * 16 + l15) * BK + l4 * 8];
        #pragma unroll
        for (int m = 0; m < 4; ++m)
            #pragma unroll
            for (int n = 0; n < 4; ++n)
                acc[m][n] = __builtin_amdgcn_mfma_f32_16x16x32_bf16(af[m], bfv[n], acc[m][n], 0, 0, 0);
        __syncthreads();
    }

    #pragma unroll
    for (int m = 0; m < 4; ++m)
        #pragma unroll
        for (int j = 0; j < 4; ++j) {
            long row = wr * 64 + m * 16 + l4 * 4 + j;
            #pragma unroll
            for (int n = 0; n < 4; ++n) {
                long col = wc * 64 + n * 16 + l15;
                if constexpr (std::is_same<OutT, float>::value)
                    Cb[row * ldc + col] = acc[m][n][j];
                else
                    Cb[row * ldc + col] = f2bf(acc[m][n][j]);
            }
        }
}

// Generic NT GEMM wrapper (batched via sA/sB/sC)
template<typename OutT>
__global__ __launch_bounds__(256, 2) void gemm_bf16(
    const ushort_t* __restrict__ A, const ushort_t* __restrict__ B,
    OutT* __restrict__ C,
    int K, int lda, int ldb, int ldc, long sA, long sB, long sC)
{
    __shared__ ushort_t As[128 * 32];
    __shared__ ushort_t Bs[128 * 32];
    const ushort_t* Ab = A + (long)blockIdx.z * sA + (long)blockIdx.y * 128 * lda;
    const ushort_t* Bb = B + (long)blockIdx.z * sB + (long)blockIdx.x * 128 * ldb;
    OutT*           Cb = C + (long)blockIdx.z * sC + (long)blockIdx.y * 128 * ldc
                           + (long)blockIdx.x * 128;
    gemm_tile128<OutT>(Ab, lda, Bb, ldb, Cb, ldc, K, As, Bs);
}

// ---------------------------------------------------------------------------
// Phase A: S lower-triangle tiles, triangle-PACKED: Spk[z'][x][128][128],
// x = ti*(ti+1)/2 + si. One z-group (16 z' = 4 heads x 4 batch) per launch.
// ---------------------------------------------------------------------------
__global__ __launch_bounds__(256, 2) void attn_s_gemm(
    const ushort_t* __restrict__ qfull, const ushort_t* __restrict__ kfull,
    ushort_t* __restrict__ Spk, int hbase)
{
    __shared__ ushort_t As[128 * 32];
    __shared__ ushort_t Bs[128 * 32];
    const int x = blockIdx.x;                 // 0..35 (packed tile idx)
    int ti = 0;
    while ((ti + 1) * (ti + 2) / 2 <= x) ++ti;  // uniform scalar (<=8 iters)
    const int si = x - ti * (ti + 1) / 2;
    const int z = blockIdx.z;                 // 0..15 local
    const int h = hbase + (z >> 2), b = z & 3;
    const ushort_t* Ab = qfull + ((long)h * 4096 + b * 1024 + ti * 128) * 576;
    const ushort_t* Bb = kfull + ((long)b * 1024 + si * 128) * KLD;
    ushort_t* Cb = Spk + (long)z * 589824 + (long)x * 16384;
    gemm_tile128<ushort_t>(Ab, 576, Bb, KLD, Cb, 128, 576, As, Bs);
}

// ---------------------------------------------------------------------------
// Phase B: in-place causal row softmax on packed S. One wave per q-row.
// grid = 16*1024/4 blocks.
// ---------------------------------------------------------------------------
__global__ __launch_bounds__(256) void attn_softmax(ushort_t* __restrict__ Spk)
{
    const int wid  = threadIdx.x >> 6;
    const int lane = threadIdx.x & 63;
    const int r = blockIdx.x * 4 + wid;              // 0..16383
    const int z = r >> 10, t = r & 1023;
    const int ti = t >> 7;
    const int nc = ti + 1;                           // valid 128-col chunks
    ushort_t* base = Spk + (long)z * 589824 + (long)(ti * (ti + 1) / 2) * 16384
                        + (t & 127) * 128;
    const float SCL = ATT_SCALE * LOG2E;

    float p0[8], p1[8];
    float mx = -INFINITY;
    #pragma unroll
    for (int c = 0; c < 8; ++c) {
        p0[c] = -INFINITY; p1[c] = -INFINITY;
        if (c < nc) {
            uint_t u = *(const uint_t*)&base[c * 16384 + lane * 2];
            int kv = c * 128 + lane * 2;
            float a  = __uint_as_float(u << 16);
            float bb = __uint_as_float(u & 0xffff0000u);
            if (kv     <= t) p0[c] = a  * SCL;
            if (kv + 1 <= t) p1[c] = bb * SCL;
            mx = fmaxf(mx, fmaxf(p0[c], p1[c]));
        }
    }
    #pragma unroll
    for (int off = 32; off >= 1; off >>= 1) mx = fmaxf(mx, __shfl_xor(mx, off));
    float s = 0.f;
    #pragma unroll
    for (int c = 0; c < 8; ++c) {
        p0[c] = exp2f(p0[c] - mx);                   // -inf -> 0
        p1[c] = exp2f(p1[c] - mx);
        if (c < nc) s += p0[c] + p1[c];
    }
    #pragma unroll
    for (int off = 32; off >= 1; off >>= 1) s += __shfl_xor(s, off);
    const float inv = 1.f / s;
    #pragma unroll
    for (int c = 0; c < 8; ++c) if (c < nc) {
        uint_t o = (uint_t)f2bf(p0[c] * inv) | ((uint_t)f2bf(p1[c] * inv) << 16);
        *(uint_t*)&base[c * 16384 + lane * 2] = o;
    }
}

// ---------------------------------------------------------------------------
// Phase C: y[zg][q][c] = P @ V from packed S. grid (4 c-tiles, 8 ti, 16 z').
// A addressing walks packed tiles: elem (q,k) at tile k>>7, offset q*128+(k&127).
// ---------------------------------------------------------------------------
__global__ __launch_bounds__(256, 2) void attn_pv_gemm(
    const ushort_t* __restrict__ Spk, const ushort_t* __restrict__ ckvT,
    ushort_t* __restrict__ y, int zbase)
{
    __shared__ ushort_t As[128 * 32];
    __shared__ ushort_t Bs[128 * 32];
    const int tid  = threadIdx.x;
    const int lane = tid & 63;
    const int w    = tid >> 6;
    const int l15 = lane & 15, l4 = lane >> 4;
    const int wr = w >> 1, wc = w & 1;
    const int srow = lane >> 2;
    const int scol = (lane & 3) * 8;
    const int cx = blockIdx.x, ti = blockIdx.y, z = blockIdx.z;
    const int b = (zbase + z) & 3;
    const int K = (ti + 1) * 128;
    const ushort_t* Abase = Spk + (long)z * 589824 + (long)(ti * (ti + 1) / 2) * 16384;
    const ushort_t* Bb = ckvT + (long)b * 512 * 1024 + (long)cx * 128 * 1024;
    ushort_t* Cb = y + ((long)(zbase + z) * 1024 + ti * 128) * 512 + cx * 128;

    f32x4 acc[4][4];
    #pragma unroll
    for (int m = 0; m < 4; ++m)
        #pragma unroll
        for (int n = 0; n < 4; ++n) acc[m][n] = (f32x4){0.f, 0.f, 0.f, 0.f};

    for (int k0 = 0; k0 < K; k0 += 32) {
        const ushort_t* At = Abase + (k0 >> 7) * 16384 + (k0 & 127);
        #pragma unroll
        for (int i = 0; i < 2; ++i) {
            int r = w * 32 + i * 16;
            gload_lds16(At + (long)(r + srow) * 128 + scol, &As[r * 32]);
            gload_lds16(Bb + (long)(r + srow) * 1024 + k0 + scol, &Bs[r * 32]);
        }
        __syncthreads();

        bf16x8 af[4], bfv[4];
        #pragma unroll
        for (int m = 0; m < 4; ++m)
            af[m] = *(const bf16x8*)&As[(wr * 64 + m * 16 + l15) * 32 + l4 * 8];
        #pragma unroll
        for (int n = 0; n < 4; ++n)
            bfv[n] = *(const bf16x8*)&Bs[(wc * 64 + n * 16 + l15) * 32 + l4 * 8];
        #pragma unroll
        for (int m = 0; m < 4; ++m)
            #pragma unroll
            for (int n = 0; n < 4; ++n)
                acc[m][n] = __builtin_amdgcn_mfma_f32_16x16x32_bf16(af[m], bfv[n], acc[m][n], 0, 0, 0);
        __syncthreads();
    }

    #pragma unroll
    for (int m = 0; m < 4; ++m)
        #pragma unroll
        for (int j = 0; j < 4; ++j) {
            long row = wr * 64 + m * 16 + l4 * 4 + j;
            #pragma unroll
            for (int n = 0; n < 4; ++n)
                Cb[row * 512 + wc * 64 + n * 16 + l15] = f2bf(acc[m][n][j]);
        }
}

// ---------------------------------------------------------------------------
// f32 -> bf16 conversion (vectorized, 8/thread). n must be multiple of 2048.
// ---------------------------------------------------------------------------
__global__ void cvt_bf16(const float* __restrict__ in, ushort_t* __restrict__ out) {
    long i = ((long)blockIdx.x * 256 + threadIdx.x) * 8;
    float4 a = *(const float4*)&in[i];
    float4 b = *(const float4*)&in[i + 4];
    ushort_t p[8] = {f2bf(a.x), f2bf(a.y), f2bf(a.z), f2bf(a.w),
                     f2bf(b.x), f2bf(b.y), f2bf(b.z), f2bf(b.w)};
    *(uint4*)&out[i] = *(const uint4*)p;
}

// zero-fill (8 ushorts/thread)
__global__ void zero_bf16(ushort_t* __restrict__ out) {
    long i = ((long)blockIdx.x * 256 + threadIdx.x) * 8;
    *(uint4*)&out[i] = make_uint4(0, 0, 0, 0);
}

// ---------------------------------------------------------------------------
// Generic transpose+convert: in [R][ldin] f32 (row-major) -> out [ldin][R] bf16.
// grid = (ldin/64, R/64). out[(c0+c)*R + r0+r] = in[(r0+r)*ldin + c0+c].
// ---------------------------------------------------------------------------
__global__ __launch_bounds__(256) void transcvt_g(
    const float* __restrict__ in, ushort_t* __restrict__ out, int ldin, int R)
{
    __shared__ float tile[64][65];
    const int c0 = blockIdx.x * 64, r0 = blockIdx.y * 64;
    const int t = threadIdx.x;
    #pragma unroll
    for (int i = 0; i < 4; ++i) {
        int idx = t + i * 256;
        int r = idx >> 4, c4 = idx & 15;
        float4 v = *(const float4*)&in[(long)(r0 + r) * ldin + c0 + c4 * 4];
        tile[r][c4 * 4 + 0] = v.x; tile[r][c4 * 4 + 1] = v.y;
        tile[r][c4 * 4 + 2] = v.z; tile[r][c4 * 4 + 3] = v.w;
    }
    __syncthreads();
    #pragma unroll
    for (int i = 0; i < 4; ++i) {
        int idx = t + i * 256;
        int c = idx >> 4, r4 = idx & 15;
        ushort_t p[4];
        #pragma unroll
        for (int j = 0; j < 4; ++j) p[j] = f2bf(tile[r4 * 4 + j][c]);
        *(uint2*)&out[(long)(c0 + c) * R + r0 + r4 * 4] = *(const uint2*)p;
    }
}

// ---------------------------------------------------------------------------
// RoPE kernels
// ---------------------------------------------------------------------------
// k_r rope: in-place on kfull cols 512..575 (bf16, pre-rope from fused GEMM)
__global__ void rope_kr_kernel(ushort_t* __restrict__ kfull,
                               const float* __restrict__ cosT, const float* __restrict__ sinT) {
    int p = blockIdx.x * 256 + threadIdx.x;          // BT*32 pairs
    if (p >= BT * 32) return;
    int bt = p >> 5, i = p & 31;
    int t = bt & (Tn - 1);
    float c = cosT[t * 32 + i], s = sinT[t * 32 + i];
    uint_t u = *(const uint_t*)&kfull[(long)bt * KLD + 512 + 2 * i];
    float re = __uint_as_float(u << 16);
    float im = __uint_as_float(u & 0xffff0000u);
    float o0 = re * c - im * s, o1 = re * s + im * c;
    uint_t o = (uint_t)f2bf(o0) | ((uint_t)f2bf(o1) << 16);
    *(uint_t*)&kfull[(long)bt * KLD + 512 + 2 * i] = o;
}

__global__ void rope_qr_kernel(const ushort_t* __restrict__ qrb, ushort_t* __restrict__ qfull,
                               const float* __restrict__ cosT, const float* __restrict__ sinT) {
    int p = blockIdx.x * 256 + threadIdx.x;          // BT*NH*32 pairs
    if (p >= BT * 512) return;
    int bt = p >> 9, rem = p & 511;
    int hh = rem >> 5, i = rem & 31;
    int t = bt & (Tn - 1);
    float c = cosT[t * 32 + i], s = sinT[t * 32 + i];
    uint_t u = *(const uint_t*)&qrb[(long)bt * 1024 + hh * 64 + 2 * i];
    float re = __uint_as_float(u << 16);
    float im = __uint_as_float(u & 0xffff0000u);
    float o0 = re * c - im * s, o1 = re * s + im * c;
    uint_t o = (uint_t)f2bf(o0) | ((uint_t)f2bf(o1) << 16);
    *(uint_t*)&qfull[(((long)hh * Bn * Tn) + bt) * 576 + 512 + 2 * i] = o;
}

// ---------------------------------------------------------------------------
// Transpose c_kv (cols 0..511 of kfull) into ckvT[b][c][t] (bf16)
// ---------------------------------------------------------------------------
__global__ void transpose_ckv(const ushort_t* __restrict__ kfull, ushort_t* __restrict__ ckvT) {
    int idx = blockIdx.x * 256 + threadIdx.x;        // 4*128*512
    int c = idx & 511, rest = idx >> 9;
    int t8 = rest & 127, b = rest >> 7;
    ushort_t v[8];
    #pragma unroll
    for (int j = 0; j < 8; ++j)
        v[j] = kfull[((long)b * Tn + t8 * 8 + j) * KLD + c];
    *(uint4*)&ckvT[((long)b * 512 + c) * Tn + t8 * 8] = *(const uint4*)v;
}

// ---------------------------------------------------------------------------
extern "C" void kernel_launch(void* const* d_in, const int* in_sizes, int n_in,
                              void* d_out, int out_size, void* d_ws, size_t ws_size,
                              hipStream_t stream)
{
    (void)in_sizes; (void)n_in; (void)out_size; (void)ws_size;
    const float* x     = (const float*)d_in[0];
    const float* cosT  = (const float*)d_in[1];
    const float* sinT  = (const float*)d_in[2];
    const float* W_dq  = (const float*)d_in[3];   // [1536][2048]
    const float* W_uq  = (const float*)d_in[4];   // flat: [1536 q][2048 hd]
    const float* W_dkv = (const float*)d_in[5];   // [512][2048]
    const float* W_uk  = (const float*)d_in[6];   // [2048][512]
    const float* W_uv  = (const float*)d_in[7];   // [2048][512]
    const float* W_qr  = (const float*)d_in[8];   // [1024][1536]
    const float* W_kr  = (const float*)d_in[9];   // [64][2048]
    const float* W_o   = (const float*)d_in[10];  // [2048][2048]
    float* out = (float*)d_out;

    // ---- workspace: <= 90,439,680 ushorts = 180.9 MB (proven footprint) ----
    // SCRATCH [0, 46661632): conversions/intermediates, aliased by attention
    // (ybuf+Spk) after the qabs GEMM retires every consumer.
    ushort_t* ws = (ushort_t*)d_ws;
    ushort_t* xb     = ws;                              // 8388608
    ushort_t* Wdq_b  = ws + 8388608;                    // 3145728
    ushort_t* WuqT_b = ws + 11534336;                   // 3145728  [2048 hd][1536 q]
    ushort_t* Wqr_b  = ws + 14680064;                   // 1572864
    ushort_t* Wo_b   = ws + 16252928;                   // 4194304
    ushort_t* Wdkv_b = ws + 20447232;                   // 1310720  [640][2048] (dkv|kr|pad)
    ushort_t* WukT_b = ws + 21757952;                   // 1048576  [512][2048]
    ushort_t* WuvT_b = ws + 22806528;                   // 1048576  [512][2048]
    ushort_t* cq_b   = ws + 23855104;                   // 6291456  [4096][1536]
    ushort_t* qr_b   = ws + 30146560;                   // 4194304  [4096][1024]
    ushort_t* qnom   = ws + 34340864;                   // 8388608  [4096][2048] -> ends 42729472
    // attention aliases (valid post-qabs):
    ushort_t* ybuf   = ws;                              // 33554432 [64 z][1024][512]
    ushort_t* Spk    = ws + 33554432;                   // 9437184  -> ends 42991616
    // PERSISTENT region:
    ushort_t* Mtb    = ws + 46661632;                   // 1048576  [2048][512]
    ushort_t* qfull  = ws + 47710208;                   // 37748736 [16][4096][576]
    ushort_t* kfull  = ws + 85458944;                   // 2621440  [4096][640] -> ends 88080384
    ushort_t* ckvT   = ws + 88080384;                   // 2097152  [4][512][1024] -> ends 90177536

    dim3 blk(256, 1, 1);

    // ---- bf16 conversions ----
    cvt_bf16<<<dim3(4096), blk, 0, stream>>>(x, xb);
    cvt_bf16<<<dim3(1536), blk, 0, stream>>>(W_dq, Wdq_b);
    cvt_bf16<<<dim3(768),  blk, 0, stream>>>(W_qr, Wqr_b);
    cvt_bf16<<<dim3(2048), blk, 0, stream>>>(W_o, Wo_b);
    // combined B for fused c_kv|c_kr: rows 0..511 = W_dkv, 512..575 = W_kr, 576..639 = 0
    cvt_bf16<<<dim3(512),  blk, 0, stream>>>(W_dkv, Wdkv_b);
    cvt_bf16<<<dim3(64),   blk, 0, stream>>>(W_kr,  Wdkv_b + 512 * 2048);
    zero_bf16<<<dim3(64),  blk, 0, stream>>>(Wdkv_b + 576 * 2048);
    // W_uq [1536][2048] -> WuqT_b [2048][1536]
    transcvt_g<<<dim3(32, 24), blk, 0, stream>>>(W_uq, WuqT_b, 2048, 1536);
    // W_uk, W_uv [2048][512] -> [512][2048]
    transcvt_g<<<dim3(8, 32), blk, 0, stream>>>(W_uk, WukT_b, 512, 2048);
    transcvt_g<<<dim3(8, 32), blk, 0, stream>>>(W_uv, WuvT_b, 512, 2048);

    // ---- projection GEMMs (all NT, bf16) ----
    // c_q = xb @ Wdq^T
    gemm_bf16<ushort_t><<<dim3(12, 32, 1), blk, 0, stream>>>(
        xb, Wdq_b, cq_b, Cn, Cn, Cn, NLQ, 0, 0, 0);
    // fused [c_kv | c_kr_pre] -> kfull[:, 0..575] (ld 640)
    gemm_bf16<ushort_t><<<dim3(5, 32, 1), blk, 0, stream>>>(
        xb, Wdkv_b, kfull, Cn, Cn, Cn, KLD, 0, 0, 0);
    rope_kr_kernel<<<dim3(BT*32/256), blk, 0, stream>>>(kfull, cosT, sinT);
    // c_qr = cq @ Wqr^T
    gemm_bf16<ushort_t><<<dim3(8, 32, 1), blk, 0, stream>>>(
        cq_b, Wqr_b, qr_b, NLQ, NLQ, NLQ, NH*DHR, 0, 0, 0);
    rope_qr_kernel<<<dim3(BT*512/256), blk, 0, stream>>>(qr_b, qfull, cosT, sinT);
    // q_nom = cq @ WuqT^T  (M=4096, N=2048, K=1536)
    gemm_bf16<ushort_t><<<dim3(16, 32, 1), blk, 0, stream>>>(
        cq_b, WuqT_b, qnom, NLQ, NLQ, NLQ, Cn, 0, 0, 0);
    // qabs[h] = q_nom_h @ Wuk_h  (K=128, per-head 128-col slices of A and B)
    gemm_bf16<ushort_t><<<dim3(4, 32, NH), blk, 0, stream>>>(
        qnom, WukT_b, qfull, HS, Cn, Cn, 576,
        128, 128, (long)BT*576);
    // Mt = Wo @ WuvT^T
    gemm_bf16<ushort_t><<<dim3(4, 16, 1), blk, 0, stream>>>(
        Wo_b, WuvT_b, Mtb, Cn, Cn, Cn, NLKV, 0, 0, 0);
    transpose_ckv<<<dim3(Bn*512*128/256), blk, 0, stream>>>(kfull, ckvT);

    // ---- attention as GEMM phases, 4 z-groups of 16 (4 heads each) ----
    for (int g = 0; g < 4; ++g) {
        attn_s_gemm<<<dim3(36, 1, 16), blk, 0, stream>>>(qfull, kfull, Spk, g * 4);
        attn_softmax<<<dim3(16 * Tn / 4), blk, 0, stream>>>(Spk);
        attn_pv_gemm<<<dim3(4, 8, 16), blk, 0, stream>>>(Spk, ckvT, ybuf, g * 16);
    }
    // D: out = y @ Mt^T  (per-head batch, f32 out, full grid)
    gemm_bf16<float><<<dim3(1, 32, NH), blk, 0, stream>>>(
        ybuf, Mtb, out, NLKV, NLKV, NLKV, Cn,
        (long)BT*NLKV, (long)HS*NLKV, HS);
}

// Round 11
// 479.769 us; speedup vs baseline: 2.9594x; 1.1824x over previous
//
#include <hip/hip_runtime.h>
#include <type_traits>

typedef unsigned short ushort_t;
typedef unsigned int   uint_t;
typedef __attribute__((ext_vector_type(8))) short bf16x8;
typedef __attribute__((ext_vector_type(4))) float f32x4;

constexpr int Bn = 4, Tn = 1024, Cn = 2048, NH = 16, HS = 128;
constexpr int NLQ = 1536, NLKV = 512, DHR = 64;
constexpr int BT = Bn * Tn;
constexpr int KLD = 640;                  // kfull leading dim (512 ckv + 64 kr + 64 pad)
constexpr float ATT_SCALE = 0.07216878364870323f; // 1/sqrt(192)
constexpr float LOG2E = 1.4426950408889634f;

__device__ __forceinline__ ushort_t f2bf(float f) {
    uint_t u = __float_as_uint(f);
    u += 0x7fffu + ((u >> 16) & 1u);   // RNE
    return (ushort_t)(u >> 16);
}

__device__ __forceinline__ void gload_lds16(const void* g, void* l) {
    __builtin_amdgcn_global_load_lds(
        (__attribute__((address_space(1))) void*)g,
        (__attribute__((address_space(3))) void*)l, 16, 0, 0);
}

// ---------------------------------------------------------------------------
// Shared 128x128 MFMA GEMM tile core (m97 structure): C128 = A128xK @ B128xK^T
// (NT). Offsets pre-folded into Ab/Bb/Cb. OutT = ushort (bf16) or f32.
// ---------------------------------------------------------------------------
template<typename OutT>
__device__ __forceinline__ void gemm_tile128(
    const ushort_t* __restrict__ Ab, int lda,
    const ushort_t* __restrict__ Bb, int ldb,
    OutT* __restrict__ Cb, int ldc, int K,
    ushort_t* As, ushort_t* Bs)
{
    constexpr int BK = 32;
    const int tid  = threadIdx.x;
    const int lane = tid & 63;
    const int w    = tid >> 6;
    const int l15 = lane & 15, l4 = lane >> 4;
    const int wr = w >> 1, wc = w & 1;
    const int srow = lane >> 2;          // 0..15
    const int scol = (lane & 3) * 8;     // octet within 32-col row

    f32x4 acc[4][4];
    #pragma unroll
    for (int m = 0; m < 4; ++m)
        #pragma unroll
        for (int n = 0; n < 4; ++n) acc[m][n] = (f32x4){0.f, 0.f, 0.f, 0.f};

    for (int k0 = 0; k0 < K; k0 += BK) {
        #pragma unroll
        for (int i = 0; i < 2; ++i) {
            int r = w * 32 + i * 16;
            gload_lds16(Ab + (long)(r + srow) * lda + k0 + scol, &As[r * BK]);
            gload_lds16(Bb + (long)(r + srow) * ldb + k0 + scol, &Bs[r * BK]);
        }
        __syncthreads();

        bf16x8 af[4], bfv[4];
        #pragma unroll
        for (int m = 0; m < 4; ++m)
            af[m] = *(const bf16x8*)&As[(wr * 64 + m * 16 + l15) * BK + l4 * 8];
        #pragma unroll
        for (int n = 0; n < 4; ++n)
            bfv[n] = *(const bf16x8*)&Bs[(wc * 64 + n * 16 + l15) * BK + l4 * 8];
        #pragma unroll
        for (int m = 0; m < 4; ++m)
            #pragma unroll
            for (int n = 0; n < 4; ++n)
                acc[m][n] = __builtin_amdgcn_mfma_f32_16x16x32_bf16(af[m], bfv[n], acc[m][n], 0, 0, 0);
        __syncthreads();
    }

    #pragma unroll
    for (int m = 0; m < 4; ++m)
        #pragma unroll
        for (int j = 0; j < 4; ++j) {
            long row = wr * 64 + m * 16 + l4 * 4 + j;
            #pragma unroll
            for (int n = 0; n < 4; ++n) {
                long col = wc * 64 + n * 16 + l15;
                if constexpr (std::is_same<OutT, float>::value)
                    Cb[row * ldc + col] = acc[m][n][j];
                else
                    Cb[row * ldc + col] = f2bf(acc[m][n][j]);
            }
        }
}

// Generic NT GEMM wrapper (batched via sA/sB/sC)
template<typename OutT>
__global__ __launch_bounds__(256, 2) void gemm_bf16(
    const ushort_t* __restrict__ A, const ushort_t* __restrict__ B,
    OutT* __restrict__ C,
    int K, int lda, int ldb, int ldc, long sA, long sB, long sC)
{
    __shared__ ushort_t As[128 * 32];
    __shared__ ushort_t Bs[128 * 32];
    const ushort_t* Ab = A + (long)blockIdx.z * sA + (long)blockIdx.y * 128 * lda;
    const ushort_t* Bb = B + (long)blockIdx.z * sB + (long)blockIdx.x * 128 * ldb;
    OutT*           Cb = C + (long)blockIdx.z * sC + (long)blockIdx.y * 128 * ldc
                           + (long)blockIdx.x * 128;
    gemm_tile128<OutT>(Ab, lda, Bb, ldb, Cb, ldc, K, As, Bs);
}

// ---------------------------------------------------------------------------
// Phase A: S lower-triangle tiles, triangle-PACKED: Spk[z][x][128][128],
// x = ti*(ti+1)/2 + si. Single launch, z = h*4+b (64).
// ---------------------------------------------------------------------------
__global__ __launch_bounds__(256, 2) void attn_s_gemm(
    const ushort_t* __restrict__ qfull, const ushort_t* __restrict__ kfull,
    ushort_t* __restrict__ Spk)
{
    __shared__ ushort_t As[128 * 32];
    __shared__ ushort_t Bs[128 * 32];
    const int x = blockIdx.x;                 // 0..35 (packed tile idx)
    int ti = 0;
    while ((ti + 1) * (ti + 2) / 2 <= x) ++ti;  // uniform scalar (<=8 iters)
    const int si = x - ti * (ti + 1) / 2;
    const int z = blockIdx.z;                 // 0..63
    const int h = z >> 2, b = z & 3;
    const ushort_t* Ab = qfull + ((long)h * 4096 + b * 1024 + ti * 128) * 576;
    const ushort_t* Bb = kfull + ((long)b * 1024 + si * 128) * KLD;
    ushort_t* Cb = Spk + (long)z * 589824 + (long)x * 16384;
    gemm_tile128<ushort_t>(Ab, 576, Bb, KLD, Cb, 128, 576, As, Bs);
}

// ---------------------------------------------------------------------------
// Phase B: in-place causal row softmax on packed S. One wave per q-row.
// grid = 64*1024/4 blocks.
// ---------------------------------------------------------------------------
__global__ __launch_bounds__(256) void attn_softmax(ushort_t* __restrict__ Spk)
{
    const int wid  = threadIdx.x >> 6;
    const int lane = threadIdx.x & 63;
    const int r = blockIdx.x * 4 + wid;              // 0..65535
    const int z = r >> 10, t = r & 1023;
    const int ti = t >> 7;
    const int nc = ti + 1;                           // valid 128-col chunks
    ushort_t* base = Spk + (long)z * 589824 + (long)(ti * (ti + 1) / 2) * 16384
                        + (t & 127) * 128;
    const float SCL = ATT_SCALE * LOG2E;

    float p0[8], p1[8];
    float mx = -INFINITY;
    #pragma unroll
    for (int c = 0; c < 8; ++c) {
        p0[c] = -INFINITY; p1[c] = -INFINITY;
        if (c < nc) {
            uint_t u = *(const uint_t*)&base[c * 16384 + lane * 2];
            int kv = c * 128 + lane * 2;
            float a  = __uint_as_float(u << 16);
            float bb = __uint_as_float(u & 0xffff0000u);
            if (kv     <= t) p0[c] = a  * SCL;
            if (kv + 1 <= t) p1[c] = bb * SCL;
            mx = fmaxf(mx, fmaxf(p0[c], p1[c]));
        }
    }
    #pragma unroll
    for (int off = 32; off >= 1; off >>= 1) mx = fmaxf(mx, __shfl_xor(mx, off));
    float s = 0.f;
    #pragma unroll
    for (int c = 0; c < 8; ++c) {
        p0[c] = exp2f(p0[c] - mx);                   // -inf -> 0
        p1[c] = exp2f(p1[c] - mx);
        if (c < nc) s += p0[c] + p1[c];
    }
    #pragma unroll
    for (int off = 32; off >= 1; off >>= 1) s += __shfl_xor(s, off);
    const float inv = 1.f / s;
    #pragma unroll
    for (int c = 0; c < 8; ++c) if (c < nc) {
        uint_t o = (uint_t)f2bf(p0[c] * inv) | ((uint_t)f2bf(p1[c] * inv) << 16);
        *(uint_t*)&base[c * 16384 + lane * 2] = o;
    }
}

// ---------------------------------------------------------------------------
// Phase C: out[b, ti-rows, h*128..] = P @ VeffT_h^T, written f32 directly.
// grid (8 ti, 1, 64 z). A walks packed S tiles; B = VeffT[b][h*128+d][1024 s].
// ---------------------------------------------------------------------------
__global__ __launch_bounds__(256, 2) void attn_pv_gemm(
    const ushort_t* __restrict__ Spk, const ushort_t* __restrict__ VeffT,
    float* __restrict__ out)
{
    __shared__ ushort_t As[128 * 32];
    __shared__ ushort_t Bs[128 * 32];
    const int tid  = threadIdx.x;
    const int lane = tid & 63;
    const int w    = tid >> 6;
    const int l15 = lane & 15, l4 = lane >> 4;
    const int wr = w >> 1, wc = w & 1;
    const int srow = lane >> 2;
    const int scol = (lane & 3) * 8;
    const int ti = blockIdx.x, z = blockIdx.z;
    const int h = z >> 2, b = z & 3;
    const int K = (ti + 1) * 128;
    const ushort_t* Abase = Spk + (long)z * 589824 + (long)(ti * (ti + 1) / 2) * 16384;
    const ushort_t* Bb = VeffT + ((long)b * 2048 + h * 128) * 1024;
    float* Cb = out + ((long)b * 1024 + ti * 128) * 2048 + h * 128;

    f32x4 acc[4][4];
    #pragma unroll
    for (int m = 0; m < 4; ++m)
        #pragma unroll
        for (int n = 0; n < 4; ++n) acc[m][n] = (f32x4){0.f, 0.f, 0.f, 0.f};

    for (int k0 = 0; k0 < K; k0 += 32) {
        const ushort_t* At = Abase + (k0 >> 7) * 16384 + (k0 & 127);
        #pragma unroll
        for (int i = 0; i < 2; ++i) {
            int r = w * 32 + i * 16;
            gload_lds16(At + (long)(r + srow) * 128 + scol, &As[r * 32]);
            gload_lds16(Bb + (long)(r + srow) * 1024 + k0 + scol, &Bs[r * 32]);
        }
        __syncthreads();

        bf16x8 af[4], bfv[4];
        #pragma unroll
        for (int m = 0; m < 4; ++m)
            af[m] = *(const bf16x8*)&As[(wr * 64 + m * 16 + l15) * 32 + l4 * 8];
        #pragma unroll
        for (int n = 0; n < 4; ++n)
            bfv[n] = *(const bf16x8*)&Bs[(wc * 64 + n * 16 + l15) * 32 + l4 * 8];
        #pragma unroll
        for (int m = 0; m < 4; ++m)
            #pragma unroll
            for (int n = 0; n < 4; ++n)
                acc[m][n] = __builtin_amdgcn_mfma_f32_16x16x32_bf16(af[m], bfv[n], acc[m][n], 0, 0, 0);
        __syncthreads();
    }

    #pragma unroll
    for (int m = 0; m < 4; ++m)
        #pragma unroll
        for (int j = 0; j < 4; ++j) {
            long row = wr * 64 + m * 16 + l4 * 4 + j;
            #pragma unroll
            for (int n = 0; n < 4; ++n)
                Cb[row * 2048 + wc * 64 + n * 16 + l15] = acc[m][n][j];
        }
}

// ---------------------------------------------------------------------------
// f32 -> bf16 conversion (vectorized, 8/thread). n must be multiple of 2048.
// ---------------------------------------------------------------------------
__global__ void cvt_bf16(const float* __restrict__ in, ushort_t* __restrict__ out) {
    long i = ((long)blockIdx.x * 256 + threadIdx.x) * 8;
    float4 a = *(const float4*)&in[i];
    float4 b = *(const float4*)&in[i + 4];
    ushort_t p[8] = {f2bf(a.x), f2bf(a.y), f2bf(a.z), f2bf(a.w),
                     f2bf(b.x), f2bf(b.y), f2bf(b.z), f2bf(b.w)};
    *(uint4*)&out[i] = *(const uint4*)p;
}

// zero-fill (8 ushorts/thread)
__global__ void zero_bf16(ushort_t* __restrict__ out) {
    long i = ((long)blockIdx.x * 256 + threadIdx.x) * 8;
    *(uint4*)&out[i] = make_uint4(0, 0, 0, 0);
}

// ---------------------------------------------------------------------------
// Generic transpose+convert: in [R][ldin] f32 (row-major) -> out [ldin][R] bf16.
// grid = (ldin/64, R/64). out[(c0+c)*R + r0+r] = in[(r0+r)*ldin + c0+c].
// ---------------------------------------------------------------------------
__global__ __launch_bounds__(256) void transcvt_g(
    const float* __restrict__ in, ushort_t* __restrict__ out, int ldin, int R)
{
    __shared__ float tile[64][65];
    const int c0 = blockIdx.x * 64, r0 = blockIdx.y * 64;
    const int t = threadIdx.x;
    #pragma unroll
    for (int i = 0; i < 4; ++i) {
        int idx = t + i * 256;
        int r = idx >> 4, c4 = idx & 15;
        float4 v = *(const float4*)&in[(long)(r0 + r) * ldin + c0 + c4 * 4];
        tile[r][c4 * 4 + 0] = v.x; tile[r][c4 * 4 + 1] = v.y;
        tile[r][c4 * 4 + 2] = v.z; tile[r][c4 * 4 + 3] = v.w;
    }
    __syncthreads();
    #pragma unroll
    for (int i = 0; i < 4; ++i) {
        int idx = t + i * 256;
        int c = idx >> 4, r4 = idx & 15;
        ushort_t p[4];
        #pragma unroll
        for (int j = 0; j < 4; ++j) p[j] = f2bf(tile[r4 * 4 + j][c]);
        *(uint2*)&out[(long)(c0 + c) * R + r0 + r4 * 4] = *(const uint2*)p;
    }
}

// ---------------------------------------------------------------------------
// RoPE kernels
// ---------------------------------------------------------------------------
// k_r rope: in-place on kfull cols 512..575 (bf16, pre-rope from fused GEMM)
__global__ void rope_kr_kernel(ushort_t* __restrict__ kfull,
                               const float* __restrict__ cosT, const float* __restrict__ sinT) {
    int p = blockIdx.x * 256 + threadIdx.x;          // BT*32 pairs
    if (p >= BT * 32) return;
    int bt = p >> 5, i = p & 31;
    int t = bt & (Tn - 1);
    float c = cosT[t * 32 + i], s = sinT[t * 32 + i];
    uint_t u = *(const uint_t*)&kfull[(long)bt * KLD + 512 + 2 * i];
    float re = __uint_as_float(u << 16);
    float im = __uint_as_float(u & 0xffff0000u);
    float o0 = re * c - im * s, o1 = re * s + im * c;
    uint_t o = (uint_t)f2bf(o0) | ((uint_t)f2bf(o1) << 16);
    *(uint_t*)&kfull[(long)bt * KLD + 512 + 2 * i] = o;
}

__global__ void rope_qr_kernel(const ushort_t* __restrict__ qrb, ushort_t* __restrict__ qfull,
                               const float* __restrict__ cosT, const float* __restrict__ sinT) {
    int p = blockIdx.x * 256 + threadIdx.x;          // BT*NH*32 pairs
    if (p >= BT * 512) return;
    int bt = p >> 9, rem = p & 511;
    int hh = rem >> 5, i = rem & 31;
    int t = bt & (Tn - 1);
    float c = cosT[t * 32 + i], s = sinT[t * 32 + i];
    uint_t u = *(const uint_t*)&qrb[(long)bt * 1024 + hh * 64 + 2 * i];
    float re = __uint_as_float(u << 16);
    float im = __uint_as_float(u & 0xffff0000u);
    float o0 = re * c - im * s, o1 = re * s + im * c;
    uint_t o = (uint_t)f2bf(o0) | ((uint_t)f2bf(o1) << 16);
    *(uint_t*)&qfull[(((long)hh * Bn * Tn) + bt) * 576 + 512 + 2 * i] = o;
}

// ---------------------------------------------------------------------------
// Transpose Veff [4096 bs][2048 hd] -> VeffT [4 b][2048 hd][1024 s] (bf16)
// ---------------------------------------------------------------------------
__global__ void transpose_veff(const ushort_t* __restrict__ Veff, ushort_t* __restrict__ VeffT) {
    int idx = blockIdx.x * 256 + threadIdx.x;        // 4*128*2048 = 1048576
    int c = idx & 2047, rest = idx >> 11;
    int t8 = rest & 127, b = rest >> 7;
    ushort_t v[8];
    #pragma unroll
    for (int j = 0; j < 8; ++j)
        v[j] = Veff[((long)b * Tn + t8 * 8 + j) * 2048 + c];
    *(uint4*)&VeffT[((long)b * 2048 + c) * Tn + t8 * 8] = *(const uint4*)v;
}

// ---------------------------------------------------------------------------
extern "C" void kernel_launch(void* const* d_in, const int* in_sizes, int n_in,
                              void* d_out, int out_size, void* d_ws, size_t ws_size,
                              hipStream_t stream)
{
    (void)in_sizes; (void)n_in; (void)out_size; (void)ws_size;
    const float* x     = (const float*)d_in[0];
    const float* cosT  = (const float*)d_in[1];
    const float* sinT  = (const float*)d_in[2];
    const float* W_dq  = (const float*)d_in[3];   // [1536][2048]
    const float* W_uq  = (const float*)d_in[4];   // flat: [1536 q][2048 hd]
    const float* W_dkv = (const float*)d_in[5];   // [512][2048]
    const float* W_uk  = (const float*)d_in[6];   // [2048][512]
    const float* W_uv  = (const float*)d_in[7];   // [2048][512]
    const float* W_qr  = (const float*)d_in[8];   // [1024][1536]
    const float* W_kr  = (const float*)d_in[9];   // [64][2048]
    const float* W_o   = (const float*)d_in[10];  // [2048][2048]
    float* out = (float*)d_out;

    // ---- workspace: <= 90,439,680 ushorts = 180.9 MB (proven footprint) ----
    // SCRATCH [0, 46661632): conversions/intermediates; post-qabs aliased by
    // Veff (transient) then Spk + VeffT for attention.
    ushort_t* ws = (ushort_t*)d_ws;
    ushort_t* xb     = ws;                              // 8388608
    ushort_t* Wdq_b  = ws + 8388608;                    // 3145728
    ushort_t* WuqT_b = ws + 11534336;                   // 3145728  [2048 hd][1536 q]
    ushort_t* Wqr_b  = ws + 14680064;                   // 1572864
    ushort_t* Wo_b   = ws + 16252928;                   // 4194304
    ushort_t* Wdkv_b = ws + 20447232;                   // 1310720  [640][2048] (dkv|kr|pad)
    ushort_t* WukT_b = ws + 21757952;                   // 1048576  [512][2048]
    ushort_t* WuvT_b = ws + 22806528;                   // 1048576  [512][2048]
    ushort_t* cq_b   = ws + 23855104;                   // 6291456  [4096][1536]
    ushort_t* qr_b   = ws + 30146560;                   // 4194304  [4096][1024]
    ushort_t* qnom   = ws + 34340864;                   // 8388608  [4096][2048] -> ends 42729472
    // attention aliases (valid post-qabs; Veff transient precedes Spk fill):
    ushort_t* Veff   = ws;                              // 8388608  [4096][2048] (transient)
    ushort_t* Spk    = ws;                              // 37748736 [64 z][36][128][128]
    ushort_t* VeffT  = ws + 37748736;                   // 8388608  [4][2048][1024] -> ends 46137344
    // PERSISTENT region:
    ushort_t* Mtb    = ws + 46661632;                   // 1048576  [2048][512]
    ushort_t* qfull  = ws + 47710208;                   // 37748736 [16][4096][576]
    ushort_t* kfull  = ws + 85458944;                   // 2621440  [4096][640] -> ends 88080384

    dim3 blk(256, 1, 1);

    // ---- bf16 conversions ----
    cvt_bf16<<<dim3(4096), blk, 0, stream>>>(x, xb);
    cvt_bf16<<<dim3(1536), blk, 0, stream>>>(W_dq, Wdq_b);
    cvt_bf16<<<dim3(768),  blk, 0, stream>>>(W_qr, Wqr_b);
    cvt_bf16<<<dim3(2048), blk, 0, stream>>>(W_o, Wo_b);
    // combined B for fused c_kv|c_kr: rows 0..511 = W_dkv, 512..575 = W_kr, 576..639 = 0
    cvt_bf16<<<dim3(512),  blk, 0, stream>>>(W_dkv, Wdkv_b);
    cvt_bf16<<<dim3(64),   blk, 0, stream>>>(W_kr,  Wdkv_b + 512 * 2048);
    zero_bf16<<<dim3(64),  blk, 0, stream>>>(Wdkv_b + 576 * 2048);
    // W_uq [1536][2048] -> WuqT_b [2048][1536]
    transcvt_g<<<dim3(32, 24), blk, 0, stream>>>(W_uq, WuqT_b, 2048, 1536);
    // W_uk, W_uv [2048][512] -> [512][2048]
    transcvt_g<<<dim3(8, 32), blk, 0, stream>>>(W_uk, WukT_b, 512, 2048);
    transcvt_g<<<dim3(8, 32), blk, 0, stream>>>(W_uv, WuvT_b, 512, 2048);

    // ---- projection GEMMs (all NT, bf16) ----
    // c_q = xb @ Wdq^T
    gemm_bf16<ushort_t><<<dim3(12, 32, 1), blk, 0, stream>>>(
        xb, Wdq_b, cq_b, Cn, Cn, Cn, NLQ, 0, 0, 0);
    // fused [c_kv | c_kr_pre] -> kfull[:, 0..575] (ld 640)
    gemm_bf16<ushort_t><<<dim3(5, 32, 1), blk, 0, stream>>>(
        xb, Wdkv_b, kfull, Cn, Cn, Cn, KLD, 0, 0, 0);
    rope_kr_kernel<<<dim3(BT*32/256), blk, 0, stream>>>(kfull, cosT, sinT);
    // c_qr = cq @ Wqr^T
    gemm_bf16<ushort_t><<<dim3(8, 32, 1), blk, 0, stream>>>(
        cq_b, Wqr_b, qr_b, NLQ, NLQ, NLQ, NH*DHR, 0, 0, 0);
    rope_qr_kernel<<<dim3(BT*512/256), blk, 0, stream>>>(qr_b, qfull, cosT, sinT);
    // q_nom = cq @ WuqT^T  (M=4096, N=2048, K=1536)
    gemm_bf16<ushort_t><<<dim3(16, 32, 1), blk, 0, stream>>>(
        cq_b, WuqT_b, qnom, NLQ, NLQ, NLQ, Cn, 0, 0, 0);
    // qabs[h] = q_nom_h @ Wuk_h  (K=128, per-head 128-col slices of A and B)
    gemm_bf16<ushort_t><<<dim3(4, 32, NH), blk, 0, stream>>>(
        qnom, WukT_b, qfull, HS, Cn, Cn, 576,
        128, 128, (long)BT*576);
    // Mt = Wo @ WuvT^T
    gemm_bf16<ushort_t><<<dim3(4, 16, 1), blk, 0, stream>>>(
        Wo_b, WuvT_b, Mtb, Cn, Cn, Cn, NLKV, 0, 0, 0);

    // ---- absorbed V: Veff = c_kv @ Mt^T (A = kfull cols 0..511, lda 640) ----
    gemm_bf16<ushort_t><<<dim3(16, 32, 1), blk, 0, stream>>>(
        kfull, Mtb, Veff, NLKV, KLD, NLKV, Cn, 0, 0, 0);
    transpose_veff<<<dim3(4096), blk, 0, stream>>>(Veff, VeffT);

    // ---- attention as GEMM phases (single-shot, 64 z) ----
    attn_s_gemm<<<dim3(36, 1, 64), blk, 0, stream>>>(qfull, kfull, Spk);
    attn_softmax<<<dim3(BT * NH / 4), blk, 0, stream>>>(Spk);
    attn_pv_gemm<<<dim3(8, 1, 64), blk, 0, stream>>>(Spk, VeffT, out);
}

// Round 12
// 387.143 us; speedup vs baseline: 3.6675x; 1.2393x over previous
//
#include <hip/hip_runtime.h>
#include <type_traits>

typedef unsigned short ushort_t;
typedef unsigned int   uint_t;
typedef __attribute__((ext_vector_type(8))) short bf16x8;
typedef __attribute__((ext_vector_type(4))) float f32x4;

constexpr int Bn = 4, Tn = 1024, Cn = 2048, NH = 16, HS = 128;
constexpr int NLQ = 1536, NLKV = 512, DHR = 64;
constexpr int BT = Bn * Tn;
constexpr int KLD = 640;                  // kfull leading dim (512 ckv + 64 kr + 64 pad)
constexpr float ATT_SCALE = 0.07216878364870323f; // 1/sqrt(192)
constexpr float LOG2E = 1.4426950408889634f;

__device__ __forceinline__ ushort_t f2bf(float f) {
    uint_t u = __float_as_uint(f);
    u += 0x7fffu + ((u >> 16) & 1u);   // RNE
    return (ushort_t)(u >> 16);
}

__device__ __forceinline__ void gload_lds16(const void* g, void* l) {
    __builtin_amdgcn_global_load_lds(
        (__attribute__((address_space(1))) void*)g,
        (__attribute__((address_space(3))) void*)l, 16, 0, 0);
}

// ---------------------------------------------------------------------------
// Shared 128x128 MFMA GEMM tile core (m97 structure): C128 = A128xK @ B128xK^T
// (NT). Offsets pre-folded into Ab/Bb/Cb. OutT = ushort (bf16) or f32.
// ---------------------------------------------------------------------------
template<typename OutT>
__device__ __forceinline__ void gemm_tile128(
    const ushort_t* __restrict__ Ab, int lda,
    const ushort_t* __restrict__ Bb, int ldb,
    OutT* __restrict__ Cb, int ldc, int K,
    ushort_t* As, ushort_t* Bs)
{
    constexpr int BK = 32;
    const int tid  = threadIdx.x;
    const int lane = tid & 63;
    const int w    = tid >> 6;
    const int l15 = lane & 15, l4 = lane >> 4;
    const int wr = w >> 1, wc = w & 1;
    const int srow = lane >> 2;          // 0..15
    const int scol = (lane & 3) * 8;     // octet within 32-col row

    f32x4 acc[4][4];
    #pragma unroll
    for (int m = 0; m < 4; ++m)
        #pragma unroll
        for (int n = 0; n < 4; ++n) acc[m][n] = (f32x4){0.f, 0.f, 0.f, 0.f};

    for (int k0 = 0; k0 < K; k0 += BK) {
        #pragma unroll
        for (int i = 0; i < 2; ++i) {
            int r = w * 32 + i * 16;
            gload_lds16(Ab + (long)(r + srow) * lda + k0 + scol, &As[r * BK]);
            gload_lds16(Bb + (long)(r + srow) * ldb + k0 + scol, &Bs[r * BK]);
        }
        __syncthreads();

        bf16x8 af[4], bfv[4];
        #pragma unroll
        for (int m = 0; m < 4; ++m)
            af[m] = *(const bf16x8*)&As[(wr * 64 + m * 16 + l15) * BK + l4 * 8];
        #pragma unroll
        for (int n = 0; n < 4; ++n)
            bfv[n] = *(const bf16x8*)&Bs[(wc * 64 + n * 16 + l15) * BK + l4 * 8];
        #pragma unroll
        for (int m = 0; m < 4; ++m)
            #pragma unroll
            for (int n = 0; n < 4; ++n)
                acc[m][n] = __builtin_amdgcn_mfma_f32_16x16x32_bf16(af[m], bfv[n], acc[m][n], 0, 0, 0);
        __syncthreads();
    }

    #pragma unroll
    for (int m = 0; m < 4; ++m)
        #pragma unroll
        for (int j = 0; j < 4; ++j) {
            long row = wr * 64 + m * 16 + l4 * 4 + j;
            #pragma unroll
            for (int n = 0; n < 4; ++n) {
                long col = wc * 64 + n * 16 + l15;
                if constexpr (std::is_same<OutT, float>::value)
                    Cb[row * ldc + col] = acc[m][n][j];
                else
                    Cb[row * ldc + col] = f2bf(acc[m][n][j]);
            }
        }
}

// Generic NT GEMM wrapper (batched via sA/sB/sC)
template<typename OutT>
__global__ __launch_bounds__(256, 2) void gemm_bf16(
    const ushort_t* __restrict__ A, const ushort_t* __restrict__ B,
    OutT* __restrict__ C,
    int K, int lda, int ldb, int ldc, long sA, long sB, long sC)
{
    __shared__ ushort_t As[128 * 32];
    __shared__ ushort_t Bs[128 * 32];
    const ushort_t* Ab = A + (long)blockIdx.z * sA + (long)blockIdx.y * 128 * lda;
    const ushort_t* Bb = B + (long)blockIdx.z * sB + (long)blockIdx.x * 128 * ldb;
    OutT*           Cb = C + (long)blockIdx.z * sC + (long)blockIdx.y * 128 * ldc
                           + (long)blockIdx.x * 128;
    gemm_tile128<OutT>(Ab, lda, Bb, ldb, Cb, ldc, K, As, Bs);
}

// ---------------------------------------------------------------------------
// Phase A: S lower-triangle tiles, triangle-PACKED: Spk[z][x][128][128].
// K = 192: A = [qnom_h(128) | qr_h(64)], B = [kabs_h(128) | kr(64)].
// 1D grid 2304 with XCD-bijective swizzle (same-z blocks co-locate per XCD).
// ---------------------------------------------------------------------------
__global__ __launch_bounds__(256, 2) void attn_s_gemm(
    const ushort_t* __restrict__ qnom, const ushort_t* __restrict__ qrb,
    const ushort_t* __restrict__ kabs, const ushort_t* __restrict__ kfull,
    ushort_t* __restrict__ Spk)
{
    __shared__ ushort_t As[128 * 32];
    __shared__ ushort_t Bs[128 * 32];
    const int id  = blockIdx.x;               // 0..2303
    const int sid = (id & 7) * 288 + (id >> 3);   // bijective (2304 % 8 == 0)
    const int x = sid % 36, z = sid / 36;
    int ti = 0;
    while ((ti + 1) * (ti + 2) / 2 <= x) ++ti;
    const int si = x - ti * (ti + 1) / 2;
    const int h = z >> 2, b = z & 3;

    const int tid  = threadIdx.x;
    const int lane = tid & 63;
    const int w    = tid >> 6;
    const int l15 = lane & 15, l4 = lane >> 4;
    const int wr = w >> 1, wc = w & 1;
    const int srow = lane >> 2;
    const int scol = (lane & 3) * 8;

    const ushort_t* A1 = qnom + ((long)(b * 1024 + ti * 128)) * 2048 + h * 128;
    const ushort_t* A2 = qrb  + ((long)(b * 1024 + ti * 128)) * 1024 + h * 64;
    const ushort_t* B1 = kabs + ((long)(b * 1024 + si * 128)) * 2048 + h * 128;
    const ushort_t* B2 = kfull + ((long)(b * 1024 + si * 128)) * KLD + 512;
    ushort_t* Cb = Spk + (long)z * 589824 + (long)x * 16384;

    f32x4 acc[4][4];
    #pragma unroll
    for (int m = 0; m < 4; ++m)
        #pragma unroll
        for (int n = 0; n < 4; ++n) acc[m][n] = (f32x4){0.f, 0.f, 0.f, 0.f};

    #pragma unroll
    for (int kk = 0; kk < 6; ++kk) {
        const bool qa = (kk < 4);
        const ushort_t* Asrc = qa ? A1 + kk * 32 : A2 + kk * 32 - 128;
        const ushort_t* Bsrc = qa ? B1 + kk * 32 : B2 + kk * 32 - 128;
        const int ldA = qa ? 2048 : 1024;
        const int ldB = qa ? 2048 : KLD;
        #pragma unroll
        for (int i = 0; i < 2; ++i) {
            int r = w * 32 + i * 16;
            gload_lds16(Asrc + (long)(r + srow) * ldA + scol, &As[r * 32]);
            gload_lds16(Bsrc + (long)(r + srow) * ldB + scol, &Bs[r * 32]);
        }
        __syncthreads();

        bf16x8 af[4], bfv[4];
        #pragma unroll
        for (int m = 0; m < 4; ++m)
            af[m] = *(const bf16x8*)&As[(wr * 64 + m * 16 + l15) * 32 + l4 * 8];
        #pragma unroll
        for (int n = 0; n < 4; ++n)
            bfv[n] = *(const bf16x8*)&Bs[(wc * 64 + n * 16 + l15) * 32 + l4 * 8];
        #pragma unroll
        for (int m = 0; m < 4; ++m)
            #pragma unroll
            for (int n = 0; n < 4; ++n)
                acc[m][n] = __builtin_amdgcn_mfma_f32_16x16x32_bf16(af[m], bfv[n], acc[m][n], 0, 0, 0);
        __syncthreads();
    }

    #pragma unroll
    for (int m = 0; m < 4; ++m)
        #pragma unroll
        for (int j = 0; j < 4; ++j) {
            long row = wr * 64 + m * 16 + l4 * 4 + j;
            #pragma unroll
            for (int n = 0; n < 4; ++n)
                Cb[row * 128 + wc * 64 + n * 16 + l15] = f2bf(acc[m][n][j]);
        }
}

// ---------------------------------------------------------------------------
// Phase B: in-place causal row softmax on packed S. One wave per q-row.
// ---------------------------------------------------------------------------
__global__ __launch_bounds__(256) void attn_softmax(ushort_t* __restrict__ Spk)
{
    const int wid  = threadIdx.x >> 6;
    const int lane = threadIdx.x & 63;
    const int r = blockIdx.x * 4 + wid;              // 0..65535
    const int z = r >> 10, t = r & 1023;
    const int ti = t >> 7;
    const int nc = ti + 1;                           // valid 128-col chunks
    ushort_t* base = Spk + (long)z * 589824 + (long)(ti * (ti + 1) / 2) * 16384
                        + (t & 127) * 128;
    const float SCL = ATT_SCALE * LOG2E;

    float p0[8], p1[8];
    float mx = -INFINITY;
    #pragma unroll
    for (int c = 0; c < 8; ++c) {
        p0[c] = -INFINITY; p1[c] = -INFINITY;
        if (c < nc) {
            uint_t u = *(const uint_t*)&base[c * 16384 + lane * 2];
            int kv = c * 128 + lane * 2;
            float a  = __uint_as_float(u << 16);
            float bb = __uint_as_float(u & 0xffff0000u);
            if (kv     <= t) p0[c] = a  * SCL;
            if (kv + 1 <= t) p1[c] = bb * SCL;
            mx = fmaxf(mx, fmaxf(p0[c], p1[c]));
        }
    }
    #pragma unroll
    for (int off = 32; off >= 1; off >>= 1) mx = fmaxf(mx, __shfl_xor(mx, off));
    float s = 0.f;
    #pragma unroll
    for (int c = 0; c < 8; ++c) {
        p0[c] = exp2f(p0[c] - mx);                   // -inf -> 0
        p1[c] = exp2f(p1[c] - mx);
        if (c < nc) s += p0[c] + p1[c];
    }
    #pragma unroll
    for (int off = 32; off >= 1; off >>= 1) s += __shfl_xor(s, off);
    const float inv = 1.f / s;
    #pragma unroll
    for (int c = 0; c < 8; ++c) if (c < nc) {
        uint_t o = (uint_t)f2bf(p0[c] * inv) | ((uint_t)f2bf(p1[c] * inv) << 16);
        *(uint_t*)&base[c * 16384 + lane * 2] = o;
    }
}

// ---------------------------------------------------------------------------
// Phase C: out[b, ti-rows, h*128..] = P @ VeffT_h^T, written f32 directly.
// 1D grid 512, XCD swizzle; z fast within XCD chunk (VeffT/Spk locality).
// ---------------------------------------------------------------------------
__global__ __launch_bounds__(256, 2) void attn_pv_gemm(
    const ushort_t* __restrict__ Spk, const ushort_t* __restrict__ VeffT,
    float* __restrict__ out)
{
    __shared__ ushort_t As[128 * 32];
    __shared__ ushort_t Bs[128 * 32];
    const int id  = blockIdx.x;               // 0..511
    const int sid = (id & 7) * 64 + (id >> 3);
    const int ti = sid & 7, z = sid >> 3;
    const int tid  = threadIdx.x;
    const int lane = tid & 63;
    const int w    = tid >> 6;
    const int l15 = lane & 15, l4 = lane >> 4;
    const int wr = w >> 1, wc = w & 1;
    const int srow = lane >> 2;
    const int scol = (lane & 3) * 8;
    const int h = z >> 2, b = z & 3;
    const int K = (ti + 1) * 128;
    const ushort_t* Abase = Spk + (long)z * 589824 + (long)(ti * (ti + 1) / 2) * 16384;
    const ushort_t* Bb = VeffT + ((long)b * 2048 + h * 128) * 1024;
    float* Cb = out + ((long)b * 1024 + ti * 128) * 2048 + h * 128;

    f32x4 acc[4][4];
    #pragma unroll
    for (int m = 0; m < 4; ++m)
        #pragma unroll
        for (int n = 0; n < 4; ++n) acc[m][n] = (f32x4){0.f, 0.f, 0.f, 0.f};

    for (int k0 = 0; k0 < K; k0 += 32) {
        const ushort_t* At = Abase + (k0 >> 7) * 16384 + (k0 & 127);
        #pragma unroll
        for (int i = 0; i < 2; ++i) {
            int r = w * 32 + i * 16;
            gload_lds16(At + (long)(r + srow) * 128 + scol, &As[r * 32]);
            gload_lds16(Bb + (long)(r + srow) * 1024 + k0 + scol, &Bs[r * 32]);
        }
        __syncthreads();

        bf16x8 af[4], bfv[4];
        #pragma unroll
        for (int m = 0; m < 4; ++m)
            af[m] = *(const bf16x8*)&As[(wr * 64 + m * 16 + l15) * 32 + l4 * 8];
        #pragma unroll
        for (int n = 0; n < 4; ++n)
            bfv[n] = *(const bf16x8*)&Bs[(wc * 64 + n * 16 + l15) * 32 + l4 * 8];
        #pragma unroll
        for (int m = 0; m < 4; ++m)
            #pragma unroll
            for (int n = 0; n < 4; ++n)
                acc[m][n] = __builtin_amdgcn_mfma_f32_16x16x32_bf16(af[m], bfv[n], acc[m][n], 0, 0, 0);
        __syncthreads();
    }

    #pragma unroll
    for (int m = 0; m < 4; ++m)
        #pragma unroll
        for (int j = 0; j < 4; ++j) {
            long row = wr * 64 + m * 16 + l4 * 4 + j;
            #pragma unroll
            for (int n = 0; n < 4; ++n)
                Cb[row * 2048 + wc * 64 + n * 16 + l15] = acc[m][n][j];
        }
}

// ---------------------------------------------------------------------------
// f32 -> bf16 conversion (vectorized, 8/thread). n must be multiple of 2048.
// ---------------------------------------------------------------------------
__global__ void cvt_bf16(const float* __restrict__ in, ushort_t* __restrict__ out) {
    long i = ((long)blockIdx.x * 256 + threadIdx.x) * 8;
    float4 a = *(const float4*)&in[i];
    float4 b = *(const float4*)&in[i + 4];
    ushort_t p[8] = {f2bf(a.x), f2bf(a.y), f2bf(a.z), f2bf(a.w),
                     f2bf(b.x), f2bf(b.y), f2bf(b.z), f2bf(b.w)};
    *(uint4*)&out[i] = *(const uint4*)p;
}

// zero-fill (8 ushorts/thread)
__global__ void zero_bf16(ushort_t* __restrict__ out) {
    long i = ((long)blockIdx.x * 256 + threadIdx.x) * 8;
    *(uint4*)&out[i] = make_uint4(0, 0, 0, 0);
}

// ---------------------------------------------------------------------------
// Generic transpose+convert: in [R][ldin] f32 (row-major) -> out [ldin][R] bf16.
// ---------------------------------------------------------------------------
__global__ __launch_bounds__(256) void transcvt_g(
    const float* __restrict__ in, ushort_t* __restrict__ out, int ldin, int R)
{
    __shared__ float tile[64][65];
    const int c0 = blockIdx.x * 64, r0 = blockIdx.y * 64;
    const int t = threadIdx.x;
    #pragma unroll
    for (int i = 0; i < 4; ++i) {
        int idx = t + i * 256;
        int r = idx >> 4, c4 = idx & 15;
        float4 v = *(const float4*)&in[(long)(r0 + r) * ldin + c0 + c4 * 4];
        tile[r][c4 * 4 + 0] = v.x; tile[r][c4 * 4 + 1] = v.y;
        tile[r][c4 * 4 + 2] = v.z; tile[r][c4 * 4 + 3] = v.w;
    }
    __syncthreads();
    #pragma unroll
    for (int i = 0; i < 4; ++i) {
        int idx = t + i * 256;
        int c = idx >> 4, r4 = idx & 15;
        ushort_t p[4];
        #pragma unroll
        for (int j = 0; j < 4; ++j) p[j] = f2bf(tile[r4 * 4 + j][c]);
        *(uint2*)&out[(long)(c0 + c) * R + r0 + r4 * 4] = *(const uint2*)p;
    }
}

// ---------------------------------------------------------------------------
// RoPE kernels (both in-place, bf16)
// ---------------------------------------------------------------------------
__global__ void rope_kr_kernel(ushort_t* __restrict__ kfull,
                               const float* __restrict__ cosT, const float* __restrict__ sinT) {
    int p = blockIdx.x * 256 + threadIdx.x;          // BT*32 pairs
    if (p >= BT * 32) return;
    int bt = p >> 5, i = p & 31;
    int t = bt & (Tn - 1);
    float c = cosT[t * 32 + i], s = sinT[t * 32 + i];
    uint_t u = *(const uint_t*)&kfull[(long)bt * KLD + 512 + 2 * i];
    float re = __uint_as_float(u << 16);
    float im = __uint_as_float(u & 0xffff0000u);
    float o0 = re * c - im * s, o1 = re * s + im * c;
    uint_t o = (uint_t)f2bf(o0) | ((uint_t)f2bf(o1) << 16);
    *(uint_t*)&kfull[(long)bt * KLD + 512 + 2 * i] = o;
}

__global__ void rope_qr_kernel(ushort_t* __restrict__ qrb,
                               const float* __restrict__ cosT, const float* __restrict__ sinT) {
    int p = blockIdx.x * 256 + threadIdx.x;          // BT*NH*32 pairs
    if (p >= BT * 512) return;
    int bt = p >> 9, rem = p & 511;
    int hh = rem >> 5, i = rem & 31;
    int t = bt & (Tn - 1);
    float c = cosT[t * 32 + i], s = sinT[t * 32 + i];
    long off = (long)bt * 1024 + hh * 64 + 2 * i;
    uint_t u = *(const uint_t*)&qrb[off];
    float re = __uint_as_float(u << 16);
    float im = __uint_as_float(u & 0xffff0000u);
    float o0 = re * c - im * s, o1 = re * s + im * c;
    uint_t o = (uint_t)f2bf(o0) | ((uint_t)f2bf(o1) << 16);
    *(uint_t*)&qrb[off] = o;
}

// ---------------------------------------------------------------------------
// Transpose Veff [4096 bs][2048 hd] -> VeffT [4 b][2048 hd][1024 s] (bf16)
// ---------------------------------------------------------------------------
__global__ void transpose_veff(const ushort_t* __restrict__ Veff, ushort_t* __restrict__ VeffT) {
    int idx = blockIdx.x * 256 + threadIdx.x;        // 4*128*2048 = 1048576
    int c = idx & 2047, rest = idx >> 11;
    int t8 = rest & 127, b = rest >> 7;
    ushort_t v[8];
    #pragma unroll
    for (int j = 0; j < 8; ++j)
        v[j] = Veff[((long)b * Tn + t8 * 8 + j) * 2048 + c];
    *(uint4*)&VeffT[((long)b * 2048 + c) * Tn + t8 * 8] = *(const uint4*)v;
}

// ---------------------------------------------------------------------------
extern "C" void kernel_launch(void* const* d_in, const int* in_sizes, int n_in,
                              void* d_out, int out_size, void* d_ws, size_t ws_size,
                              hipStream_t stream)
{
    (void)in_sizes; (void)n_in; (void)out_size; (void)ws_size;
    const float* x     = (const float*)d_in[0];
    const float* cosT  = (const float*)d_in[1];
    const float* sinT  = (const float*)d_in[2];
    const float* W_dq  = (const float*)d_in[3];   // [1536][2048]
    const float* W_uq  = (const float*)d_in[4];   // [1536 q][2048 hd]
    const float* W_dkv = (const float*)d_in[5];   // [512][2048]
    const float* W_uk  = (const float*)d_in[6];   // [2048 hd][512 k]  (NT-ready!)
    const float* W_uv  = (const float*)d_in[7];   // [2048][512]
    const float* W_qr  = (const float*)d_in[8];   // [1024][1536]
    const float* W_kr  = (const float*)d_in[9];   // [64][2048]
    const float* W_o   = (const float*)d_in[10];  // [2048][2048]
    float* out = (float*)d_out;

    // ---- workspace: 70,778,880 ushorts = 141.6 MB (was 180.9) ----
    // SCRATCH [0, 30146560): conversions + cq; dead before attention.
    // Veff (transient) aliases [0, 8388608); Spk aliases [0, 37748736).
    ushort_t* ws = (ushort_t*)d_ws;
    ushort_t* xb     = ws;                              // 8388608
    ushort_t* Wdq_b  = ws + 8388608;                    // 3145728
    ushort_t* WuqT_b = ws + 11534336;                   // 3145728  [2048 hd][1536 q]
    ushort_t* Wqr_b  = ws + 14680064;                   // 1572864
    ushort_t* Wo_b   = ws + 16252928;                   // 4194304
    ushort_t* Wdkv_b = ws + 20447232;                   // 1310720  [640][2048] (dkv|kr|pad)
    ushort_t* Wuk_b  = ws + 21757952;                   // 1048576  [2048][512] plain cvt
    ushort_t* WuvT_b = ws + 22806528;                   // 1048576  [512][2048]
    ushort_t* cq_b   = ws + 23855104;                   // 6291456  [4096][1536] -> 30146560
    // aliases:
    ushort_t* Veff   = ws;                              // 8388608 (transient, pre-attn)
    ushort_t* Spk    = ws;                              // 37748736 [64 z][36][128][128]
    // PERSISTENT region (live through attention):
    ushort_t* qnom   = ws + 37748736;                   // 8388608  [4096][2048]
    ushort_t* qr_b   = ws + 46137344;                   // 4194304  [4096][1024]
    ushort_t* kabs   = ws + 50331648;                   // 8388608  [4096][2048]
    ushort_t* kfull  = ws + 58720256;                   // 2621440  [4096][640]
    ushort_t* Mtb    = ws + 61341696;                   // 1048576  [2048][512]
    ushort_t* VeffT  = ws + 62390272;                   // 8388608  [4][2048][1024] -> 70778880

    dim3 blk(256, 1, 1);

    // ---- bf16 conversions ----
    cvt_bf16<<<dim3(4096), blk, 0, stream>>>(x, xb);
    cvt_bf16<<<dim3(1536), blk, 0, stream>>>(W_dq, Wdq_b);
    cvt_bf16<<<dim3(768),  blk, 0, stream>>>(W_qr, Wqr_b);
    cvt_bf16<<<dim3(2048), blk, 0, stream>>>(W_o, Wo_b);
    cvt_bf16<<<dim3(512),  blk, 0, stream>>>(W_uk, Wuk_b);        // already NT
    // combined B for fused c_kv|c_kr: rows 0..511 = W_dkv, 512..575 = W_kr, pad 0
    cvt_bf16<<<dim3(512),  blk, 0, stream>>>(W_dkv, Wdkv_b);
    cvt_bf16<<<dim3(64),   blk, 0, stream>>>(W_kr,  Wdkv_b + 512 * 2048);
    zero_bf16<<<dim3(64),  blk, 0, stream>>>(Wdkv_b + 576 * 2048);
    // W_uq [1536][2048] -> WuqT_b [2048][1536]; W_uv [2048][512] -> [512][2048]
    transcvt_g<<<dim3(32, 24), blk, 0, stream>>>(W_uq, WuqT_b, 2048, 1536);
    transcvt_g<<<dim3(8, 32), blk, 0, stream>>>(W_uv, WuvT_b, 512, 2048);

    // ---- projection GEMMs (all NT, bf16) ----
    // c_q = xb @ Wdq^T
    gemm_bf16<ushort_t><<<dim3(12, 32, 1), blk, 0, stream>>>(
        xb, Wdq_b, cq_b, Cn, Cn, Cn, NLQ, 0, 0, 0);
    // fused [c_kv | c_kr_pre] -> kfull (ld 640)
    gemm_bf16<ushort_t><<<dim3(5, 32, 1), blk, 0, stream>>>(
        xb, Wdkv_b, kfull, Cn, Cn, Cn, KLD, 0, 0, 0);
    rope_kr_kernel<<<dim3(BT*32/256), blk, 0, stream>>>(kfull, cosT, sinT);
    // c_qr = cq @ Wqr^T -> qr_b, then rope in-place
    gemm_bf16<ushort_t><<<dim3(8, 32, 1), blk, 0, stream>>>(
        cq_b, Wqr_b, qr_b, NLQ, NLQ, NLQ, NH*DHR, 0, 0, 0);
    rope_qr_kernel<<<dim3(BT*512/256), blk, 0, stream>>>(qr_b, cosT, sinT);
    // q_nom = cq @ WuqT^T  (M=4096, N=2048, K=1536)
    gemm_bf16<ushort_t><<<dim3(16, 32, 1), blk, 0, stream>>>(
        cq_b, WuqT_b, qnom, NLQ, NLQ, NLQ, Cn, 0, 0, 0);
    // kabs = c_kv @ W_uk^T  (M=4096, N=2048, K=512; A = kfull cols 0..511)
    gemm_bf16<ushort_t><<<dim3(16, 32, 1), blk, 0, stream>>>(
        kfull, Wuk_b, kabs, NLKV, KLD, NLKV, Cn, 0, 0, 0);
    // Mt = Wo @ WuvT^T
    gemm_bf16<ushort_t><<<dim3(4, 16, 1), blk, 0, stream>>>(
        Wo_b, WuvT_b, Mtb, Cn, Cn, Cn, NLKV, 0, 0, 0);
    // Veff = c_kv @ Mt^T  (transient at ws+0; xb dead by now)
    gemm_bf16<ushort_t><<<dim3(16, 32, 1), blk, 0, stream>>>(
        kfull, Mtb, Veff, NLKV, KLD, NLKV, Cn, 0, 0, 0);
    transpose_veff<<<dim3(4096), blk, 0, stream>>>(Veff, VeffT);

    // ---- attention as GEMM phases (single-shot, 64 z) ----
    attn_s_gemm<<<dim3(2304, 1, 1), blk, 0, stream>>>(qnom, qr_b, kabs, kfull, Spk);
    attn_softmax<<<dim3(BT * NH / 4), blk, 0, stream>>>(Spk);
    attn_pv_gemm<<<dim3(512, 1, 1), blk, 0, stream>>>(Spk, VeffT, out);
}

// Round 13
// 310.832 us; speedup vs baseline: 4.5678x; 1.2455x over previous
//
#include <hip/hip_runtime.h>
#include <type_traits>

typedef unsigned short ushort_t;
typedef unsigned int   uint_t;
typedef __attribute__((ext_vector_type(8))) short bf16x8;
typedef __attribute__((ext_vector_type(4))) float f32x4;

constexpr int Bn = 4, Tn = 1024, Cn = 2048, NH = 16, HS = 128;
constexpr int NLQ = 1536, NLKV = 512, DHR = 64;
constexpr int BT = Bn * Tn;
constexpr int KLD = 640;                  // kfull leading dim (512 ckv + 64 kr + 64 pad)
constexpr float ATT_SCALE = 0.07216878364870323f; // 1/sqrt(192)
constexpr float LOG2E = 1.4426950408889634f;

__device__ __forceinline__ ushort_t f2bf(float f) {
    uint_t u = __float_as_uint(f);
    u += 0x7fffu + ((u >> 16) & 1u);   // RNE
    return (ushort_t)(u >> 16);
}

__device__ __forceinline__ void gload_lds16(const void* g, void* l) {
    __builtin_amdgcn_global_load_lds(
        (__attribute__((address_space(1))) void*)g,
        (__attribute__((address_space(3))) void*)l, 16, 0, 0);
}

// ---------------------------------------------------------------------------
// Shared 128x128 MFMA GEMM tile core (m97 structure): C128 = A128xK @ B128xK^T
// (NT). Offsets pre-folded into Ab/Bb/Cb. OutT = ushort (bf16) or f32.
// ---------------------------------------------------------------------------
template<typename OutT>
__device__ __forceinline__ void gemm_tile128(
    const ushort_t* __restrict__ Ab, int lda,
    const ushort_t* __restrict__ Bb, int ldb,
    OutT* __restrict__ Cb, int ldc, int K,
    ushort_t* As, ushort_t* Bs)
{
    constexpr int BK = 32;
    const int tid  = threadIdx.x;
    const int lane = tid & 63;
    const int w    = tid >> 6;
    const int l15 = lane & 15, l4 = lane >> 4;
    const int wr = w >> 1, wc = w & 1;
    const int srow = lane >> 2;          // 0..15
    const int scol = (lane & 3) * 8;     // octet within 32-col row

    f32x4 acc[4][4];
    #pragma unroll
    for (int m = 0; m < 4; ++m)
        #pragma unroll
        for (int n = 0; n < 4; ++n) acc[m][n] = (f32x4){0.f, 0.f, 0.f, 0.f};

    for (int k0 = 0; k0 < K; k0 += BK) {
        #pragma unroll
        for (int i = 0; i < 2; ++i) {
            int r = w * 32 + i * 16;
            gload_lds16(Ab + (long)(r + srow) * lda + k0 + scol, &As[r * BK]);
            gload_lds16(Bb + (long)(r + srow) * ldb + k0 + scol, &Bs[r * BK]);
        }
        __syncthreads();

        bf16x8 af[4], bfv[4];
        #pragma unroll
        for (int m = 0; m < 4; ++m)
            af[m] = *(const bf16x8*)&As[(wr * 64 + m * 16 + l15) * BK + l4 * 8];
        #pragma unroll
        for (int n = 0; n < 4; ++n)
            bfv[n] = *(const bf16x8*)&Bs[(wc * 64 + n * 16 + l15) * BK + l4 * 8];
        #pragma unroll
        for (int m = 0; m < 4; ++m)
            #pragma unroll
            for (int n = 0; n < 4; ++n)
                acc[m][n] = __builtin_amdgcn_mfma_f32_16x16x32_bf16(af[m], bfv[n], acc[m][n], 0, 0, 0);
        __syncthreads();
    }

    #pragma unroll
    for (int m = 0; m < 4; ++m)
        #pragma unroll
        for (int j = 0; j < 4; ++j) {
            long row = wr * 64 + m * 16 + l4 * 4 + j;
            #pragma unroll
            for (int n = 0; n < 4; ++n) {
                long col = wc * 64 + n * 16 + l15;
                if constexpr (std::is_same<OutT, float>::value)
                    Cb[row * ldc + col] = acc[m][n][j];
                else
                    Cb[row * ldc + col] = f2bf(acc[m][n][j]);
            }
        }
}

// Generic NT GEMM wrapper
template<typename OutT>
__global__ __launch_bounds__(256, 2) void gemm_bf16(
    const ushort_t* __restrict__ A, const ushort_t* __restrict__ B,
    OutT* __restrict__ C,
    int K, int lda, int ldb, int ldc)
{
    __shared__ ushort_t As[128 * 32];
    __shared__ ushort_t Bs[128 * 32];
    const ushort_t* Ab = A + (long)blockIdx.y * 128 * lda;
    const ushort_t* Bb = B + (long)blockIdx.x * 128 * ldb;
    OutT*           Cb = C + (long)blockIdx.y * 128 * ldc + (long)blockIdx.x * 128;
    gemm_tile128<OutT>(Ab, lda, Bb, ldb, Cb, ldc, K, As, Bs);
}

// Split-output NT GEMM: combined B rows (ldb=K), C1 for n-tiles < split, C2 after.
__global__ __launch_bounds__(256, 2) void gemm_split(
    const ushort_t* __restrict__ A, int lda, int K,
    const ushort_t* __restrict__ B,
    ushort_t* __restrict__ C1, int ldc1, int split,
    ushort_t* __restrict__ C2, int ldc2)
{
    __shared__ ushort_t As[128 * 32];
    __shared__ ushort_t Bs[128 * 32];
    const int nt = blockIdx.x, mt = blockIdx.y;
    const ushort_t* Ab = A + (long)mt * 128 * lda;
    const ushort_t* Bb = B + (long)nt * 128 * K;
    ushort_t* Cb; int ldc;
    if (nt < split) { Cb = C1 + (long)mt * 128 * ldc1 + nt * 128;           ldc = ldc1; }
    else            { Cb = C2 + (long)mt * 128 * ldc2 + (nt - split) * 128; ldc = ldc2; }
    gemm_tile128<ushort_t>(Ab, lda, Bb, K, Cb, ldc, K, As, Bs);
}

// ---------------------------------------------------------------------------
// Phase A: S lower-triangle tiles, triangle-PACKED: Spk[z][x][128][128].
// K = 192: A = [qnom_h(128) | qr_h(64)], B = [kabs_h(128) | kr(64)].
// 1D grid 2304 with XCD-bijective swizzle.
// ---------------------------------------------------------------------------
__global__ __launch_bounds__(256, 2) void attn_s_gemm(
    const ushort_t* __restrict__ qnom, const ushort_t* __restrict__ qrb,
    const ushort_t* __restrict__ kabs, const ushort_t* __restrict__ kfull,
    ushort_t* __restrict__ Spk)
{
    __shared__ ushort_t As[128 * 32];
    __shared__ ushort_t Bs[128 * 32];
    const int id  = blockIdx.x;               // 0..2303
    const int sid = (id & 7) * 288 + (id >> 3);   // bijective (2304 % 8 == 0)
    const int x = sid % 36, z = sid / 36;
    int ti = 0;
    while ((ti + 1) * (ti + 2) / 2 <= x) ++ti;
    const int si = x - ti * (ti + 1) / 2;
    const int h = z >> 2, b = z & 3;

    const int tid  = threadIdx.x;
    const int lane = tid & 63;
    const int w    = tid >> 6;
    const int l15 = lane & 15, l4 = lane >> 4;
    const int wr = w >> 1, wc = w & 1;
    const int srow = lane >> 2;
    const int scol = (lane & 3) * 8;

    const ushort_t* A1 = qnom + ((long)(b * 1024 + ti * 128)) * 2048 + h * 128;
    const ushort_t* A2 = qrb  + ((long)(b * 1024 + ti * 128)) * 1024 + h * 64;
    const ushort_t* B1 = kabs + ((long)(b * 1024 + si * 128)) * 2048 + h * 128;
    const ushort_t* B2 = kfull + ((long)(b * 1024 + si * 128)) * KLD + 512;
    ushort_t* Cb = Spk + (long)z * 589824 + (long)x * 16384;

    f32x4 acc[4][4];
    #pragma unroll
    for (int m = 0; m < 4; ++m)
        #pragma unroll
        for (int n = 0; n < 4; ++n) acc[m][n] = (f32x4){0.f, 0.f, 0.f, 0.f};

    #pragma unroll
    for (int kk = 0; kk < 6; ++kk) {
        const bool qa = (kk < 4);
        const ushort_t* Asrc = qa ? A1 + kk * 32 : A2 + kk * 32 - 128;
        const ushort_t* Bsrc = qa ? B1 + kk * 32 : B2 + kk * 32 - 128;
        const int ldA = qa ? 2048 : 1024;
        const int ldB = qa ? 2048 : KLD;
        #pragma unroll
        for (int i = 0; i < 2; ++i) {
            int r = w * 32 + i * 16;
            gload_lds16(Asrc + (long)(r + srow) * ldA + scol, &As[r * 32]);
            gload_lds16(Bsrc + (long)(r + srow) * ldB + scol, &Bs[r * 32]);
        }
        __syncthreads();

        bf16x8 af[4], bfv[4];
        #pragma unroll
        for (int m = 0; m < 4; ++m)
            af[m] = *(const bf16x8*)&As[(wr * 64 + m * 16 + l15) * 32 + l4 * 8];
        #pragma unroll
        for (int n = 0; n < 4; ++n)
            bfv[n] = *(const bf16x8*)&Bs[(wc * 64 + n * 16 + l15) * 32 + l4 * 8];
        #pragma unroll
        for (int m = 0; m < 4; ++m)
            #pragma unroll
            for (int n = 0; n < 4; ++n)
                acc[m][n] = __builtin_amdgcn_mfma_f32_16x16x32_bf16(af[m], bfv[n], acc[m][n], 0, 0, 0);
        __syncthreads();
    }

    #pragma unroll
    for (int m = 0; m < 4; ++m)
        #pragma unroll
        for (int j = 0; j < 4; ++j) {
            long row = wr * 64 + m * 16 + l4 * 4 + j;
            #pragma unroll
            for (int n = 0; n < 4; ++n)
                Cb[row * 128 + wc * 64 + n * 16 + l15] = f2bf(acc[m][n][j]);
        }
}

// ---------------------------------------------------------------------------
// Phase B: in-place causal row softmax on packed S. One wave per q-row.
// ---------------------------------------------------------------------------
__global__ __launch_bounds__(256) void attn_softmax(ushort_t* __restrict__ Spk)
{
    const int wid  = threadIdx.x >> 6;
    const int lane = threadIdx.x & 63;
    const int r = blockIdx.x * 4 + wid;              // 0..65535
    const int z = r >> 10, t = r & 1023;
    const int ti = t >> 7;
    const int nc = ti + 1;                           // valid 128-col chunks
    ushort_t* base = Spk + (long)z * 589824 + (long)(ti * (ti + 1) / 2) * 16384
                        + (t & 127) * 128;
    const float SCL = ATT_SCALE * LOG2E;

    float p0[8], p1[8];
    float mx = -INFINITY;
    #pragma unroll
    for (int c = 0; c < 8; ++c) {
        p0[c] = -INFINITY; p1[c] = -INFINITY;
        if (c < nc) {
            uint_t u = *(const uint_t*)&base[c * 16384 + lane * 2];
            int kv = c * 128 + lane * 2;
            float a  = __uint_as_float(u << 16);
            float bb = __uint_as_float(u & 0xffff0000u);
            if (kv     <= t) p0[c] = a  * SCL;
            if (kv + 1 <= t) p1[c] = bb * SCL;
            mx = fmaxf(mx, fmaxf(p0[c], p1[c]));
        }
    }
    #pragma unroll
    for (int off = 32; off >= 1; off >>= 1) mx = fmaxf(mx, __shfl_xor(mx, off));
    float s = 0.f;
    #pragma unroll
    for (int c = 0; c < 8; ++c) {
        p0[c] = exp2f(p0[c] - mx);                   // -inf -> 0
        p1[c] = exp2f(p1[c] - mx);
        if (c < nc) s += p0[c] + p1[c];
    }
    #pragma unroll
    for (int off = 32; off >= 1; off >>= 1) s += __shfl_xor(s, off);
    const float inv = 1.f / s;
    #pragma unroll
    for (int c = 0; c < 8; ++c) if (c < nc) {
        uint_t o = (uint_t)f2bf(p0[c] * inv) | ((uint_t)f2bf(p1[c] * inv) << 16);
        *(uint_t*)&base[c * 16384 + lane * 2] = o;
    }
}

// ---------------------------------------------------------------------------
// Phase C: out[b, ti-rows, h*128..] = P @ VeffT_h^T, written f32 directly.
// 1D grid 512, XCD swizzle.
// ---------------------------------------------------------------------------
__global__ __launch_bounds__(256, 2) void attn_pv_gemm(
    const ushort_t* __restrict__ Spk, const ushort_t* __restrict__ VeffT,
    float* __restrict__ out)
{
    __shared__ ushort_t As[128 * 32];
    __shared__ ushort_t Bs[128 * 32];
    const int id  = blockIdx.x;               // 0..511
    const int sid = (id & 7) * 64 + (id >> 3);
    const int ti = sid & 7, z = sid >> 3;
    const int tid  = threadIdx.x;
    const int lane = tid & 63;
    const int w    = tid >> 6;
    const int l15 = lane & 15, l4 = lane >> 4;
    const int wr = w >> 1, wc = w & 1;
    const int srow = lane >> 2;
    const int scol = (lane & 3) * 8;
    const int h = z >> 2, b = z & 3;
    const int K = (ti + 1) * 128;
    const ushort_t* Abase = Spk + (long)z * 589824 + (long)(ti * (ti + 1) / 2) * 16384;
    const ushort_t* Bb = VeffT + ((long)b * 2048 + h * 128) * 1024;
    float* Cb = out + ((long)b * 1024 + ti * 128) * 2048 + h * 128;

    f32x4 acc[4][4];
    #pragma unroll
    for (int m = 0; m < 4; ++m)
        #pragma unroll
        for (int n = 0; n < 4; ++n) acc[m][n] = (f32x4){0.f, 0.f, 0.f, 0.f};

    for (int k0 = 0; k0 < K; k0 += 32) {
        const ushort_t* At = Abase + (k0 >> 7) * 16384 + (k0 & 127);
        #pragma unroll
        for (int i = 0; i < 2; ++i) {
            int r = w * 32 + i * 16;
            gload_lds16(At + (long)(r + srow) * 128 + scol, &As[r * 32]);
            gload_lds16(Bb + (long)(r + srow) * 1024 + k0 + scol, &Bs[r * 32]);
        }
        __syncthreads();

        bf16x8 af[4], bfv[4];
        #pragma unroll
        for (int m = 0; m < 4; ++m)
            af[m] = *(const bf16x8*)&As[(wr * 64 + m * 16 + l15) * 32 + l4 * 8];
        #pragma unroll
        for (int n = 0; n < 4; ++n)
            bfv[n] = *(const bf16x8*)&Bs[(wc * 64 + n * 16 + l15) * 32 + l4 * 8];
        #pragma unroll
        for (int m = 0; m < 4; ++m)
            #pragma unroll
            for (int n = 0; n < 4; ++n)
                acc[m][n] = __builtin_amdgcn_mfma_f32_16x16x32_bf16(af[m], bfv[n], acc[m][n], 0, 0, 0);
        __syncthreads();
    }

    #pragma unroll
    for (int m = 0; m < 4; ++m)
        #pragma unroll
        for (int j = 0; j < 4; ++j) {
            long row = wr * 64 + m * 16 + l4 * 4 + j;
            #pragma unroll
            for (int n = 0; n < 4; ++n)
                Cb[row * 2048 + wc * 64 + n * 16 + l15] = acc[m][n][j];
        }
}

// ---------------------------------------------------------------------------
// Fused f32->bf16 conversion for all plain-layout operands. One block = 2048
// contiguous elements. Range-dispatch over the concatenated job list.
// ---------------------------------------------------------------------------
__global__ void cvt_all(const float* __restrict__ x,   const float* __restrict__ Wdq,
                        const float* __restrict__ Wdkv, const float* __restrict__ Wkr,
                        const float* __restrict__ Wqr,  const float* __restrict__ Wo,
                        const float* __restrict__ Wuk,
                        ushort_t* __restrict__ xb, ushort_t* __restrict__ WB1,
                        ushort_t* __restrict__ WB2, ushort_t* __restrict__ Wo_b,
                        ushort_t* __restrict__ WB3)
{
    const int bid = blockIdx.x;
    const float* src = nullptr; ushort_t* dst;
    if      (bid < 4096) { src = x    + (long)bid * 2048;          dst = xb   + (long)bid * 2048; }
    else if (bid < 5632) { long b = bid - 4096; src = Wdq  + b * 2048; dst = WB1 + b * 2048; }
    else if (bid < 6144) { long b = bid - 5632; src = Wdkv + b * 2048; dst = WB1 + 3145728 + b * 2048; }
    else if (bid < 6208) { long b = bid - 6144; src = Wkr  + b * 2048; dst = WB1 + 4194304 + b * 2048; }
    else if (bid < 6272) { long b = bid - 6208;                        dst = WB1 + 4325376 + b * 2048; }
    else if (bid < 7040) { long b = bid - 6272; src = Wqr  + b * 2048; dst = WB2 + 3145728 + b * 2048; }
    else if (bid < 9088) { long b = bid - 7040; src = Wo   + b * 2048; dst = Wo_b + b * 2048; }
    else                 { long b = bid - 9088; src = Wuk  + b * 2048; dst = WB3 + b * 2048; }

    const long i = (long)threadIdx.x * 8;
    if (!src) { *(uint4*)&dst[i] = make_uint4(0, 0, 0, 0); return; }
    float4 a = *(const float4*)&src[i];
    float4 b4 = *(const float4*)&src[i + 4];
    ushort_t p[8] = {f2bf(a.x), f2bf(a.y), f2bf(a.z), f2bf(a.w),
                     f2bf(b4.x), f2bf(b4.y), f2bf(b4.z), f2bf(b4.w)};
    *(uint4*)&dst[i] = *(const uint4*)p;
}

// ---------------------------------------------------------------------------
// Generic transpose+convert: in [R][ldin] f32 (row-major) -> out [ldin][R] bf16.
// ---------------------------------------------------------------------------
__global__ __launch_bounds__(256) void transcvt_g(
    const float* __restrict__ in, ushort_t* __restrict__ out, int ldin, int R)
{
    __shared__ float tile[64][65];
    const int c0 = blockIdx.x * 64, r0 = blockIdx.y * 64;
    const int t = threadIdx.x;
    #pragma unroll
    for (int i = 0; i < 4; ++i) {
        int idx = t + i * 256;
        int r = idx >> 4, c4 = idx & 15;
        float4 v = *(const float4*)&in[(long)(r0 + r) * ldin + c0 + c4 * 4];
        tile[r][c4 * 4 + 0] = v.x; tile[r][c4 * 4 + 1] = v.y;
        tile[r][c4 * 4 + 2] = v.z; tile[r][c4 * 4 + 3] = v.w;
    }
    __syncthreads();
    #pragma unroll
    for (int i = 0; i < 4; ++i) {
        int idx = t + i * 256;
        int c = idx >> 4, r4 = idx & 15;
        ushort_t p[4];
        #pragma unroll
        for (int j = 0; j < 4; ++j) p[j] = f2bf(tile[r4 * 4 + j][c]);
        *(uint2*)&out[(long)(c0 + c) * R + r0 + r4 * 4] = *(const uint2*)p;
    }
}

// ---------------------------------------------------------------------------
// RoPE kernels (both in-place, bf16)
// ---------------------------------------------------------------------------
__global__ void rope_kr_kernel(ushort_t* __restrict__ kfull,
                               const float* __restrict__ cosT, const float* __restrict__ sinT) {
    int p = blockIdx.x * 256 + threadIdx.x;          // BT*32 pairs
    if (p >= BT * 32) return;
    int bt = p >> 5, i = p & 31;
    int t = bt & (Tn - 1);
    float c = cosT[t * 32 + i], s = sinT[t * 32 + i];
    uint_t u = *(const uint_t*)&kfull[(long)bt * KLD + 512 + 2 * i];
    float re = __uint_as_float(u << 16);
    float im = __uint_as_float(u & 0xffff0000u);
    float o0 = re * c - im * s, o1 = re * s + im * c;
    uint_t o = (uint_t)f2bf(o0) | ((uint_t)f2bf(o1) << 16);
    *(uint_t*)&kfull[(long)bt * KLD + 512 + 2 * i] = o;
}

__global__ void rope_qr_kernel(ushort_t* __restrict__ qrb,
                               const float* __restrict__ cosT, const float* __restrict__ sinT) {
    int p = blockIdx.x * 256 + threadIdx.x;          // BT*NH*32 pairs
    if (p >= BT * 512) return;
    int bt = p >> 9, rem = p & 511;
    int hh = rem >> 5, i = rem & 31;
    int t = bt & (Tn - 1);
    float c = cosT[t * 32 + i], s = sinT[t * 32 + i];
    long off = (long)bt * 1024 + hh * 64 + 2 * i;
    uint_t u = *(const uint_t*)&qrb[off];
    float re = __uint_as_float(u << 16);
    float im = __uint_as_float(u & 0xffff0000u);
    float o0 = re * c - im * s, o1 = re * s + im * c;
    uint_t o = (uint_t)f2bf(o0) | ((uint_t)f2bf(o1) << 16);
    *(uint_t*)&qrb[off] = o;
}

// ---------------------------------------------------------------------------
// Transpose Veff [4096 bs][2048 hd] -> VeffT [4 b][2048 hd][1024 s] (bf16)
// ---------------------------------------------------------------------------
__global__ void transpose_veff(const ushort_t* __restrict__ Veff, ushort_t* __restrict__ VeffT) {
    int idx = blockIdx.x * 256 + threadIdx.x;        // 4*128*2048 = 1048576
    int c = idx & 2047, rest = idx >> 11;
    int t8 = rest & 127, b = rest >> 7;
    ushort_t v[8];
    #pragma unroll
    for (int j = 0; j < 8; ++j)
        v[j] = Veff[((long)b * Tn + t8 * 8 + j) * 2048 + c];
    *(uint4*)&VeffT[((long)b * 2048 + c) * Tn + t8 * 8] = *(const uint4*)v;
}

// ---------------------------------------------------------------------------
extern "C" void kernel_launch(void* const* d_in, const int* in_sizes, int n_in,
                              void* d_out, int out_size, void* d_ws, size_t ws_size,
                              hipStream_t stream)
{
    (void)in_sizes; (void)n_in; (void)out_size; (void)ws_size;
    const float* x     = (const float*)d_in[0];
    const float* cosT  = (const float*)d_in[1];
    const float* sinT  = (const float*)d_in[2];
    const float* W_dq  = (const float*)d_in[3];   // [1536][2048]
    const float* W_uq  = (const float*)d_in[4];   // [1536 q][2048 hd]
    const float* W_dkv = (const float*)d_in[5];   // [512][2048]
    const float* W_uk  = (const float*)d_in[6];   // [2048 hd][512 k] (NT-ready)
    const float* W_uv  = (const float*)d_in[7];   // [2048][512]
    const float* W_qr  = (const float*)d_in[8];   // [1024][1536]
    const float* W_kr  = (const float*)d_in[9];   // [64][2048]
    const float* W_o   = (const float*)d_in[10];  // [2048][2048]
    float* out = (float*)d_out;

    // ---- workspace: 71,565,312 ushorts = 143.1 MB ----
    // SCRATCH [0, 31195136): conversions + cq + combined weights; all dead
    // before attn_s. Veff transient [31195136, 39583744) dead before attn_s.
    // Spk [0, 37748736) written only at attn_s.
    ushort_t* ws = (ushort_t*)d_ws;
    ushort_t* xb     = ws;                              // 8388608
    ushort_t* WB1    = ws + 8388608;                    // 4456448  [2176][2048] = Wdq|Wdkv|Wkr|pad
    ushort_t* WB2    = ws + 12845056;                   // 4718592  [3072][1536] = WuqT|Wqr
    ushort_t* Wo_b   = ws + 17563648;                   // 4194304  [2048][2048]
    ushort_t* WuvT_b = ws + 21757952;                   // 1048576  [512][2048]
    ushort_t* cq_b   = ws + 22806528;                   // 6291456  [4096][1536] -> 29097984
    ushort_t* WB3    = ws + 29097984;                   // 2097152  [4096][512] = Wuk|Mt -> 31195136
    ushort_t* Veff   = ws + 31195136;                   // 8388608  (transient) -> 39583744
    ushort_t* Spk    = ws;                              // 37748736 [64 z][36][128][128]
    // PERSISTENT region:
    ushort_t* qnom   = ws + 39583744;                   // 8388608  [4096][2048]
    ushort_t* qr_b   = ws + 47972352;                   // 4194304  [4096][1024]
    ushort_t* kabs   = ws + 52166656;                   // 8388608  [4096][2048]
    ushort_t* kfull  = ws + 60555264;                   // 2621440  [4096][640]
    ushort_t* VeffT  = ws + 63176704;                   // 8388608  [4][2048][1024] -> 71565312
    ushort_t* Mtb    = WB3 + 1048576;                   // Mt output inside WB3

    dim3 blk(256, 1, 1);

    // ---- conversions (1 fused + 2 transposes) ----
    cvt_all<<<dim3(9600), blk, 0, stream>>>(x, W_dq, W_dkv, W_kr, W_qr, W_o, W_uk,
                                            xb, WB1, WB2, Wo_b, WB3);
    transcvt_g<<<dim3(32, 24), blk, 0, stream>>>(W_uq, WB2, 2048, 1536);      // WuqT
    transcvt_g<<<dim3(8, 32), blk, 0, stream>>>(W_uv, WuvT_b, 512, 2048);     // WuvT

    // ---- Mt = Wo @ WuvT^T -> WB3 rows 2048..4095 ----
    gemm_bf16<ushort_t><<<dim3(4, 16, 1), blk, 0, stream>>>(
        Wo_b, WuvT_b, Mtb, Cn, Cn, Cn, NLKV);

    // ---- group1: [c_q | c_kv|c_kr] = xb @ WB1^T  (N=2176, K=2048) ----
    gemm_split<<<dim3(17, 32, 1), blk, 0, stream>>>(
        xb, Cn, Cn, WB1, cq_b, NLQ, 12, kfull, KLD);
    rope_kr_kernel<<<dim3(BT*32/256), blk, 0, stream>>>(kfull, cosT, sinT);

    // ---- group2: [q_nom | c_qr] = cq_b @ WB2^T  (N=3072, K=1536) ----
    gemm_split<<<dim3(24, 32, 1), blk, 0, stream>>>(
        cq_b, NLQ, NLQ, WB2, qnom, Cn, 16, qr_b, NH*DHR);
    rope_qr_kernel<<<dim3(BT*512/256), blk, 0, stream>>>(qr_b, cosT, sinT);

    // ---- group3: [kabs | Veff] = c_kv @ WB3^T  (N=4096, K=512, A lda 640) ----
    gemm_split<<<dim3(32, 32, 1), blk, 0, stream>>>(
        kfull, KLD, NLKV, WB3, kabs, Cn, 16, Veff, Cn);
    transpose_veff<<<dim3(4096), blk, 0, stream>>>(Veff, VeffT);

    // ---- attention as GEMM phases (single-shot, 64 z) ----
    attn_s_gemm<<<dim3(2304, 1, 1), blk, 0, stream>>>(qnom, qr_b, kabs, kfull, Spk);
    attn_softmax<<<dim3(BT * NH / 4), blk, 0, stream>>>(Spk);
    attn_pv_gemm<<<dim3(512, 1, 1), blk, 0, stream>>>(Spk, VeffT, out);
}